// Round 6
// baseline (1292.071 us; speedup 1.0000x reference)
//
#include <hip/hip_runtime.h>
#include <hip/hip_bf16.h>
#include <cstdint>

#define N_NODES 100000
#define N_EDGES 1600000
#define NBUK 391   // ceil(N_NODES / 256) buckets of 256 dst nodes
#define CHUNK 4096
#define MAXB 10240 // LDS staging capacity per bucket (mean 8192, +22σ)
#define NSB 13     // src super-buckets: src>>13 in [0,13)

static inline size_t alup(size_t x) { return (x + 255) & ~(size_t)255; }

static __device__ __forceinline__ uint32_t pack_bf16x2(float a, float b) {
  uint32_t ua = __float_as_uint(a); ua += 0x7FFF + ((ua >> 16) & 1);
  uint32_t ub = __float_as_uint(b); ub += 0x7FFF + ((ub >> 16) & 1);
  return (ua >> 16) | (ub & 0xFFFF0000u);
}
static __device__ __forceinline__ float bf16lo(uint32_t u) { return __uint_as_float(u << 16); }
static __device__ __forceinline__ float bf16hi(uint32_t u) { return __uint_as_float(u & 0xFFFF0000u); }

// ---------------- prep kernels ----------------

__global__ __launch_bounds__(256) void k_deg(const int* __restrict__ ei, int* __restrict__ deg) {
  int e = blockIdx.x * 256 + threadIdx.x;
  if (e < N_EDGES) {
    atomicAdd(&deg[ei[e]], 1);
    atomicAdd(&deg[ei[N_EDGES + e]], 1);
  }
}

__global__ __launch_bounds__(256) void k_dinv(const int* __restrict__ deg, float* __restrict__ dinv) {
  int i = blockIdx.x * 256 + threadIdx.x;
  if (i < N_NODES) dinv[i] = rsqrtf((float)(deg[i] + 1));  // +1 self loop
}

__global__ __launch_bounds__(1024) void k_scan(const int* __restrict__ deg,
                                               int* __restrict__ rowptr) {
  __shared__ int part[1024];
  const int CH = (N_NODES + 1023) / 1024;  // 98
  const int t = threadIdx.x;
  const int s0 = t * CH, s1 = min(s0 + CH, N_NODES);
  int s = 0;
  for (int i = s0; i < s1; ++i) s += deg[i];
  part[t] = s;
  __syncthreads();
  for (int off = 1; off < 1024; off <<= 1) {
    int v = (t >= off) ? part[t - off] : 0;
    __syncthreads();
    if (t >= off) part[t] += v;
    __syncthreads();
  }
  int excl = (t == 0) ? 0 : part[t - 1];
  for (int i = s0; i < s1; ++i) {
    rowptr[i] = excl;
    excl += deg[i];
  }
  if (t == 1023) rowptr[N_NODES] = excl;  // = 2*N_EDGES
}

__global__ __launch_bounds__(256) void k_binit(const int* __restrict__ rowptr,
                                               int* __restrict__ bcursor) {
  int b = blockIdx.x * 256 + threadIdx.x;
  if (b < NBUK) bcursor[b] = rowptr[min(b * 256, N_NODES)];
}

// Pass 1: multisplit edges into 391 coarse dst-buckets with coalesced writes.
// payload pack = (dst&255)<<17 | src   (src < 2^17)
__global__ __launch_bounds__(256) void k_bin(const int* __restrict__ ei,
                                             int* __restrict__ bcursor,
                                             uint32_t* __restrict__ ebuf) {
  __shared__ int hist[NBUK];
  __shared__ int excl[NBUK + 1];
  __shared__ int gbase[NBUK];
  __shared__ uint32_t stage[CHUNK];
  const int tid = threadIdx.x;
  const int base = blockIdx.x * CHUNK;
  const int n = min(CHUNK, 2 * N_EDGES - base);
  for (int i = tid; i < NBUK; i += 256) hist[i] = 0;
  __syncthreads();
  uint32_t pk[16]; int bk[16]; int rk[16];
#pragma unroll
  for (int i = 0; i < 16; ++i) {
    const int li = i * 256 + tid;
    bk[i] = -1;
    if (li < n) {
      const int e = base + li;
      const int src = ei[e];
      const int dst = (e < N_EDGES) ? ei[N_EDGES + e] : ei[e - N_EDGES];
      bk[i] = dst >> 8;
      pk[i] = ((uint32_t)(dst & 255) << 17) | (uint32_t)src;
      rk[i] = atomicAdd(&hist[bk[i]], 1);
    }
  }
  __syncthreads();
  if (tid < 64) {
    int c[7]; int s = 0;
#pragma unroll
    for (int j = 0; j < 7; ++j) {
      const int b = tid * 7 + j;
      c[j] = (b < NBUK) ? hist[b] : 0;
      s += c[j];
    }
    int incl = s;
#pragma unroll
    for (int off = 1; off < 64; off <<= 1) {
      const int v = __shfl_up(incl, off);
      if (tid >= off) incl += v;
    }
    int run = incl - s;
#pragma unroll
    for (int j = 0; j < 7; ++j) {
      const int b = tid * 7 + j;
      if (b < NBUK) {
        excl[b] = run;
        gbase[b] = atomicAdd(&bcursor[b], c[j]);
        run += c[j];
      }
    }
    if (tid == 63) excl[NBUK] = incl;
  }
  __syncthreads();
#pragma unroll
  for (int i = 0; i < 16; ++i)
    if (bk[i] >= 0) stage[excl[bk[i]] + rk[i]] = pk[i];
  __syncthreads();
  for (int i = tid; i < n; i += 256) {
    int lo = 0, hi = NBUK - 1;
#pragma unroll
    for (int it = 0; it < 9; ++it) {
      const int mid = (lo + hi + 1) >> 1;
      if (excl[mid] <= i) lo = mid; else hi = mid - 1;
    }
    ebuf[gbase[lo] + (i - excl[lo])] = stage[i];
  }
}

// Pass 2: one workgroup per bucket. Counting sort by (dst_local, src>>13); also emits
// per-(node, sb) segment boundaries rp2[node][0..NSB] for the phase-ordered aggregation.
__global__ __launch_bounds__(256) void k_csr(const uint32_t* __restrict__ ebuf,
                                             const int* __restrict__ rowptr,
                                             int* __restrict__ col,
                                             int* __restrict__ rp2) {
  __shared__ int cnt[256 * NSB];   // 13.3 KB
  __shared__ int lstage[MAXB];     // 40 KB
  const int b = blockIdx.x;
  const int node0 = b << 8;
  const int node1 = min(node0 + 256, N_NODES);
  const int gstart = rowptr[node0];
  const int total = rowptr[node1] - gstart;
  const int tid = threadIdx.x;
  for (int i = tid; i < 256 * NSB; i += 256) cnt[i] = 0;
  __syncthreads();
  for (int i = tid; i < total; i += 256) {
    const uint32_t pk = ebuf[gstart + i];
    atomicAdd(&cnt[(pk >> 17) * NSB + ((pk & 0x1FFFF) >> 13)], 1);
  }
  __syncthreads();
  {  // per-segment scan: thread dl owns its NSB counters; emit boundaries
    const int dl = tid;
    const bool valid = (node0 + dl < node1);
    int run = valid ? (rowptr[node0 + dl] - gstart) : 0;
#pragma unroll
    for (int s = 0; s < NSB; ++s) {
      const int c = cnt[dl * NSB + s];
      cnt[dl * NSB + s] = run;
      if (valid) rp2[(size_t)(node0 + dl) * 16 + s] = gstart + run;
      run += c;
    }
    if (valid) rp2[(size_t)(node0 + dl) * 16 + NSB] = gstart + run;
  }
  __syncthreads();
  for (int i = tid; i < total; i += 256) {
    const uint32_t pk = ebuf[gstart + i];
    const int src = pk & 0x1FFFF;
    const int p = atomicAdd(&cnt[(pk >> 17) * NSB + (src >> 13)], 1);
    if (p < MAXB) lstage[p] = src;
    else col[gstart + p] = src;  // overflow fallback (statistically never)
  }
  __syncthreads();
  const int m = min(total, MAXB);
  for (int i = tid; i < m; i += 256) col[gstart + i] = lstage[i];
}

// ---------------- GEMM: hs = dinv[row] * (x @ W.T) ----------------
template<int OUT, bool BF16OUT>
__global__ __launch_bounds__(256) void k_gemm(const float* __restrict__ x,
                                              const float* __restrict__ W,
                                              const float* __restrict__ dinv,
                                              void* __restrict__ hout) {
  __shared__ float wlds[128 * 68];
  __shared__ float xlds[128 * 33];
  const int tid = threadIdx.x;
  const int cg = tid & 15;
  const int rg = tid >> 4;
  const int obase = blockIdx.y * 64;
  for (int idx = tid; idx < 64 * 32; idx += 256) {
    int o = idx >> 5;
    int k4 = (idx & 31) << 2;
    const float4 wv = *(const float4*)(W + (size_t)(obase + o) * 128 + k4);
    wlds[(k4 + 0) * 68 + o] = wv.x;
    wlds[(k4 + 1) * 68 + o] = wv.y;
    wlds[(k4 + 2) * 68 + o] = wv.z;
    wlds[(k4 + 3) * 68 + o] = wv.w;
  }
  for (int tile = blockIdx.x; tile < N_NODES / 32; tile += gridDim.x) {
    const int row0 = tile * 32;
    __syncthreads();
    for (int idx = tid; idx < 32 * 32; idx += 256) {
      int r = idx >> 5;
      int k4 = (idx & 31) << 2;
      const float4 xv = *(const float4*)(x + (size_t)(row0 + r) * 128 + k4);
      xlds[(k4 + 0) * 33 + r] = xv.x;
      xlds[(k4 + 1) * 33 + r] = xv.y;
      xlds[(k4 + 2) * 33 + r] = xv.z;
      xlds[(k4 + 3) * 33 + r] = xv.w;
    }
    __syncthreads();
    float a00 = 0, a01 = 0, a02 = 0, a03 = 0;
    float a10 = 0, a11 = 0, a12 = 0, a13 = 0;
#pragma unroll 4
    for (int k = 0; k < 128; ++k) {
      const float4 wv = *(const float4*)(wlds + k * 68 + cg * 4);
      const float x0 = xlds[k * 33 + rg * 2 + 0];
      const float x1 = xlds[k * 33 + rg * 2 + 1];
      a00 = fmaf(x0, wv.x, a00); a01 = fmaf(x0, wv.y, a01);
      a02 = fmaf(x0, wv.z, a02); a03 = fmaf(x0, wv.w, a03);
      a10 = fmaf(x1, wv.x, a10); a11 = fmaf(x1, wv.y, a11);
      a12 = fmaf(x1, wv.z, a12); a13 = fmaf(x1, wv.w, a13);
    }
    const float dv0 = dinv[row0 + rg * 2 + 0];
    const float dv1 = dinv[row0 + rg * 2 + 1];
    if (BF16OUT) {
      uint32_t* hp = (uint32_t*)hout + (size_t)(row0 + rg * 2) * (OUT / 2) + obase / 2 + cg * 2;
      *(uint2*)hp = make_uint2(pack_bf16x2(a00 * dv0, a01 * dv0), pack_bf16x2(a02 * dv0, a03 * dv0));
      *(uint2*)(hp + OUT / 2) = make_uint2(pack_bf16x2(a10 * dv1, a11 * dv1), pack_bf16x2(a12 * dv1, a13 * dv1));
    } else {
      float* hp = (float*)hout + (size_t)(row0 + rg * 2) * OUT + obase + cg * 4;
      *(float4*)hp = make_float4(a00 * dv0, a01 * dv0, a02 * dv0, a03 * dv0);
      *(float4*)(hp + OUT) = make_float4(a10 * dv1, a11 * dv1, a12 * dv1, a13 * dv1);
    }
  }
}

// ---------------- aggregation, phase-ordered over src super-buckets ----------------
// out[i] = di*(sum_c hs[c] + hs[i]) + b ; one wave per node; 2 cols/lane (bf16x2).
template<bool RELU>
__global__ __launch_bounds__(256) void k_agg128(const uint32_t* __restrict__ hs,
                                                const float* __restrict__ dinv,
                                                const int* __restrict__ rp2,
                                                const int* __restrict__ col,
                                                const float* __restrict__ bias,
                                                float* __restrict__ out) {
  const int lane = threadIdx.x & 63;
  const int node = blockIdx.x * 4 + (threadIdx.x >> 6);
  if (node >= N_NODES) return;
  const int bnd = rp2[(size_t)node * 16 + min(lane, NSB)];  // lanes 0..13 hold boundaries
  const uint32_t us = hs[(size_t)node * 64 + lane];  // prescaled self-loop term
  float ax = bf16lo(us), ay = bf16hi(us);
  for (int sb = 0; sb < NSB; ++sb) {
    const int s = __shfl(bnd, sb);
    const int e = __shfl(bnd, sb + 1);
    for (int eb = s; eb < e; eb += 64) {
      const int n = min(64, e - eb);
      const int ce = col[min(eb + lane, e - 1)];
      for (int j = 0; j < n; ++j) {
        const int c = __shfl(ce, j);
        const uint32_t u = hs[(size_t)c * 64 + lane];
        ax += bf16lo(u);
        ay += bf16hi(u);
      }
    }
  }
  const float di = dinv[node];
  const float2 bv = ((const float2*)bias)[lane];
  float ox = di * ax + bv.x;
  float oy = di * ay + bv.y;
  if (RELU) { ox = fmaxf(ox, 0.f); oy = fmaxf(oy, 0.f); }
  ((float2*)out)[(size_t)node * 64 + lane] = make_float2(ox, oy);
}

// Final layer: bf16 gather (row = 32 u32), paired-edge layout (lanes 0-31 even edges,
// 32-63 odd), phase-ordered; fused bias + log_softmax (2 cols/lane over 32 lanes).
__global__ __launch_bounds__(256) void k_agg64_lsm(const uint32_t* __restrict__ hs,
                                                   const float* __restrict__ dinv,
                                                   const int* __restrict__ rp2,
                                                   const int* __restrict__ col,
                                                   const float* __restrict__ bias,
                                                   float* __restrict__ out) {
  const int lane = threadIdx.x & 63;
  const int half = lane >> 5;
  const int w = lane & 31;
  const int node = blockIdx.x * 4 + (threadIdx.x >> 6);
  if (node >= N_NODES) return;
  const int bnd = rp2[(size_t)node * 16 + min(lane, NSB)];
  float ax = 0.f, ay = 0.f;
  if (half == 0) {  // self-loop term counted once
    const uint32_t us = hs[(size_t)node * 32 + w];
    ax = bf16lo(us); ay = bf16hi(us);
  }
  for (int sb = 0; sb < NSB; ++sb) {
    const int s = __shfl(bnd, sb);
    const int e = __shfl(bnd, sb + 1);
    for (int eb = s; eb < e; eb += 64) {
      const int n = min(64, e - eb);
      const int ce = col[min(eb + lane, e - 1)];
      const int hn = (n + 1) >> 1;
      for (int j = 0; j < hn; ++j) {
        const int idx = 2 * j + half;
        const int c = __shfl(ce, idx);
        if (idx < n) {
          const uint32_t u = hs[(size_t)c * 32 + w];
          ax += bf16lo(u);
          ay += bf16hi(u);
        }
      }
    }
  }
  ax += __shfl_xor(ax, 32);
  ay += __shfl_xor(ay, 32);
  const float di = dinv[node];
  const float2 bv = ((const float2*)bias)[w];
  const float v0 = di * ax + bv.x;
  const float v1 = di * ay + bv.y;
  float m = fmaxf(v0, v1);
#pragma unroll
  for (int off = 16; off > 0; off >>= 1) m = fmaxf(m, __shfl_xor(m, off));
  float s = __expf(v0 - m) + __expf(v1 - m);
#pragma unroll
  for (int off = 16; off > 0; off >>= 1) s += __shfl_xor(s, off);
  const float ls = m + __logf(s);
  if (half == 0)
    ((float2*)out)[(size_t)node * 32 + w] = make_float2(v0 - ls, v1 - ls);
}

// ---------------- launch ----------------

extern "C" void kernel_launch(void* const* d_in, const int* in_sizes, int n_in,
                              void* d_out, int out_size, void* d_ws, size_t ws_size,
                              hipStream_t stream) {
  const float* x  = (const float*)d_in[0];
  const int*   ei = (const int*)d_in[1];
  const float* W0 = (const float*)d_in[2];
  const float* b0 = (const float*)d_in[3];
  const float* W1 = (const float*)d_in[4];
  const float* b1 = (const float*)d_in[5];
  const float* W2 = (const float*)d_in[6];
  const float* b2 = (const float*)d_in[7];
  float* outp = (float*)d_out;

  char* p = (char*)d_ws;
  int*   deg     = (int*)p;   p += alup((size_t)N_NODES * 4);
  float* dinv    = (float*)p; p += alup((size_t)N_NODES * 4);
  int*   rowptr  = (int*)p;   p += alup((size_t)(N_NODES + 1) * 4);
  int*   bcursor = (int*)p;   p += alup((size_t)NBUK * 4);
  int*   col     = (int*)p;   p += alup((size_t)2 * N_EDGES * 4);
  int*   rp2     = (int*)p;   p += alup((size_t)N_NODES * 16 * 4);
  float* bufA    = (float*)p; p += alup((size_t)N_NODES * 128 * 4);
  float* bufB    = (float*)p;
  uint32_t* ebuf = (uint32_t*)bufA;       // pass-1 staging aliases bufA
  uint32_t* h16  = (uint32_t*)bufA;       // bf16x2 gemm output (all layers)

  hipMemsetAsync(deg, 0, (size_t)N_NODES * 4, stream);
  k_deg<<<(N_EDGES + 255) / 256, 256, 0, stream>>>(ei, deg);
  k_dinv<<<(N_NODES + 255) / 256, 256, 0, stream>>>(deg, dinv);
  k_scan<<<1, 1024, 0, stream>>>(deg, rowptr);
  k_binit<<<(NBUK + 255) / 256, 256, 0, stream>>>(rowptr, bcursor);
  k_bin<<<(2 * N_EDGES + CHUNK - 1) / CHUNK, 256, 0, stream>>>(ei, bcursor, ebuf);
  k_csr<<<NBUK, 256, 0, stream>>>(ebuf, rowptr, col, rp2);

  dim3 g128(640, 2), g64(640, 1);
  k_gemm<128, true><<<g128, 256, 0, stream>>>(x, W0, dinv, h16);
  k_agg128<true><<<N_NODES / 4, 256, 0, stream>>>(h16, dinv, rp2, col, b0, bufB);
  k_gemm<128, true><<<g128, 256, 0, stream>>>(bufB, W1, dinv, h16);
  k_agg128<true><<<N_NODES / 4, 256, 0, stream>>>(h16, dinv, rp2, col, b1, bufB);
  k_gemm<64, true><<<g64, 256, 0, stream>>>(bufB, W2, dinv, h16);
  k_agg64_lsm<<<N_NODES / 4, 256, 0, stream>>>(h16, dinv, rp2, col, b2, outp);
}

// Round 7
// 963.097 us; speedup vs baseline: 1.3416x; 1.3416x over previous
//
#include <hip/hip_runtime.h>
#include <hip/hip_bf16.h>
#include <cstdint>

#define N_NODES 100000
#define N_EDGES 1600000
#define NBUK 391   // ceil(N_NODES / 256) buckets of 256 dst nodes
#define CHUNK 4096
#define MAXB 10240 // LDS staging capacity per bucket (mean 8192, +22σ)
#define NSB 16     // src super-buckets: src>>13 in [0,13)

static inline size_t alup(size_t x) { return (x + 255) & ~(size_t)255; }

static __device__ __forceinline__ uint32_t pack_bf16x2(float a, float b) {
  uint32_t ua = __float_as_uint(a); ua += 0x7FFF + ((ua >> 16) & 1);
  uint32_t ub = __float_as_uint(b); ub += 0x7FFF + ((ub >> 16) & 1);
  return (ua >> 16) | (ub & 0xFFFF0000u);
}
static __device__ __forceinline__ float bf16lo(uint32_t u) { return __uint_as_float(u << 16); }
static __device__ __forceinline__ float bf16hi(uint32_t u) { return __uint_as_float(u & 0xFFFF0000u); }

// ---------------- prep kernels ----------------

__global__ __launch_bounds__(256) void k_deg(const int* __restrict__ ei, int* __restrict__ deg) {
  int e = blockIdx.x * 256 + threadIdx.x;
  if (e < N_EDGES) {
    atomicAdd(&deg[ei[e]], 1);
    atomicAdd(&deg[ei[N_EDGES + e]], 1);
  }
}

__global__ __launch_bounds__(256) void k_dinv(const int* __restrict__ deg, float* __restrict__ dinv) {
  int i = blockIdx.x * 256 + threadIdx.x;
  if (i < N_NODES) dinv[i] = rsqrtf((float)(deg[i] + 1));  // +1 self loop
}

__global__ __launch_bounds__(1024) void k_scan(const int* __restrict__ deg,
                                               int* __restrict__ rowptr) {
  __shared__ int part[1024];
  const int CH = (N_NODES + 1023) / 1024;  // 98
  const int t = threadIdx.x;
  const int s0 = t * CH, s1 = min(s0 + CH, N_NODES);
  int s = 0;
  for (int i = s0; i < s1; ++i) s += deg[i];
  part[t] = s;
  __syncthreads();
  for (int off = 1; off < 1024; off <<= 1) {
    int v = (t >= off) ? part[t - off] : 0;
    __syncthreads();
    if (t >= off) part[t] += v;
    __syncthreads();
  }
  int excl = (t == 0) ? 0 : part[t - 1];
  for (int i = s0; i < s1; ++i) {
    rowptr[i] = excl;
    excl += deg[i];
  }
  if (t == 1023) rowptr[N_NODES] = excl;  // = 2*N_EDGES
}

__global__ __launch_bounds__(256) void k_binit(const int* __restrict__ rowptr,
                                               int* __restrict__ bcursor) {
  int b = blockIdx.x * 256 + threadIdx.x;
  if (b < NBUK) bcursor[b] = rowptr[min(b * 256, N_NODES)];
}

// Pass 1: multisplit edges into 391 coarse dst-buckets with coalesced writes.
// payload pack = (dst&255)<<17 | src   (src < 2^17)
__global__ __launch_bounds__(256) void k_bin(const int* __restrict__ ei,
                                             int* __restrict__ bcursor,
                                             uint32_t* __restrict__ ebuf) {
  __shared__ int hist[NBUK];
  __shared__ int excl[NBUK + 1];
  __shared__ int gbase[NBUK];
  __shared__ uint32_t stage[CHUNK];
  const int tid = threadIdx.x;
  const int base = blockIdx.x * CHUNK;
  const int n = min(CHUNK, 2 * N_EDGES - base);
  for (int i = tid; i < NBUK; i += 256) hist[i] = 0;
  __syncthreads();
  uint32_t pk[16]; int bk[16]; int rk[16];
#pragma unroll
  for (int i = 0; i < 16; ++i) {
    const int li = i * 256 + tid;
    bk[i] = -1;
    if (li < n) {
      const int e = base + li;
      const int src = ei[e];
      const int dst = (e < N_EDGES) ? ei[N_EDGES + e] : ei[e - N_EDGES];
      bk[i] = dst >> 8;
      pk[i] = ((uint32_t)(dst & 255) << 17) | (uint32_t)src;
      rk[i] = atomicAdd(&hist[bk[i]], 1);
    }
  }
  __syncthreads();
  if (tid < 64) {
    int c[7]; int s = 0;
#pragma unroll
    for (int j = 0; j < 7; ++j) {
      const int b = tid * 7 + j;
      c[j] = (b < NBUK) ? hist[b] : 0;
      s += c[j];
    }
    int incl = s;
#pragma unroll
    for (int off = 1; off < 64; off <<= 1) {
      const int v = __shfl_up(incl, off);
      if (tid >= off) incl += v;
    }
    int run = incl - s;
#pragma unroll
    for (int j = 0; j < 7; ++j) {
      const int b = tid * 7 + j;
      if (b < NBUK) {
        excl[b] = run;
        gbase[b] = atomicAdd(&bcursor[b], c[j]);
        run += c[j];
      }
    }
    if (tid == 63) excl[NBUK] = incl;
  }
  __syncthreads();
#pragma unroll
  for (int i = 0; i < 16; ++i)
    if (bk[i] >= 0) stage[excl[bk[i]] + rk[i]] = pk[i];
  __syncthreads();
  for (int i = tid; i < n; i += 256) {
    int lo = 0, hi = NBUK - 1;
#pragma unroll
    for (int it = 0; it < 9; ++it) {
      const int mid = (lo + hi + 1) >> 1;
      if (excl[mid] <= i) lo = mid; else hi = mid - 1;
    }
    ebuf[gbase[lo] + (i - excl[lo])] = stage[i];
  }
}

// Pass 2: one workgroup per bucket. Counting sort by (dst_local, src>>13) so each
// node's neighbor list is grouped by src super-bucket (L2 locality), then
// coalesced CSR writeback.
__global__ __launch_bounds__(256) void k_csr(const uint32_t* __restrict__ ebuf,
                                             const int* __restrict__ rowptr,
                                             int* __restrict__ col) {
  __shared__ int cnt[256 * NSB];   // 16 KB
  __shared__ int lstage[MAXB];     // 40 KB
  const int b = blockIdx.x;
  const int node0 = b << 8;
  const int node1 = min(node0 + 256, N_NODES);
  const int gstart = rowptr[node0];
  const int total = rowptr[node1] - gstart;
  const int tid = threadIdx.x;
  for (int i = tid; i < 256 * NSB; i += 256) cnt[i] = 0;
  __syncthreads();
  for (int i = tid; i < total; i += 256) {
    const uint32_t pk = ebuf[gstart + i];
    atomicAdd(&cnt[(pk >> 17) * NSB + ((pk & 0x1FFFF) >> 13)], 1);
  }
  __syncthreads();
  {  // per-segment scan: thread dl owns its 16 counters
    const int dl = tid;
    int run = (node0 + dl < node1) ? (rowptr[node0 + dl] - gstart) : 0;
#pragma unroll
    for (int s = 0; s < NSB; ++s) {
      const int c = cnt[dl * NSB + s];
      cnt[dl * NSB + s] = run;
      run += c;
    }
  }
  __syncthreads();
  for (int i = tid; i < total; i += 256) {
    const uint32_t pk = ebuf[gstart + i];
    const int src = pk & 0x1FFFF;
    const int p = atomicAdd(&cnt[(pk >> 17) * NSB + (src >> 13)], 1);
    if (p < MAXB) lstage[p] = src;
    else col[gstart + p] = src;  // overflow fallback (statistically never)
  }
  __syncthreads();
  const int m = min(total, MAXB);
  for (int i = tid; i < m; i += 256) col[gstart + i] = lstage[i];
}

// ---------------- GEMM: hs = dinv[row] * (x @ W.T) ----------------
template<int OUT, bool BF16OUT>
__global__ __launch_bounds__(256) void k_gemm(const float* __restrict__ x,
                                              const float* __restrict__ W,
                                              const float* __restrict__ dinv,
                                              void* __restrict__ hout) {
  __shared__ float wlds[128 * 68];
  __shared__ float xlds[128 * 33];
  const int tid = threadIdx.x;
  const int cg = tid & 15;
  const int rg = tid >> 4;
  const int obase = blockIdx.y * 64;
  for (int idx = tid; idx < 64 * 32; idx += 256) {
    int o = idx >> 5;
    int k4 = (idx & 31) << 2;
    const float4 wv = *(const float4*)(W + (size_t)(obase + o) * 128 + k4);
    wlds[(k4 + 0) * 68 + o] = wv.x;
    wlds[(k4 + 1) * 68 + o] = wv.y;
    wlds[(k4 + 2) * 68 + o] = wv.z;
    wlds[(k4 + 3) * 68 + o] = wv.w;
  }
  for (int tile = blockIdx.x; tile < N_NODES / 32; tile += gridDim.x) {
    const int row0 = tile * 32;
    __syncthreads();
    for (int idx = tid; idx < 32 * 32; idx += 256) {
      int r = idx >> 5;
      int k4 = (idx & 31) << 2;
      const float4 xv = *(const float4*)(x + (size_t)(row0 + r) * 128 + k4);
      xlds[(k4 + 0) * 33 + r] = xv.x;
      xlds[(k4 + 1) * 33 + r] = xv.y;
      xlds[(k4 + 2) * 33 + r] = xv.z;
      xlds[(k4 + 3) * 33 + r] = xv.w;
    }
    __syncthreads();
    float a00 = 0, a01 = 0, a02 = 0, a03 = 0;
    float a10 = 0, a11 = 0, a12 = 0, a13 = 0;
#pragma unroll 4
    for (int k = 0; k < 128; ++k) {
      const float4 wv = *(const float4*)(wlds + k * 68 + cg * 4);
      const float x0 = xlds[k * 33 + rg * 2 + 0];
      const float x1 = xlds[k * 33 + rg * 2 + 1];
      a00 = fmaf(x0, wv.x, a00); a01 = fmaf(x0, wv.y, a01);
      a02 = fmaf(x0, wv.z, a02); a03 = fmaf(x0, wv.w, a03);
      a10 = fmaf(x1, wv.x, a10); a11 = fmaf(x1, wv.y, a11);
      a12 = fmaf(x1, wv.z, a12); a13 = fmaf(x1, wv.w, a13);
    }
    const float dv0 = dinv[row0 + rg * 2 + 0];
    const float dv1 = dinv[row0 + rg * 2 + 1];
    if (BF16OUT) {
      uint32_t* hp = (uint32_t*)hout + (size_t)(row0 + rg * 2) * (OUT / 2) + obase / 2 + cg * 2;
      *(uint2*)hp = make_uint2(pack_bf16x2(a00 * dv0, a01 * dv0), pack_bf16x2(a02 * dv0, a03 * dv0));
      *(uint2*)(hp + OUT / 2) = make_uint2(pack_bf16x2(a10 * dv1, a11 * dv1), pack_bf16x2(a12 * dv1, a13 * dv1));
    } else {
      float* hp = (float*)hout + (size_t)(row0 + rg * 2) * OUT + obase + cg * 4;
      *(float4*)hp = make_float4(a00 * dv0, a01 * dv0, a02 * dv0, a03 * dv0);
      *(float4*)(hp + OUT) = make_float4(a10 * dv1, a11 * dv1, a12 * dv1, a13 * dv1);
    }
  }
}

// ---------------- aggregation: out[i] = di*(sum_c hs[c] + hs[i]) + b ----------------
// Paired-edge layout: lanes 0-31 even edges, 32-63 odd edges; each 32-lane half
// reads a full 256B row as uint2 (2 rows in flight per instr); 4 cols/lane fp32 acc;
// halves combined via shfl_xor(32).
template<bool RELU>
__global__ __launch_bounds__(256) void k_agg128(const uint32_t* __restrict__ hs,
                                                const float* __restrict__ dinv,
                                                const int* __restrict__ rowptr,
                                                const int* __restrict__ col,
                                                const float* __restrict__ bias,
                                                float* __restrict__ out) {
  const int lane = threadIdx.x & 63;
  const int half = lane >> 5;   // 0 = even edges, 1 = odd edges
  const int w = lane & 31;      // uint2 index: cols {4w..4w+3}
  const int node = blockIdx.x * 4 + (threadIdx.x >> 6);
  if (node >= N_NODES) return;
  const int e0 = rowptr[node], e1 = rowptr[node + 1];
  const uint2* hp = (const uint2*)hs;   // row = 32 uint2
  float a0 = 0.f, a1 = 0.f, a2 = 0.f, a3 = 0.f;
  if (half == 0) {  // self-loop counted once
    const uint2 us = hp[(size_t)node * 32 + w];
    a0 = bf16lo(us.x); a1 = bf16hi(us.x); a2 = bf16lo(us.y); a3 = bf16hi(us.y);
  }
  for (int eb = e0; eb < e1; eb += 64) {
    const int n = min(64, e1 - eb);
    const int ce = col[min(eb + lane, e1 - 1)];
    const int hn = (n + 1) >> 1;
#pragma unroll 4
    for (int j = 0; j < hn; ++j) {
      const int idx = 2 * j + half;
      const int c = __shfl(ce, idx);
      if (idx < n) {
        const uint2 u = hp[(size_t)c * 32 + w];
        a0 += bf16lo(u.x); a1 += bf16hi(u.x);
        a2 += bf16lo(u.y); a3 += bf16hi(u.y);
      }
    }
  }
  a0 += __shfl_xor(a0, 32); a1 += __shfl_xor(a1, 32);
  a2 += __shfl_xor(a2, 32); a3 += __shfl_xor(a3, 32);
  if (half == 0) {
    const float di = dinv[node];
    const float4 bv = ((const float4*)bias)[w];
    float o0 = di * a0 + bv.x, o1 = di * a1 + bv.y;
    float o2 = di * a2 + bv.z, o3 = di * a3 + bv.w;
    if (RELU) {
      o0 = fmaxf(o0, 0.f); o1 = fmaxf(o1, 0.f);
      o2 = fmaxf(o2, 0.f); o3 = fmaxf(o3, 0.f);
    }
    ((float4*)out)[(size_t)node * 32 + w] = make_float4(o0, o1, o2, o3);
  }
}

// Final layer: quad-edge layout (lane quarter q handles edges 4j+q); each 16-lane
// quarter reads a full 128B row as uint2; combine via shfl_xor(32),(16);
// fused bias + log_softmax (4 cols/lane over 16 lanes).
__global__ __launch_bounds__(256) void k_agg64_lsm(const uint32_t* __restrict__ hs,
                                                   const float* __restrict__ dinv,
                                                   const int* __restrict__ rowptr,
                                                   const int* __restrict__ col,
                                                   const float* __restrict__ bias,
                                                   float* __restrict__ out) {
  const int lane = threadIdx.x & 63;
  const int q = lane >> 4;      // edge sub-slot 0..3
  const int t = lane & 15;      // uint2 index: cols {4t..4t+3}
  const int node = blockIdx.x * 4 + (threadIdx.x >> 6);
  if (node >= N_NODES) return;
  const int e0 = rowptr[node], e1 = rowptr[node + 1];
  const uint2* hp = (const uint2*)hs;   // row = 16 uint2
  float a0 = 0.f, a1 = 0.f, a2 = 0.f, a3 = 0.f;
  if (q == 0) {  // self-loop counted once
    const uint2 us = hp[(size_t)node * 16 + t];
    a0 = bf16lo(us.x); a1 = bf16hi(us.x); a2 = bf16lo(us.y); a3 = bf16hi(us.y);
  }
  for (int eb = e0; eb < e1; eb += 64) {
    const int n = min(64, e1 - eb);
    const int ce = col[min(eb + lane, e1 - 1)];
    const int qn = (n + 3) >> 2;
#pragma unroll 4
    for (int j = 0; j < qn; ++j) {
      const int idx = 4 * j + q;
      const int c = __shfl(ce, idx);
      if (idx < n) {
        const uint2 u = hp[(size_t)c * 16 + t];
        a0 += bf16lo(u.x); a1 += bf16hi(u.x);
        a2 += bf16lo(u.y); a3 += bf16hi(u.y);
      }
    }
  }
  a0 += __shfl_xor(a0, 32); a1 += __shfl_xor(a1, 32);
  a2 += __shfl_xor(a2, 32); a3 += __shfl_xor(a3, 32);
  a0 += __shfl_xor(a0, 16); a1 += __shfl_xor(a1, 16);
  a2 += __shfl_xor(a2, 16); a3 += __shfl_xor(a3, 16);
  const float di = dinv[node];
  const float4 bv = ((const float4*)bias)[t];
  const float v0 = di * a0 + bv.x;
  const float v1 = di * a1 + bv.y;
  const float v2 = di * a2 + bv.z;
  const float v3 = di * a3 + bv.w;
  float m = fmaxf(fmaxf(v0, v1), fmaxf(v2, v3));
#pragma unroll
  for (int off = 8; off > 0; off >>= 1) m = fmaxf(m, __shfl_xor(m, off));
  float s = __expf(v0 - m) + __expf(v1 - m) + __expf(v2 - m) + __expf(v3 - m);
#pragma unroll
  for (int off = 8; off > 0; off >>= 1) s += __shfl_xor(s, off);
  const float ls = m + __logf(s);
  if (q == 0)
    ((float4*)out)[(size_t)node * 16 + t] = make_float4(v0 - ls, v1 - ls, v2 - ls, v3 - ls);
}

// ---------------- launch ----------------

extern "C" void kernel_launch(void* const* d_in, const int* in_sizes, int n_in,
                              void* d_out, int out_size, void* d_ws, size_t ws_size,
                              hipStream_t stream) {
  const float* x  = (const float*)d_in[0];
  const int*   ei = (const int*)d_in[1];
  const float* W0 = (const float*)d_in[2];
  const float* b0 = (const float*)d_in[3];
  const float* W1 = (const float*)d_in[4];
  const float* b1 = (const float*)d_in[5];
  const float* W2 = (const float*)d_in[6];
  const float* b2 = (const float*)d_in[7];
  float* outp = (float*)d_out;

  char* p = (char*)d_ws;
  int*   deg     = (int*)p;   p += alup((size_t)N_NODES * 4);
  float* dinv    = (float*)p; p += alup((size_t)N_NODES * 4);
  int*   rowptr  = (int*)p;   p += alup((size_t)(N_NODES + 1) * 4);
  int*   bcursor = (int*)p;   p += alup((size_t)NBUK * 4);
  int*   col     = (int*)p;   p += alup((size_t)2 * N_EDGES * 4);
  float* bufA    = (float*)p; p += alup((size_t)N_NODES * 128 * 4);
  float* bufB    = (float*)p;
  uint32_t* ebuf = (uint32_t*)bufA;       // pass-1 staging aliases bufA
  uint32_t* h16  = (uint32_t*)bufA;       // bf16x2 gemm output (all layers)

  hipMemsetAsync(deg, 0, (size_t)N_NODES * 4, stream);
  k_deg<<<(N_EDGES + 255) / 256, 256, 0, stream>>>(ei, deg);
  k_dinv<<<(N_NODES + 255) / 256, 256, 0, stream>>>(deg, dinv);
  k_scan<<<1, 1024, 0, stream>>>(deg, rowptr);
  k_binit<<<(NBUK + 255) / 256, 256, 0, stream>>>(rowptr, bcursor);
  k_bin<<<(2 * N_EDGES + CHUNK - 1) / CHUNK, 256, 0, stream>>>(ei, bcursor, ebuf);
  k_csr<<<NBUK, 256, 0, stream>>>(ebuf, rowptr, col);

  dim3 g128(640, 2), g64(640, 1);
  k_gemm<128, true><<<g128, 256, 0, stream>>>(x, W0, dinv, h16);
  k_agg128<true><<<N_NODES / 4, 256, 0, stream>>>(h16, dinv, rowptr, col, b0, bufB);
  k_gemm<128, true><<<g128, 256, 0, stream>>>(bufB, W1, dinv, h16);
  k_agg128<true><<<N_NODES / 4, 256, 0, stream>>>(h16, dinv, rowptr, col, b1, bufB);
  k_gemm<64, true><<<g64, 256, 0, stream>>>(bufB, W2, dinv, h16);
  k_agg64_lsm<<<N_NODES / 4, 256, 0, stream>>>(h16, dinv, rowptr, col, b2, outp);
}

// Round 8
// 807.033 us; speedup vs baseline: 1.6010x; 1.1934x over previous
//
#include <hip/hip_runtime.h>
#include <hip/hip_bf16.h>
#include <cstdint>

#define N_NODES 100000
#define N_EDGES 1600000
#define NBUK 391   // ceil(N_NODES / 256) buckets of 256 dst nodes
#define CHUNK 4096
#define MAXB 10240 // LDS staging capacity per bucket (mean 8192, +22σ)
#define NSB 16     // src super-buckets: src>>13 in [0,13)

static inline size_t alup(size_t x) { return (x + 255) & ~(size_t)255; }

static __device__ __forceinline__ uint32_t pack_bf16x2(float a, float b) {
  uint32_t ua = __float_as_uint(a); ua += 0x7FFF + ((ua >> 16) & 1);
  uint32_t ub = __float_as_uint(b); ub += 0x7FFF + ((ub >> 16) & 1);
  return (ua >> 16) | (ub & 0xFFFF0000u);
}
static __device__ __forceinline__ float bf16lo(uint32_t u) { return __uint_as_float(u << 16); }
static __device__ __forceinline__ float bf16hi(uint32_t u) { return __uint_as_float(u & 0xFFFF0000u); }

// ---------------- prep kernels ----------------

__global__ __launch_bounds__(256) void k_deg(const int* __restrict__ ei, int* __restrict__ deg) {
  int e = blockIdx.x * 256 + threadIdx.x;
  if (e < N_EDGES) {
    atomicAdd(&deg[ei[e]], 1);
    atomicAdd(&deg[ei[N_EDGES + e]], 1);
  }
}

__global__ __launch_bounds__(256) void k_dinv(const int* __restrict__ deg, float* __restrict__ dinv) {
  int i = blockIdx.x * 256 + threadIdx.x;
  if (i < N_NODES) dinv[i] = rsqrtf((float)(deg[i] + 1));  // +1 self loop
}

// Hierarchical scan, phase 1: per-bucket (256 nodes) inclusive scan via wave shuffles.
// rowptr[i] <- local exclusive prefix; bsum[b] <- bucket total.
__global__ __launch_bounds__(256) void k_scan1(const int* __restrict__ deg,
                                               int* __restrict__ rowptr,
                                               int* __restrict__ bsum) {
  const int tid = threadIdx.x;
  const int i = blockIdx.x * 256 + tid;
  const int v = (i < N_NODES) ? deg[i] : 0;
  int incl = v;
#pragma unroll
  for (int off = 1; off < 64; off <<= 1) {
    const int u = __shfl_up(incl, off);
    if ((tid & 63) >= off) incl += u;
  }
  __shared__ int wsum[4];
  if ((tid & 63) == 63) wsum[tid >> 6] = incl;
  __syncthreads();
  const int wid = tid >> 6;
  int add = 0;
#pragma unroll
  for (int k = 0; k < 3; ++k)
    if (k < wid) add += wsum[k];
  incl += add;
  if (i < N_NODES) rowptr[i] = incl - v;
  if (tid == 255) bsum[blockIdx.x] = incl;
}

// Phase 2: single block scans 391 bucket totals -> exclusive bbase[0..NBUK].
__global__ __launch_bounds__(512) void k_scan2(const int* __restrict__ bsum,
                                               int* __restrict__ bbase) {
  const int tid = threadIdx.x;
  const int v = (tid < NBUK) ? bsum[tid] : 0;
  int incl = v;
#pragma unroll
  for (int off = 1; off < 64; off <<= 1) {
    const int u = __shfl_up(incl, off);
    if ((tid & 63) >= off) incl += u;
  }
  __shared__ int wsum[8];
  if ((tid & 63) == 63) wsum[tid >> 6] = incl;
  __syncthreads();
  const int wid = tid >> 6;
  int add = 0;
#pragma unroll
  for (int k = 0; k < 7; ++k)
    if (k < wid) add += wsum[k];
  incl += add;
  if (tid < NBUK) bbase[tid] = incl - v;
  if (tid == NBUK - 1) bbase[NBUK] = incl;  // = 2*N_EDGES
}

// Phase 3: propagate bucket bases; also set rowptr[N_NODES] and bcursor (absorbs k_binit).
__global__ __launch_bounds__(256) void k_scan3(int* __restrict__ rowptr,
                                               const int* __restrict__ bbase,
                                               int* __restrict__ bcursor) {
  const int i = blockIdx.x * 256 + threadIdx.x;
  if (i < N_NODES) rowptr[i] += bbase[i >> 8];
  if (i == N_NODES) rowptr[N_NODES] = bbase[NBUK];
  if (threadIdx.x == 0) bcursor[blockIdx.x] = bbase[blockIdx.x];
}

// Pass 1: multisplit edges into 391 coarse dst-buckets with coalesced writes.
// payload pack = (dst&255)<<17 | src   (src < 2^17)
__global__ __launch_bounds__(256) void k_bin(const int* __restrict__ ei,
                                             int* __restrict__ bcursor,
                                             uint32_t* __restrict__ ebuf) {
  __shared__ int hist[NBUK];
  __shared__ int excl[NBUK + 1];
  __shared__ int gbase[NBUK];
  __shared__ uint32_t stage[CHUNK];
  const int tid = threadIdx.x;
  const int base = blockIdx.x * CHUNK;
  const int n = min(CHUNK, 2 * N_EDGES - base);
  for (int i = tid; i < NBUK; i += 256) hist[i] = 0;
  __syncthreads();
  uint32_t pk[16]; int bk[16]; int rk[16];
#pragma unroll
  for (int i = 0; i < 16; ++i) {
    const int li = i * 256 + tid;
    bk[i] = -1;
    if (li < n) {
      const int e = base + li;
      const int src = ei[e];
      const int dst = (e < N_EDGES) ? ei[N_EDGES + e] : ei[e - N_EDGES];
      bk[i] = dst >> 8;
      pk[i] = ((uint32_t)(dst & 255) << 17) | (uint32_t)src;
      rk[i] = atomicAdd(&hist[bk[i]], 1);
    }
  }
  __syncthreads();
  if (tid < 64) {
    int c[7]; int s = 0;
#pragma unroll
    for (int j = 0; j < 7; ++j) {
      const int b = tid * 7 + j;
      c[j] = (b < NBUK) ? hist[b] : 0;
      s += c[j];
    }
    int incl = s;
#pragma unroll
    for (int off = 1; off < 64; off <<= 1) {
      const int v = __shfl_up(incl, off);
      if (tid >= off) incl += v;
    }
    int run = incl - s;
#pragma unroll
    for (int j = 0; j < 7; ++j) {
      const int b = tid * 7 + j;
      if (b < NBUK) {
        excl[b] = run;
        gbase[b] = atomicAdd(&bcursor[b], c[j]);
        run += c[j];
      }
    }
    if (tid == 63) excl[NBUK] = incl;
  }
  __syncthreads();
#pragma unroll
  for (int i = 0; i < 16; ++i)
    if (bk[i] >= 0) stage[excl[bk[i]] + rk[i]] = pk[i];
  __syncthreads();
  for (int i = tid; i < n; i += 256) {
    int lo = 0, hi = NBUK - 1;
#pragma unroll
    for (int it = 0; it < 9; ++it) {
      const int mid = (lo + hi + 1) >> 1;
      if (excl[mid] <= i) lo = mid; else hi = mid - 1;
    }
    ebuf[gbase[lo] + (i - excl[lo])] = stage[i];
  }
}

// Pass 2: one workgroup per bucket. Counting sort by (dst_local, src>>13) so each
// node's neighbor list is grouped by src super-bucket (L2 locality), then
// coalesced CSR writeback.
__global__ __launch_bounds__(256) void k_csr(const uint32_t* __restrict__ ebuf,
                                             const int* __restrict__ rowptr,
                                             int* __restrict__ col) {
  __shared__ int cnt[256 * NSB];   // 16 KB
  __shared__ int lstage[MAXB];     // 40 KB
  const int b = blockIdx.x;
  const int node0 = b << 8;
  const int node1 = min(node0 + 256, N_NODES);
  const int gstart = rowptr[node0];
  const int total = rowptr[node1] - gstart;
  const int tid = threadIdx.x;
  for (int i = tid; i < 256 * NSB; i += 256) cnt[i] = 0;
  __syncthreads();
  for (int i = tid; i < total; i += 256) {
    const uint32_t pk = ebuf[gstart + i];
    atomicAdd(&cnt[(pk >> 17) * NSB + ((pk & 0x1FFFF) >> 13)], 1);
  }
  __syncthreads();
  {  // per-segment scan: thread dl owns its 16 counters
    const int dl = tid;
    int run = (node0 + dl < node1) ? (rowptr[node0 + dl] - gstart) : 0;
#pragma unroll
    for (int s = 0; s < NSB; ++s) {
      const int c = cnt[dl * NSB + s];
      cnt[dl * NSB + s] = run;
      run += c;
    }
  }
  __syncthreads();
  for (int i = tid; i < total; i += 256) {
    const uint32_t pk = ebuf[gstart + i];
    const int src = pk & 0x1FFFF;
    const int p = atomicAdd(&cnt[(pk >> 17) * NSB + (src >> 13)], 1);
    if (p < MAXB) lstage[p] = src;
    else col[gstart + p] = src;  // overflow fallback (statistically never)
  }
  __syncthreads();
  const int m = min(total, MAXB);
  for (int i = tid; i < m; i += 256) col[gstart + i] = lstage[i];
}

// ---------------- GEMM: hs = dinv[row] * (x @ W.T) ----------------
template<int OUT, bool BF16OUT>
__global__ __launch_bounds__(256) void k_gemm(const float* __restrict__ x,
                                              const float* __restrict__ W,
                                              const float* __restrict__ dinv,
                                              void* __restrict__ hout) {
  __shared__ float wlds[128 * 68];
  __shared__ float xlds[128 * 33];
  const int tid = threadIdx.x;
  const int cg = tid & 15;
  const int rg = tid >> 4;
  const int obase = blockIdx.y * 64;
  for (int idx = tid; idx < 64 * 32; idx += 256) {
    int o = idx >> 5;
    int k4 = (idx & 31) << 2;
    const float4 wv = *(const float4*)(W + (size_t)(obase + o) * 128 + k4);
    wlds[(k4 + 0) * 68 + o] = wv.x;
    wlds[(k4 + 1) * 68 + o] = wv.y;
    wlds[(k4 + 2) * 68 + o] = wv.z;
    wlds[(k4 + 3) * 68 + o] = wv.w;
  }
  for (int tile = blockIdx.x; tile < N_NODES / 32; tile += gridDim.x) {
    const int row0 = tile * 32;
    __syncthreads();
    for (int idx = tid; idx < 32 * 32; idx += 256) {
      int r = idx >> 5;
      int k4 = (idx & 31) << 2;
      const float4 xv = *(const float4*)(x + (size_t)(row0 + r) * 128 + k4);
      xlds[(k4 + 0) * 33 + r] = xv.x;
      xlds[(k4 + 1) * 33 + r] = xv.y;
      xlds[(k4 + 2) * 33 + r] = xv.z;
      xlds[(k4 + 3) * 33 + r] = xv.w;
    }
    __syncthreads();
    float a00 = 0, a01 = 0, a02 = 0, a03 = 0;
    float a10 = 0, a11 = 0, a12 = 0, a13 = 0;
#pragma unroll 4
    for (int k = 0; k < 128; ++k) {
      const float4 wv = *(const float4*)(wlds + k * 68 + cg * 4);
      const float x0 = xlds[k * 33 + rg * 2 + 0];
      const float x1 = xlds[k * 33 + rg * 2 + 1];
      a00 = fmaf(x0, wv.x, a00); a01 = fmaf(x0, wv.y, a01);
      a02 = fmaf(x0, wv.z, a02); a03 = fmaf(x0, wv.w, a03);
      a10 = fmaf(x1, wv.x, a10); a11 = fmaf(x1, wv.y, a11);
      a12 = fmaf(x1, wv.z, a12); a13 = fmaf(x1, wv.w, a13);
    }
    const float dv0 = dinv[row0 + rg * 2 + 0];
    const float dv1 = dinv[row0 + rg * 2 + 1];
    if (BF16OUT) {
      uint32_t* hp = (uint32_t*)hout + (size_t)(row0 + rg * 2) * (OUT / 2) + obase / 2 + cg * 2;
      *(uint2*)hp = make_uint2(pack_bf16x2(a00 * dv0, a01 * dv0), pack_bf16x2(a02 * dv0, a03 * dv0));
      *(uint2*)(hp + OUT / 2) = make_uint2(pack_bf16x2(a10 * dv1, a11 * dv1), pack_bf16x2(a12 * dv1, a13 * dv1));
    } else {
      float* hp = (float*)hout + (size_t)(row0 + rg * 2) * OUT + obase + cg * 4;
      *(float4*)hp = make_float4(a00 * dv0, a01 * dv0, a02 * dv0, a03 * dv0);
      *(float4*)(hp + OUT) = make_float4(a10 * dv1, a11 * dv1, a12 * dv1, a13 * dv1);
    }
  }
}

// ---------------- aggregation: out[i] = di*(sum_c hs[c] + hs[i]) + b ----------------
// Paired-edge layout: lanes 0-31 even edges, 32-63 odd edges; each 32-lane half
// reads a full 256B row as uint2 (2 rows in flight per instr); 4 cols/lane fp32 acc;
// halves combined via shfl_xor(32).
template<bool RELU>
__global__ __launch_bounds__(256) void k_agg128(const uint32_t* __restrict__ hs,
                                                const float* __restrict__ dinv,
                                                const int* __restrict__ rowptr,
                                                const int* __restrict__ col,
                                                const float* __restrict__ bias,
                                                float* __restrict__ out) {
  const int lane = threadIdx.x & 63;
  const int half = lane >> 5;   // 0 = even edges, 1 = odd edges
  const int w = lane & 31;      // uint2 index: cols {4w..4w+3}
  const int node = blockIdx.x * 4 + (threadIdx.x >> 6);
  if (node >= N_NODES) return;
  const int e0 = rowptr[node], e1 = rowptr[node + 1];
  const uint2* hp = (const uint2*)hs;   // row = 32 uint2
  float a0 = 0.f, a1 = 0.f, a2 = 0.f, a3 = 0.f;
  if (half == 0) {  // self-loop counted once
    const uint2 us = hp[(size_t)node * 32 + w];
    a0 = bf16lo(us.x); a1 = bf16hi(us.x); a2 = bf16lo(us.y); a3 = bf16hi(us.y);
  }
  for (int eb = e0; eb < e1; eb += 64) {
    const int n = min(64, e1 - eb);
    const int ce = col[min(eb + lane, e1 - 1)];
    const int hn = (n + 1) >> 1;
#pragma unroll 4
    for (int j = 0; j < hn; ++j) {
      const int idx = 2 * j + half;
      const int c = __shfl(ce, idx);
      if (idx < n) {
        const uint2 u = hp[(size_t)c * 32 + w];
        a0 += bf16lo(u.x); a1 += bf16hi(u.x);
        a2 += bf16lo(u.y); a3 += bf16hi(u.y);
      }
    }
  }
  a0 += __shfl_xor(a0, 32); a1 += __shfl_xor(a1, 32);
  a2 += __shfl_xor(a2, 32); a3 += __shfl_xor(a3, 32);
  if (half == 0) {
    const float di = dinv[node];
    const float4 bv = ((const float4*)bias)[w];
    float o0 = di * a0 + bv.x, o1 = di * a1 + bv.y;
    float o2 = di * a2 + bv.z, o3 = di * a3 + bv.w;
    if (RELU) {
      o0 = fmaxf(o0, 0.f); o1 = fmaxf(o1, 0.f);
      o2 = fmaxf(o2, 0.f); o3 = fmaxf(o3, 0.f);
    }
    ((float4*)out)[(size_t)node * 32 + w] = make_float4(o0, o1, o2, o3);
  }
}

// Final layer: quad-edge layout (lane quarter q handles edges 4j+q); each 16-lane
// quarter reads a full 128B row as uint2; combine via shfl_xor(32),(16);
// fused bias + log_softmax (4 cols/lane over 16 lanes).
__global__ __launch_bounds__(256) void k_agg64_lsm(const uint32_t* __restrict__ hs,
                                                   const float* __restrict__ dinv,
                                                   const int* __restrict__ rowptr,
                                                   const int* __restrict__ col,
                                                   const float* __restrict__ bias,
                                                   float* __restrict__ out) {
  const int lane = threadIdx.x & 63;
  const int q = lane >> 4;      // edge sub-slot 0..3
  const int t = lane & 15;      // uint2 index: cols {4t..4t+3}
  const int node = blockIdx.x * 4 + (threadIdx.x >> 6);
  if (node >= N_NODES) return;
  const int e0 = rowptr[node], e1 = rowptr[node + 1];
  const uint2* hp = (const uint2*)hs;   // row = 16 uint2
  float a0 = 0.f, a1 = 0.f, a2 = 0.f, a3 = 0.f;
  if (q == 0) {  // self-loop counted once
    const uint2 us = hp[(size_t)node * 16 + t];
    a0 = bf16lo(us.x); a1 = bf16hi(us.x); a2 = bf16lo(us.y); a3 = bf16hi(us.y);
  }
  for (int eb = e0; eb < e1; eb += 64) {
    const int n = min(64, e1 - eb);
    const int ce = col[min(eb + lane, e1 - 1)];
    const int qn = (n + 3) >> 2;
#pragma unroll 4
    for (int j = 0; j < qn; ++j) {
      const int idx = 4 * j + q;
      const int c = __shfl(ce, idx);
      if (idx < n) {
        const uint2 u = hp[(size_t)c * 16 + t];
        a0 += bf16lo(u.x); a1 += bf16hi(u.x);
        a2 += bf16lo(u.y); a3 += bf16hi(u.y);
      }
    }
  }
  a0 += __shfl_xor(a0, 32); a1 += __shfl_xor(a1, 32);
  a2 += __shfl_xor(a2, 32); a3 += __shfl_xor(a3, 32);
  a0 += __shfl_xor(a0, 16); a1 += __shfl_xor(a1, 16);
  a2 += __shfl_xor(a2, 16); a3 += __shfl_xor(a3, 16);
  const float di = dinv[node];
  const float4 bv = ((const float4*)bias)[t];
  const float v0 = di * a0 + bv.x;
  const float v1 = di * a1 + bv.y;
  const float v2 = di * a2 + bv.z;
  const float v3 = di * a3 + bv.w;
  float m = fmaxf(fmaxf(v0, v1), fmaxf(v2, v3));
#pragma unroll
  for (int off = 8; off > 0; off >>= 1) m = fmaxf(m, __shfl_xor(m, off));
  float s = __expf(v0 - m) + __expf(v1 - m) + __expf(v2 - m) + __expf(v3 - m);
#pragma unroll
  for (int off = 8; off > 0; off >>= 1) s += __shfl_xor(s, off);
  const float ls = m + __logf(s);
  if (q == 0)
    ((float4*)out)[(size_t)node * 16 + t] = make_float4(v0 - ls, v1 - ls, v2 - ls, v3 - ls);
}

// ---------------- launch ----------------

extern "C" void kernel_launch(void* const* d_in, const int* in_sizes, int n_in,
                              void* d_out, int out_size, void* d_ws, size_t ws_size,
                              hipStream_t stream) {
  const float* x  = (const float*)d_in[0];
  const int*   ei = (const int*)d_in[1];
  const float* W0 = (const float*)d_in[2];
  const float* b0 = (const float*)d_in[3];
  const float* W1 = (const float*)d_in[4];
  const float* b1 = (const float*)d_in[5];
  const float* W2 = (const float*)d_in[6];
  const float* b2 = (const float*)d_in[7];
  float* outp = (float*)d_out;

  char* p = (char*)d_ws;
  int*   deg     = (int*)p;   p += alup((size_t)N_NODES * 4);
  float* dinv    = (float*)p; p += alup((size_t)N_NODES * 4);
  int*   rowptr  = (int*)p;   p += alup((size_t)(N_NODES + 1) * 4);
  int*   bcursor = (int*)p;   p += alup((size_t)NBUK * 4);
  int*   bsum    = (int*)p;   p += alup((size_t)NBUK * 4);
  int*   bbase   = (int*)p;   p += alup((size_t)(NBUK + 1) * 4);
  int*   col     = (int*)p;   p += alup((size_t)2 * N_EDGES * 4);
  float* bufA    = (float*)p; p += alup((size_t)N_NODES * 128 * 4);
  float* bufB    = (float*)p;
  uint32_t* ebuf = (uint32_t*)bufA;       // pass-1 staging aliases bufA
  uint32_t* h16  = (uint32_t*)bufA;       // bf16x2 gemm output (all layers)

  hipMemsetAsync(deg, 0, (size_t)N_NODES * 4, stream);
  k_deg<<<(N_EDGES + 255) / 256, 256, 0, stream>>>(ei, deg);
  k_dinv<<<(N_NODES + 255) / 256, 256, 0, stream>>>(deg, dinv);
  k_scan1<<<NBUK, 256, 0, stream>>>(deg, rowptr, bsum);
  k_scan2<<<1, 512, 0, stream>>>(bsum, bbase);
  k_scan3<<<NBUK, 256, 0, stream>>>(rowptr, bbase, bcursor);
  k_bin<<<(2 * N_EDGES + CHUNK - 1) / CHUNK, 256, 0, stream>>>(ei, bcursor, ebuf);
  k_csr<<<NBUK, 256, 0, stream>>>(ebuf, rowptr, col);

  dim3 g128(640, 2), g64(640, 1);
  k_gemm<128, true><<<g128, 256, 0, stream>>>(x, W0, dinv, h16);
  k_agg128<true><<<N_NODES / 4, 256, 0, stream>>>(h16, dinv, rowptr, col, b0, bufB);
  k_gemm<128, true><<<g128, 256, 0, stream>>>(bufB, W1, dinv, h16);
  k_agg128<true><<<N_NODES / 4, 256, 0, stream>>>(h16, dinv, rowptr, col, b1, bufB);
  k_gemm<64, true><<<g64, 256, 0, stream>>>(bufB, W2, dinv, h16);
  k_agg64_lsm<<<N_NODES / 4, 256, 0, stream>>>(h16, dinv, rowptr, col, b2, outp);
}

// Round 9
// 699.063 us; speedup vs baseline: 1.8483x; 1.1544x over previous
//
#include <hip/hip_runtime.h>
#include <hip/hip_bf16.h>
#include <cstdint>

#define N_NODES 100000
#define N_EDGES 1600000
#define NBUK 391   // ceil(N_NODES / 256) buckets of 256 dst nodes
#define CHUNK 4096
#define MAXB 10240 // LDS staging capacity per bucket (mean 8192, +22σ)
#define NSB 16     // src super-buckets: src>>13 in [0,13)

static inline size_t alup(size_t x) { return (x + 255) & ~(size_t)255; }

static __device__ __forceinline__ uint32_t pack_bf16x2(float a, float b) {
  uint32_t ua = __float_as_uint(a); ua += 0x7FFF + ((ua >> 16) & 1);
  uint32_t ub = __float_as_uint(b); ub += 0x7FFF + ((ub >> 16) & 1);
  return (ua >> 16) | (ub & 0xFFFF0000u);
}
static __device__ __forceinline__ float bf16lo(uint32_t u) { return __uint_as_float(u << 16); }
static __device__ __forceinline__ float bf16hi(uint32_t u) { return __uint_as_float(u & 0xFFFF0000u); }

// ---------------- prep kernels ----------------

// Coarse histogram: LDS per-block, one global atomic per (block,bucket).
// Replaces per-edge global atomics (k_deg) -> no L2-line bouncing.
__global__ __launch_bounds__(256) void k_hist(const int* __restrict__ ei,
                                              int* __restrict__ bukcnt) {
  __shared__ int hist[NBUK];
  const int tid = threadIdx.x;
  const int base = blockIdx.x * CHUNK;
  const int n = min(CHUNK, 2 * N_EDGES - base);
  for (int i = tid; i < NBUK; i += 256) hist[i] = 0;
  __syncthreads();
  for (int i = tid; i < n; i += 256) {
    const int e = base + i;
    const int dst = (e < N_EDGES) ? ei[N_EDGES + e] : ei[e - N_EDGES];
    atomicAdd(&hist[dst >> 8], 1);
  }
  __syncthreads();
  for (int i = tid; i < NBUK; i += 256)
    if (hist[i]) atomicAdd(&bukcnt[i], hist[i]);
}

// Scan 391 bucket totals -> exclusive bbase[0..NBUK].
__global__ __launch_bounds__(512) void k_scan2(const int* __restrict__ bsum,
                                               int* __restrict__ bbase) {
  const int tid = threadIdx.x;
  const int v = (tid < NBUK) ? bsum[tid] : 0;
  int incl = v;
#pragma unroll
  for (int off = 1; off < 64; off <<= 1) {
    const int u = __shfl_up(incl, off);
    if ((tid & 63) >= off) incl += u;
  }
  __shared__ int wsum[8];
  if ((tid & 63) == 63) wsum[tid >> 6] = incl;
  __syncthreads();
  const int wid = tid >> 6;
  int add = 0;
#pragma unroll
  for (int k = 0; k < 7; ++k)
    if (k < wid) add += wsum[k];
  incl += add;
  if (tid < NBUK) bbase[tid] = incl - v;
  if (tid == NBUK - 1) bbase[NBUK] = incl;  // = 2*N_EDGES
}

__global__ __launch_bounds__(256) void k_binit(const int* __restrict__ bbase,
                                               int* __restrict__ bcursor,
                                               int* __restrict__ rowptr) {
  int b = blockIdx.x * 256 + threadIdx.x;
  if (b < NBUK) bcursor[b] = bbase[b];
  if (b == 0) rowptr[N_NODES] = 2 * N_EDGES;
}

// Pass 1: multisplit edges into 391 coarse dst-buckets with coalesced writes.
// payload pack = (dst&255)<<17 | src   (src < 2^17)
__global__ __launch_bounds__(256) void k_bin(const int* __restrict__ ei,
                                             int* __restrict__ bcursor,
                                             uint32_t* __restrict__ ebuf) {
  __shared__ int hist[NBUK];
  __shared__ int excl[NBUK + 1];
  __shared__ int gbase[NBUK];
  __shared__ uint32_t stage[CHUNK];
  const int tid = threadIdx.x;
  const int base = blockIdx.x * CHUNK;
  const int n = min(CHUNK, 2 * N_EDGES - base);
  for (int i = tid; i < NBUK; i += 256) hist[i] = 0;
  __syncthreads();
  uint32_t pk[16]; int bk[16]; int rk[16];
#pragma unroll
  for (int i = 0; i < 16; ++i) {
    const int li = i * 256 + tid;
    bk[i] = -1;
    if (li < n) {
      const int e = base + li;
      const int src = ei[e];
      const int dst = (e < N_EDGES) ? ei[N_EDGES + e] : ei[e - N_EDGES];
      bk[i] = dst >> 8;
      pk[i] = ((uint32_t)(dst & 255) << 17) | (uint32_t)src;
      rk[i] = atomicAdd(&hist[bk[i]], 1);
    }
  }
  __syncthreads();
  if (tid < 64) {
    int c[7]; int s = 0;
#pragma unroll
    for (int j = 0; j < 7; ++j) {
      const int b = tid * 7 + j;
      c[j] = (b < NBUK) ? hist[b] : 0;
      s += c[j];
    }
    int incl = s;
#pragma unroll
    for (int off = 1; off < 64; off <<= 1) {
      const int v = __shfl_up(incl, off);
      if (tid >= off) incl += v;
    }
    int run = incl - s;
#pragma unroll
    for (int j = 0; j < 7; ++j) {
      const int b = tid * 7 + j;
      if (b < NBUK) {
        excl[b] = run;
        gbase[b] = atomicAdd(&bcursor[b], c[j]);
        run += c[j];
      }
    }
    if (tid == 63) excl[NBUK] = incl;
  }
  __syncthreads();
#pragma unroll
  for (int i = 0; i < 16; ++i)
    if (bk[i] >= 0) stage[excl[bk[i]] + rk[i]] = pk[i];
  __syncthreads();
  for (int i = tid; i < n; i += 256) {
    int lo = 0, hi = NBUK - 1;
#pragma unroll
    for (int it = 0; it < 9; ++it) {
      const int mid = (lo + hi + 1) >> 1;
      if (excl[mid] <= i) lo = mid; else hi = mid - 1;
    }
    ebuf[gbase[lo] + (i - excl[lo])] = stage[i];
  }
}

// Pass 2: one workgroup per bucket. Derives per-node degree from its own histogram
// (writes rowptr + dinv as side outputs), counting sort by (dst_local, src>>13),
// coalesced CSR writeback.
__global__ __launch_bounds__(256) void k_csr(const uint32_t* __restrict__ ebuf,
                                             const int* __restrict__ bbase,
                                             int* __restrict__ col,
                                             int* __restrict__ rowptr,
                                             float* __restrict__ dinv) {
  __shared__ int cnt[256 * NSB];   // 16 KB
  __shared__ int lstage[MAXB];     // 40 KB
  __shared__ int wsum[4];
  const int b = blockIdx.x;
  const int node0 = b << 8;
  const int gstart = bbase[b];
  const int total = bbase[b + 1] - gstart;
  const int tid = threadIdx.x;
  for (int i = tid; i < 256 * NSB; i += 256) cnt[i] = 0;
  __syncthreads();
  for (int i = tid; i < total; i += 256) {
    const uint32_t pk = ebuf[gstart + i];
    atomicAdd(&cnt[(pk >> 17) * NSB + ((pk & 0x1FFFF) >> 13)], 1);
  }
  __syncthreads();
  // per-node degree + block exclusive scan (thread tid owns node node0+tid)
  int nodetotal = 0;
#pragma unroll
  for (int s = 0; s < NSB; ++s) nodetotal += cnt[tid * NSB + s];
  int incl = nodetotal;
#pragma unroll
  for (int off = 1; off < 64; off <<= 1) {
    const int u = __shfl_up(incl, off);
    if ((tid & 63) >= off) incl += u;
  }
  if ((tid & 63) == 63) wsum[tid >> 6] = incl;
  __syncthreads();
  const int wid = tid >> 6;
  int add = 0;
#pragma unroll
  for (int k = 0; k < 3; ++k)
    if (k < wid) add += wsum[k];
  incl += add;
  const int prefix = incl - nodetotal;
  const int node = node0 + tid;
  if (node < N_NODES) {
    rowptr[node] = gstart + prefix;
    dinv[node] = rsqrtf((float)(nodetotal + 1));  // +1 self loop
  }
  {
    int run = prefix;
#pragma unroll
    for (int s = 0; s < NSB; ++s) {
      const int c = cnt[tid * NSB + s];
      cnt[tid * NSB + s] = run;
      run += c;
    }
  }
  __syncthreads();
  for (int i = tid; i < total; i += 256) {
    const uint32_t pk = ebuf[gstart + i];
    const int src = pk & 0x1FFFF;
    const int p = atomicAdd(&cnt[(pk >> 17) * NSB + (src >> 13)], 1);
    if (p < MAXB) lstage[p] = src;
    else col[gstart + p] = src;  // overflow fallback (statistically never)
  }
  __syncthreads();
  const int m = min(total, MAXB);
  for (int i = tid; i < m; i += 256) col[gstart + i] = lstage[i];
}

// ---------------- GEMM: hs = dinv[row] * (x @ W.T) ----------------
template<int OUT, bool BF16OUT>
__global__ __launch_bounds__(256) void k_gemm(const float* __restrict__ x,
                                              const float* __restrict__ W,
                                              const float* __restrict__ dinv,
                                              void* __restrict__ hout) {
  __shared__ float wlds[128 * 68];
  __shared__ float xlds[128 * 33];
  const int tid = threadIdx.x;
  const int cg = tid & 15;
  const int rg = tid >> 4;
  const int obase = blockIdx.y * 64;
  for (int idx = tid; idx < 64 * 32; idx += 256) {
    int o = idx >> 5;
    int k4 = (idx & 31) << 2;
    const float4 wv = *(const float4*)(W + (size_t)(obase + o) * 128 + k4);
    wlds[(k4 + 0) * 68 + o] = wv.x;
    wlds[(k4 + 1) * 68 + o] = wv.y;
    wlds[(k4 + 2) * 68 + o] = wv.z;
    wlds[(k4 + 3) * 68 + o] = wv.w;
  }
  for (int tile = blockIdx.x; tile < N_NODES / 32; tile += gridDim.x) {
    const int row0 = tile * 32;
    __syncthreads();
    for (int idx = tid; idx < 32 * 32; idx += 256) {
      int r = idx >> 5;
      int k4 = (idx & 31) << 2;
      const float4 xv = *(const float4*)(x + (size_t)(row0 + r) * 128 + k4);
      xlds[(k4 + 0) * 33 + r] = xv.x;
      xlds[(k4 + 1) * 33 + r] = xv.y;
      xlds[(k4 + 2) * 33 + r] = xv.z;
      xlds[(k4 + 3) * 33 + r] = xv.w;
    }
    __syncthreads();
    float a00 = 0, a01 = 0, a02 = 0, a03 = 0;
    float a10 = 0, a11 = 0, a12 = 0, a13 = 0;
#pragma unroll 4
    for (int k = 0; k < 128; ++k) {
      const float4 wv = *(const float4*)(wlds + k * 68 + cg * 4);
      const float x0 = xlds[k * 33 + rg * 2 + 0];
      const float x1 = xlds[k * 33 + rg * 2 + 1];
      a00 = fmaf(x0, wv.x, a00); a01 = fmaf(x0, wv.y, a01);
      a02 = fmaf(x0, wv.z, a02); a03 = fmaf(x0, wv.w, a03);
      a10 = fmaf(x1, wv.x, a10); a11 = fmaf(x1, wv.y, a11);
      a12 = fmaf(x1, wv.z, a12); a13 = fmaf(x1, wv.w, a13);
    }
    const float dv0 = dinv[row0 + rg * 2 + 0];
    const float dv1 = dinv[row0 + rg * 2 + 1];
    if (BF16OUT) {
      uint32_t* hp = (uint32_t*)hout + (size_t)(row0 + rg * 2) * (OUT / 2) + obase / 2 + cg * 2;
      *(uint2*)hp = make_uint2(pack_bf16x2(a00 * dv0, a01 * dv0), pack_bf16x2(a02 * dv0, a03 * dv0));
      *(uint2*)(hp + OUT / 2) = make_uint2(pack_bf16x2(a10 * dv1, a11 * dv1), pack_bf16x2(a12 * dv1, a13 * dv1));
    } else {
      float* hp = (float*)hout + (size_t)(row0 + rg * 2) * OUT + obase + cg * 4;
      *(float4*)hp = make_float4(a00 * dv0, a01 * dv0, a02 * dv0, a03 * dv0);
      *(float4*)(hp + OUT) = make_float4(a10 * dv1, a11 * dv1, a12 * dv1, a13 * dv1);
    }
  }
}

// ---------------- aggregation: out[i] = di*(sum_c hs[c] + hs[i]) + b ----------------
// Paired-edge layout: lanes 0-31 even edges, 32-63 odd edges; each 32-lane half
// reads a full 256B row as uint2 (2 rows in flight per instr); 4 cols/lane fp32 acc;
// halves combined via shfl_xor(32).
template<bool RELU>
__global__ __launch_bounds__(256) void k_agg128(const uint32_t* __restrict__ hs,
                                                const float* __restrict__ dinv,
                                                const int* __restrict__ rowptr,
                                                const int* __restrict__ col,
                                                const float* __restrict__ bias,
                                                float* __restrict__ out) {
  const int lane = threadIdx.x & 63;
  const int half = lane >> 5;   // 0 = even edges, 1 = odd edges
  const int w = lane & 31;      // uint2 index: cols {4w..4w+3}
  const int node = blockIdx.x * 4 + (threadIdx.x >> 6);
  if (node >= N_NODES) return;
  const int e0 = rowptr[node], e1 = rowptr[node + 1];
  const uint2* hp = (const uint2*)hs;   // row = 32 uint2
  float a0 = 0.f, a1 = 0.f, a2 = 0.f, a3 = 0.f;
  if (half == 0) {  // self-loop counted once
    const uint2 us = hp[(size_t)node * 32 + w];
    a0 = bf16lo(us.x); a1 = bf16hi(us.x); a2 = bf16lo(us.y); a3 = bf16hi(us.y);
  }
  for (int eb = e0; eb < e1; eb += 64) {
    const int n = min(64, e1 - eb);
    const int ce = col[min(eb + lane, e1 - 1)];
    const int hn = (n + 1) >> 1;
#pragma unroll 4
    for (int j = 0; j < hn; ++j) {
      const int idx = 2 * j + half;
      const int c = __shfl(ce, idx);
      if (idx < n) {
        const uint2 u = hp[(size_t)c * 32 + w];
        a0 += bf16lo(u.x); a1 += bf16hi(u.x);
        a2 += bf16lo(u.y); a3 += bf16hi(u.y);
      }
    }
  }
  a0 += __shfl_xor(a0, 32); a1 += __shfl_xor(a1, 32);
  a2 += __shfl_xor(a2, 32); a3 += __shfl_xor(a3, 32);
  if (half == 0) {
    const float di = dinv[node];
    const float4 bv = ((const float4*)bias)[w];
    float o0 = di * a0 + bv.x, o1 = di * a1 + bv.y;
    float o2 = di * a2 + bv.z, o3 = di * a3 + bv.w;
    if (RELU) {
      o0 = fmaxf(o0, 0.f); o1 = fmaxf(o1, 0.f);
      o2 = fmaxf(o2, 0.f); o3 = fmaxf(o3, 0.f);
    }
    ((float4*)out)[(size_t)node * 32 + w] = make_float4(o0, o1, o2, o3);
  }
}

// Final layer: quad-edge layout (lane quarter q handles edges 4j+q); each 16-lane
// quarter reads a full 128B row as uint2; combine via shfl_xor(32),(16);
// fused bias + log_softmax (4 cols/lane over 16 lanes).
__global__ __launch_bounds__(256) void k_agg64_lsm(const uint32_t* __restrict__ hs,
                                                   const float* __restrict__ dinv,
                                                   const int* __restrict__ rowptr,
                                                   const int* __restrict__ col,
                                                   const float* __restrict__ bias,
                                                   float* __restrict__ out) {
  const int lane = threadIdx.x & 63;
  const int q = lane >> 4;      // edge sub-slot 0..3
  const int t = lane & 15;      // uint2 index: cols {4t..4t+3}
  const int node = blockIdx.x * 4 + (threadIdx.x >> 6);
  if (node >= N_NODES) return;
  const int e0 = rowptr[node], e1 = rowptr[node + 1];
  const uint2* hp = (const uint2*)hs;   // row = 16 uint2
  float a0 = 0.f, a1 = 0.f, a2 = 0.f, a3 = 0.f;
  if (q == 0) {  // self-loop counted once
    const uint2 us = hp[(size_t)node * 16 + t];
    a0 = bf16lo(us.x); a1 = bf16hi(us.x); a2 = bf16lo(us.y); a3 = bf16hi(us.y);
  }
  for (int eb = e0; eb < e1; eb += 64) {
    const int n = min(64, e1 - eb);
    const int ce = col[min(eb + lane, e1 - 1)];
    const int qn = (n + 3) >> 2;
#pragma unroll 4
    for (int j = 0; j < qn; ++j) {
      const int idx = 4 * j + q;
      const int c = __shfl(ce, idx);
      if (idx < n) {
        const uint2 u = hp[(size_t)c * 16 + t];
        a0 += bf16lo(u.x); a1 += bf16hi(u.x);
        a2 += bf16lo(u.y); a3 += bf16hi(u.y);
      }
    }
  }
  a0 += __shfl_xor(a0, 32); a1 += __shfl_xor(a1, 32);
  a2 += __shfl_xor(a2, 32); a3 += __shfl_xor(a3, 32);
  a0 += __shfl_xor(a0, 16); a1 += __shfl_xor(a1, 16);
  a2 += __shfl_xor(a2, 16); a3 += __shfl_xor(a3, 16);
  const float di = dinv[node];
  const float4 bv = ((const float4*)bias)[t];
  const float v0 = di * a0 + bv.x;
  const float v1 = di * a1 + bv.y;
  const float v2 = di * a2 + bv.z;
  const float v3 = di * a3 + bv.w;
  float m = fmaxf(fmaxf(v0, v1), fmaxf(v2, v3));
#pragma unroll
  for (int off = 8; off > 0; off >>= 1) m = fmaxf(m, __shfl_xor(m, off));
  float s = __expf(v0 - m) + __expf(v1 - m) + __expf(v2 - m) + __expf(v3 - m);
#pragma unroll
  for (int off = 8; off > 0; off >>= 1) s += __shfl_xor(s, off);
  const float ls = m + __logf(s);
  if (q == 0)
    ((float4*)out)[(size_t)node * 16 + t] = make_float4(v0 - ls, v1 - ls, v2 - ls, v3 - ls);
}

// ---------------- launch ----------------

extern "C" void kernel_launch(void* const* d_in, const int* in_sizes, int n_in,
                              void* d_out, int out_size, void* d_ws, size_t ws_size,
                              hipStream_t stream) {
  const float* x  = (const float*)d_in[0];
  const int*   ei = (const int*)d_in[1];
  const float* W0 = (const float*)d_in[2];
  const float* b0 = (const float*)d_in[3];
  const float* W1 = (const float*)d_in[4];
  const float* b1 = (const float*)d_in[5];
  const float* W2 = (const float*)d_in[6];
  const float* b2 = (const float*)d_in[7];
  float* outp = (float*)d_out;

  char* p = (char*)d_ws;
  float* dinv    = (float*)p; p += alup((size_t)N_NODES * 4);
  int*   rowptr  = (int*)p;   p += alup((size_t)(N_NODES + 1) * 4);
  int*   bcursor = (int*)p;   p += alup((size_t)NBUK * 4);
  int*   bukcnt  = (int*)p;   p += alup((size_t)NBUK * 4);
  int*   bbase   = (int*)p;   p += alup((size_t)(NBUK + 1) * 4);
  int*   col     = (int*)p;   p += alup((size_t)2 * N_EDGES * 4);
  float* bufA    = (float*)p; p += alup((size_t)N_NODES * 128 * 4);
  float* bufB    = (float*)p;
  uint32_t* ebuf = (uint32_t*)bufA;       // pass-1 staging aliases bufA
  uint32_t* h16  = (uint32_t*)bufA;       // bf16x2 gemm output (all layers)

  hipMemsetAsync(bukcnt, 0, (size_t)NBUK * 4, stream);
  k_hist<<<(2 * N_EDGES + CHUNK - 1) / CHUNK, 256, 0, stream>>>(ei, bukcnt);
  k_scan2<<<1, 512, 0, stream>>>(bukcnt, bbase);
  k_binit<<<(NBUK + 255) / 256, 256, 0, stream>>>(bbase, bcursor, rowptr);
  k_bin<<<(2 * N_EDGES + CHUNK - 1) / CHUNK, 256, 0, stream>>>(ei, bcursor, ebuf);
  k_csr<<<NBUK, 256, 0, stream>>>(ebuf, bbase, col, rowptr, dinv);

  dim3 g128(640, 2), g64(640, 1);
  k_gemm<128, true><<<g128, 256, 0, stream>>>(x, W0, dinv, h16);
  k_agg128<true><<<N_NODES / 4, 256, 0, stream>>>(h16, dinv, rowptr, col, b0, bufB);
  k_gemm<128, true><<<g128, 256, 0, stream>>>(bufB, W1, dinv, h16);
  k_agg128<true><<<N_NODES / 4, 256, 0, stream>>>(h16, dinv, rowptr, col, b1, bufB);
  k_gemm<64, true><<<g64, 256, 0, stream>>>(bufB, W2, dinv, h16);
  k_agg64_lsm<<<N_NODES / 4, 256, 0, stream>>>(h16, dinv, rowptr, col, b2, outp);
}

// Round 10
// 695.202 us; speedup vs baseline: 1.8586x; 1.0056x over previous
//
#include <hip/hip_runtime.h>
#include <hip/hip_bf16.h>
#include <cstdint>

#define N_NODES 100000
#define N_EDGES 1600000
#define NBUK 391   // ceil(N_NODES / 256) buckets of 256 dst nodes
#define CHUNK 4096
#define MAXB 10240 // LDS staging capacity per bucket (mean 8192, +22σ)
#define NSB 16     // src super-buckets: src>>13 in [0,13)

static inline size_t alup(size_t x) { return (x + 255) & ~(size_t)255; }

static __device__ __forceinline__ uint32_t pack_bf16x2(float a, float b) {
  uint32_t ua = __float_as_uint(a); ua += 0x7FFF + ((ua >> 16) & 1);
  uint32_t ub = __float_as_uint(b); ub += 0x7FFF + ((ub >> 16) & 1);
  return (ua >> 16) | (ub & 0xFFFF0000u);
}
static __device__ __forceinline__ float bf16lo(uint32_t u) { return __uint_as_float(u << 16); }
static __device__ __forceinline__ float bf16hi(uint32_t u) { return __uint_as_float(u & 0xFFFF0000u); }

// ---------------- prep kernels ----------------

// Coarse histogram: LDS per-block, one global atomic per (block,bucket).
__global__ __launch_bounds__(256) void k_hist(const int* __restrict__ ei,
                                              int* __restrict__ bukcnt) {
  __shared__ int hist[NBUK];
  const int tid = threadIdx.x;
  const int base = blockIdx.x * CHUNK;
  const int n = min(CHUNK, 2 * N_EDGES - base);
  for (int i = tid; i < NBUK; i += 256) hist[i] = 0;
  __syncthreads();
  for (int i = tid; i < n; i += 256) {
    const int e = base + i;
    const int dst = (e < N_EDGES) ? ei[N_EDGES + e] : ei[e - N_EDGES];
    atomicAdd(&hist[dst >> 8], 1);
  }
  __syncthreads();
  for (int i = tid; i < NBUK; i += 256)
    if (hist[i]) atomicAdd(&bukcnt[i], hist[i]);
}

// Scan 391 bucket totals -> exclusive bbase[0..NBUK].
__global__ __launch_bounds__(512) void k_scan2(const int* __restrict__ bsum,
                                               int* __restrict__ bbase) {
  const int tid = threadIdx.x;
  const int v = (tid < NBUK) ? bsum[tid] : 0;
  int incl = v;
#pragma unroll
  for (int off = 1; off < 64; off <<= 1) {
    const int u = __shfl_up(incl, off);
    if ((tid & 63) >= off) incl += u;
  }
  __shared__ int wsum[8];
  if ((tid & 63) == 63) wsum[tid >> 6] = incl;
  __syncthreads();
  const int wid = tid >> 6;
  int add = 0;
#pragma unroll
  for (int k = 0; k < 7; ++k)
    if (k < wid) add += wsum[k];
  incl += add;
  if (tid < NBUK) bbase[tid] = incl - v;
  if (tid == NBUK - 1) bbase[NBUK] = incl;  // = 2*N_EDGES
}

__global__ __launch_bounds__(256) void k_binit(const int* __restrict__ bbase,
                                               int* __restrict__ bcursor,
                                               int* __restrict__ rowptr) {
  int b = blockIdx.x * 256 + threadIdx.x;
  if (b < NBUK) bcursor[b] = bbase[b];
  if (b == 0) rowptr[N_NODES] = 2 * N_EDGES;
}

// Pass 1: multisplit edges into 391 coarse dst-buckets with coalesced writes.
// payload pack = (dst&255)<<17 | src   (src < 2^17)
__global__ __launch_bounds__(256) void k_bin(const int* __restrict__ ei,
                                             int* __restrict__ bcursor,
                                             uint32_t* __restrict__ ebuf) {
  __shared__ int hist[NBUK];
  __shared__ int excl[NBUK + 1];
  __shared__ int gbase[NBUK];
  __shared__ uint32_t stage[CHUNK];
  const int tid = threadIdx.x;
  const int base = blockIdx.x * CHUNK;
  const int n = min(CHUNK, 2 * N_EDGES - base);
  for (int i = tid; i < NBUK; i += 256) hist[i] = 0;
  __syncthreads();
  uint32_t pk[16]; int bk[16]; int rk[16];
#pragma unroll
  for (int i = 0; i < 16; ++i) {
    const int li = i * 256 + tid;
    bk[i] = -1;
    if (li < n) {
      const int e = base + li;
      const int src = ei[e];
      const int dst = (e < N_EDGES) ? ei[N_EDGES + e] : ei[e - N_EDGES];
      bk[i] = dst >> 8;
      pk[i] = ((uint32_t)(dst & 255) << 17) | (uint32_t)src;
      rk[i] = atomicAdd(&hist[bk[i]], 1);
    }
  }
  __syncthreads();
  if (tid < 64) {
    int c[7]; int s = 0;
#pragma unroll
    for (int j = 0; j < 7; ++j) {
      const int b = tid * 7 + j;
      c[j] = (b < NBUK) ? hist[b] : 0;
      s += c[j];
    }
    int incl = s;
#pragma unroll
    for (int off = 1; off < 64; off <<= 1) {
      const int v = __shfl_up(incl, off);
      if (tid >= off) incl += v;
    }
    int run = incl - s;
#pragma unroll
    for (int j = 0; j < 7; ++j) {
      const int b = tid * 7 + j;
      if (b < NBUK) {
        excl[b] = run;
        gbase[b] = atomicAdd(&bcursor[b], c[j]);
        run += c[j];
      }
    }
    if (tid == 63) excl[NBUK] = incl;
  }
  __syncthreads();
#pragma unroll
  for (int i = 0; i < 16; ++i)
    if (bk[i] >= 0) stage[excl[bk[i]] + rk[i]] = pk[i];
  __syncthreads();
  for (int i = tid; i < n; i += 256) {
    int lo = 0, hi = NBUK - 1;
#pragma unroll
    for (int it = 0; it < 9; ++it) {
      const int mid = (lo + hi + 1) >> 1;
      if (excl[mid] <= i) lo = mid; else hi = mid - 1;
    }
    ebuf[gbase[lo] + (i - excl[lo])] = stage[i];
  }
}

// Pass 2: one workgroup per bucket. Derives per-node degree from its own histogram
// (writes rowptr + dinv), counting sort by (dst_local, src>>13), coalesced writeback.
__global__ __launch_bounds__(256) void k_csr(const uint32_t* __restrict__ ebuf,
                                             const int* __restrict__ bbase,
                                             int* __restrict__ col,
                                             int* __restrict__ rowptr,
                                             float* __restrict__ dinv) {
  __shared__ int cnt[256 * NSB];   // 16 KB
  __shared__ int lstage[MAXB];     // 40 KB
  __shared__ int wsum[4];
  const int b = blockIdx.x;
  const int node0 = b << 8;
  const int gstart = bbase[b];
  const int total = bbase[b + 1] - gstart;
  const int tid = threadIdx.x;
  for (int i = tid; i < 256 * NSB; i += 256) cnt[i] = 0;
  __syncthreads();
  for (int i = tid; i < total; i += 256) {
    const uint32_t pk = ebuf[gstart + i];
    atomicAdd(&cnt[(pk >> 17) * NSB + ((pk & 0x1FFFF) >> 13)], 1);
  }
  __syncthreads();
  int nodetotal = 0;
#pragma unroll
  for (int s = 0; s < NSB; ++s) nodetotal += cnt[tid * NSB + s];
  int incl = nodetotal;
#pragma unroll
  for (int off = 1; off < 64; off <<= 1) {
    const int u = __shfl_up(incl, off);
    if ((tid & 63) >= off) incl += u;
  }
  if ((tid & 63) == 63) wsum[tid >> 6] = incl;
  __syncthreads();
  const int wid = tid >> 6;
  int add = 0;
#pragma unroll
  for (int k = 0; k < 3; ++k)
    if (k < wid) add += wsum[k];
  incl += add;
  const int prefix = incl - nodetotal;
  const int node = node0 + tid;
  if (node < N_NODES) {
    rowptr[node] = gstart + prefix;
    dinv[node] = rsqrtf((float)(nodetotal + 1));  // +1 self loop
  }
  {
    int run = prefix;
#pragma unroll
    for (int s = 0; s < NSB; ++s) {
      const int c = cnt[tid * NSB + s];
      cnt[tid * NSB + s] = run;
      run += c;
    }
  }
  __syncthreads();
  for (int i = tid; i < total; i += 256) {
    const uint32_t pk = ebuf[gstart + i];
    const int src = pk & 0x1FFFF;
    const int p = atomicAdd(&cnt[(pk >> 17) * NSB + (src >> 13)], 1);
    if (p < MAXB) lstage[p] = src;
    else col[gstart + p] = src;  // overflow fallback (statistically never)
  }
  __syncthreads();
  const int m = min(total, MAXB);
  for (int i = tid; i < m; i += 256) col[gstart + i] = lstage[i];
}

// ---------------- GEMM: hs = dinv[row] * (x @ W.T) ----------------
// BF16IN: x is packed bf16x2 (64 words/row, K=128); converted to fp32 in LDS staging.
template<int OUT, bool BF16IN>
__global__ __launch_bounds__(256) void k_gemm(const void* __restrict__ xin,
                                              const float* __restrict__ W,
                                              const float* __restrict__ dinv,
                                              uint32_t* __restrict__ hout) {
  __shared__ float wlds[128 * 68];
  __shared__ float xlds[128 * 33];
  const int tid = threadIdx.x;
  const int cg = tid & 15;
  const int rg = tid >> 4;
  const int obase = blockIdx.y * 64;
  for (int idx = tid; idx < 64 * 32; idx += 256) {
    int o = idx >> 5;
    int k4 = (idx & 31) << 2;
    const float4 wv = *(const float4*)(W + (size_t)(obase + o) * 128 + k4);
    wlds[(k4 + 0) * 68 + o] = wv.x;
    wlds[(k4 + 1) * 68 + o] = wv.y;
    wlds[(k4 + 2) * 68 + o] = wv.z;
    wlds[(k4 + 3) * 68 + o] = wv.w;
  }
  for (int tile = blockIdx.x; tile < N_NODES / 32; tile += gridDim.x) {
    const int row0 = tile * 32;
    __syncthreads();
    if (BF16IN) {
      const uint2* xp = (const uint2*)xin;   // row = 32 uint2 (128 bf16)
      for (int idx = tid; idx < 32 * 32; idx += 256) {
        int r = idx >> 5;
        int w2 = idx & 31;                   // covers cols 4*w2 .. 4*w2+3
        const uint2 u = xp[(size_t)(row0 + r) * 32 + w2];
        xlds[(4 * w2 + 0) * 33 + r] = bf16lo(u.x);
        xlds[(4 * w2 + 1) * 33 + r] = bf16hi(u.x);
        xlds[(4 * w2 + 2) * 33 + r] = bf16lo(u.y);
        xlds[(4 * w2 + 3) * 33 + r] = bf16hi(u.y);
      }
    } else {
      const float* xp = (const float*)xin;
      for (int idx = tid; idx < 32 * 32; idx += 256) {
        int r = idx >> 5;
        int k4 = (idx & 31) << 2;
        const float4 xv = *(const float4*)(xp + (size_t)(row0 + r) * 128 + k4);
        xlds[(k4 + 0) * 33 + r] = xv.x;
        xlds[(k4 + 1) * 33 + r] = xv.y;
        xlds[(k4 + 2) * 33 + r] = xv.z;
        xlds[(k4 + 3) * 33 + r] = xv.w;
      }
    }
    __syncthreads();
    float a00 = 0, a01 = 0, a02 = 0, a03 = 0;
    float a10 = 0, a11 = 0, a12 = 0, a13 = 0;
#pragma unroll 4
    for (int k = 0; k < 128; ++k) {
      const float4 wv = *(const float4*)(wlds + k * 68 + cg * 4);
      const float x0 = xlds[k * 33 + rg * 2 + 0];
      const float x1 = xlds[k * 33 + rg * 2 + 1];
      a00 = fmaf(x0, wv.x, a00); a01 = fmaf(x0, wv.y, a01);
      a02 = fmaf(x0, wv.z, a02); a03 = fmaf(x0, wv.w, a03);
      a10 = fmaf(x1, wv.x, a10); a11 = fmaf(x1, wv.y, a11);
      a12 = fmaf(x1, wv.z, a12); a13 = fmaf(x1, wv.w, a13);
    }
    const float dv0 = dinv[row0 + rg * 2 + 0];
    const float dv1 = dinv[row0 + rg * 2 + 1];
    uint32_t* hp = hout + (size_t)(row0 + rg * 2) * (OUT / 2) + obase / 2 + cg * 2;
    *(uint2*)hp = make_uint2(pack_bf16x2(a00 * dv0, a01 * dv0), pack_bf16x2(a02 * dv0, a03 * dv0));
    *(uint2*)(hp + OUT / 2) = make_uint2(pack_bf16x2(a10 * dv1, a11 * dv1), pack_bf16x2(a12 * dv1, a13 * dv1));
  }
}

// ---------------- aggregation: out[i] = di*(sum_c hs[c] + hs[i]) + b ----------------
// Paired-edge layout; bf16x2 OUTPUT (halves write + next-gemm read traffic).
// Chunked XCD swizzle: each XCD gets a contiguous 1/8 node range (L2 window probe).
template<bool RELU>
__global__ __launch_bounds__(256) void k_agg128(const uint32_t* __restrict__ hs,
                                                const float* __restrict__ dinv,
                                                const int* __restrict__ rowptr,
                                                const int* __restrict__ col,
                                                const float* __restrict__ bias,
                                                uint32_t* __restrict__ out) {
  const int lane = threadIdx.x & 63;
  const int half = lane >> 5;   // 0 = even edges, 1 = odd edges
  const int w = lane & 31;      // uint2 index: cols {4w..4w+3}
  const int bswz = (blockIdx.x & 7) * (gridDim.x >> 3) + (blockIdx.x >> 3);
  const int node = bswz * 4 + (threadIdx.x >> 6);
  if (node >= N_NODES) return;
  const int e0 = rowptr[node], e1 = rowptr[node + 1];
  const uint2* hp = (const uint2*)hs;   // row = 32 uint2
  float a0 = 0.f, a1 = 0.f, a2 = 0.f, a3 = 0.f;
  if (half == 0) {  // self-loop counted once
    const uint2 us = hp[(size_t)node * 32 + w];
    a0 = bf16lo(us.x); a1 = bf16hi(us.x); a2 = bf16lo(us.y); a3 = bf16hi(us.y);
  }
  for (int eb = e0; eb < e1; eb += 64) {
    const int n = min(64, e1 - eb);
    const int ce = col[min(eb + lane, e1 - 1)];
    const int hn = (n + 1) >> 1;
#pragma unroll 4
    for (int j = 0; j < hn; ++j) {
      const int idx = 2 * j + half;
      const int c = __shfl(ce, idx);
      if (idx < n) {
        const uint2 u = hp[(size_t)c * 32 + w];
        a0 += bf16lo(u.x); a1 += bf16hi(u.x);
        a2 += bf16lo(u.y); a3 += bf16hi(u.y);
      }
    }
  }
  a0 += __shfl_xor(a0, 32); a1 += __shfl_xor(a1, 32);
  a2 += __shfl_xor(a2, 32); a3 += __shfl_xor(a3, 32);
  if (half == 0) {
    const float di = dinv[node];
    const float4 bv = ((const float4*)bias)[w];
    float o0 = di * a0 + bv.x, o1 = di * a1 + bv.y;
    float o2 = di * a2 + bv.z, o3 = di * a3 + bv.w;
    if (RELU) {
      o0 = fmaxf(o0, 0.f); o1 = fmaxf(o1, 0.f);
      o2 = fmaxf(o2, 0.f); o3 = fmaxf(o3, 0.f);
    }
    ((uint2*)out)[(size_t)node * 32 + w] = make_uint2(pack_bf16x2(o0, o1), pack_bf16x2(o2, o3));
  }
}

// Final layer: quad-edge layout; fused bias + log_softmax; fp32 output.
__global__ __launch_bounds__(256) void k_agg64_lsm(const uint32_t* __restrict__ hs,
                                                   const float* __restrict__ dinv,
                                                   const int* __restrict__ rowptr,
                                                   const int* __restrict__ col,
                                                   const float* __restrict__ bias,
                                                   float* __restrict__ out) {
  const int lane = threadIdx.x & 63;
  const int q = lane >> 4;      // edge sub-slot 0..3
  const int t = lane & 15;      // uint2 index: cols {4t..4t+3}
  const int bswz = (blockIdx.x & 7) * (gridDim.x >> 3) + (blockIdx.x >> 3);
  const int node = bswz * 4 + (threadIdx.x >> 6);
  if (node >= N_NODES) return;
  const int e0 = rowptr[node], e1 = rowptr[node + 1];
  const uint2* hp = (const uint2*)hs;   // row = 16 uint2
  float a0 = 0.f, a1 = 0.f, a2 = 0.f, a3 = 0.f;
  if (q == 0) {  // self-loop counted once
    const uint2 us = hp[(size_t)node * 16 + t];
    a0 = bf16lo(us.x); a1 = bf16hi(us.x); a2 = bf16lo(us.y); a3 = bf16hi(us.y);
  }
  for (int eb = e0; eb < e1; eb += 64) {
    const int n = min(64, e1 - eb);
    const int ce = col[min(eb + lane, e1 - 1)];
    const int qn = (n + 3) >> 2;
#pragma unroll 4
    for (int j = 0; j < qn; ++j) {
      const int idx = 4 * j + q;
      const int c = __shfl(ce, idx);
      if (idx < n) {
        const uint2 u = hp[(size_t)c * 16 + t];
        a0 += bf16lo(u.x); a1 += bf16hi(u.x);
        a2 += bf16lo(u.y); a3 += bf16hi(u.y);
      }
    }
  }
  a0 += __shfl_xor(a0, 32); a1 += __shfl_xor(a1, 32);
  a2 += __shfl_xor(a2, 32); a3 += __shfl_xor(a3, 32);
  a0 += __shfl_xor(a0, 16); a1 += __shfl_xor(a1, 16);
  a2 += __shfl_xor(a2, 16); a3 += __shfl_xor(a3, 16);
  const float di = dinv[node];
  const float4 bv = ((const float4*)bias)[t];
  const float v0 = di * a0 + bv.x;
  const float v1 = di * a1 + bv.y;
  const float v2 = di * a2 + bv.z;
  const float v3 = di * a3 + bv.w;
  float m = fmaxf(fmaxf(v0, v1), fmaxf(v2, v3));
#pragma unroll
  for (int off = 8; off > 0; off >>= 1) m = fmaxf(m, __shfl_xor(m, off));
  float s = __expf(v0 - m) + __expf(v1 - m) + __expf(v2 - m) + __expf(v3 - m);
#pragma unroll
  for (int off = 8; off > 0; off >>= 1) s += __shfl_xor(s, off);
  const float ls = m + __logf(s);
  if (q == 0)
    ((float4*)out)[(size_t)node * 16 + t] = make_float4(v0 - ls, v1 - ls, v2 - ls, v3 - ls);
}

// ---------------- launch ----------------

extern "C" void kernel_launch(void* const* d_in, const int* in_sizes, int n_in,
                              void* d_out, int out_size, void* d_ws, size_t ws_size,
                              hipStream_t stream) {
  const float* x  = (const float*)d_in[0];
  const int*   ei = (const int*)d_in[1];
  const float* W0 = (const float*)d_in[2];
  const float* b0 = (const float*)d_in[3];
  const float* W1 = (const float*)d_in[4];
  const float* b1 = (const float*)d_in[5];
  const float* W2 = (const float*)d_in[6];
  const float* b2 = (const float*)d_in[7];
  float* outp = (float*)d_out;

  char* p = (char*)d_ws;
  float* dinv    = (float*)p; p += alup((size_t)N_NODES * 4);
  int*   rowptr  = (int*)p;   p += alup((size_t)(N_NODES + 1) * 4);
  int*   bcursor = (int*)p;   p += alup((size_t)NBUK * 4);
  int*   bukcnt  = (int*)p;   p += alup((size_t)NBUK * 4);
  int*   bbase   = (int*)p;   p += alup((size_t)(NBUK + 1) * 4);
  int*   col     = (int*)p;   p += alup((size_t)2 * N_EDGES * 4);
  float* bufA    = (float*)p; p += alup((size_t)N_NODES * 128 * 4);
  float* bufB    = (float*)p;
  uint32_t* ebuf = (uint32_t*)bufA;       // pass-1 staging aliases bufA
  uint32_t* h16  = (uint32_t*)bufA;       // bf16x2 gemm output (all layers)
  uint32_t* a16  = (uint32_t*)bufB;       // bf16x2 agg output (layers 0/1)

  hipMemsetAsync(bukcnt, 0, (size_t)NBUK * 4, stream);
  k_hist<<<(2 * N_EDGES + CHUNK - 1) / CHUNK, 256, 0, stream>>>(ei, bukcnt);
  k_scan2<<<1, 512, 0, stream>>>(bukcnt, bbase);
  k_binit<<<(NBUK + 255) / 256, 256, 0, stream>>>(bbase, bcursor, rowptr);
  k_bin<<<(2 * N_EDGES + CHUNK - 1) / CHUNK, 256, 0, stream>>>(ei, bcursor, ebuf);
  k_csr<<<NBUK, 256, 0, stream>>>(ebuf, bbase, col, rowptr, dinv);

  dim3 g128(640, 2), g64(640, 1);
  k_gemm<128, false><<<g128, 256, 0, stream>>>(x, W0, dinv, h16);
  k_agg128<true><<<N_NODES / 4, 256, 0, stream>>>(h16, dinv, rowptr, col, b0, a16);
  k_gemm<128, true><<<g128, 256, 0, stream>>>(a16, W1, dinv, h16);
  k_agg128<true><<<N_NODES / 4, 256, 0, stream>>>(h16, dinv, rowptr, col, b1, a16);
  k_gemm<64, true><<<g64, 256, 0, stream>>>(a16, W2, dinv, h16);
  k_agg64_lsm<<<N_NODES / 4, 256, 0, stream>>>(h16, dinv, rowptr, col, b2, outp);
}

// Round 11
// 553.178 us; speedup vs baseline: 2.3357x; 1.2567x over previous
//
#include <hip/hip_runtime.h>
#include <hip/hip_bf16.h>
#include <cstdint>

#define N_NODES 100000
#define N_EDGES 1600000
#define NBUK 391   // ceil(N_NODES / 256) buckets of 256 dst nodes
#define CHUNK 4096
#define MAXB 10240 // LDS staging capacity per bucket (mean 8192, +22σ)
#define NSB 16     // src super-buckets: src>>13 in [0,13)

static inline size_t alup(size_t x) { return (x + 255) & ~(size_t)255; }

typedef __attribute__((ext_vector_type(8))) short bf16x8;
typedef __attribute__((ext_vector_type(4))) float f32x4;
union U4 { uint4 u; bf16x8 v; };

static __device__ __forceinline__ uint32_t pack_bf16x2(float a, float b) {
  uint32_t ua = __float_as_uint(a); ua += 0x7FFF + ((ua >> 16) & 1);
  uint32_t ub = __float_as_uint(b); ub += 0x7FFF + ((ub >> 16) & 1);
  return (ua >> 16) | (ub & 0xFFFF0000u);
}
static __device__ __forceinline__ float bf16lo(uint32_t u) { return __uint_as_float(u << 16); }
static __device__ __forceinline__ float bf16hi(uint32_t u) { return __uint_as_float(u & 0xFFFF0000u); }

// ---------------- prep kernels ----------------

// Coarse histogram: LDS per-block, one global atomic per (block,bucket).
__global__ __launch_bounds__(256) void k_hist(const int* __restrict__ ei,
                                              int* __restrict__ bukcnt) {
  __shared__ int hist[NBUK];
  const int tid = threadIdx.x;
  const int base = blockIdx.x * CHUNK;
  const int n = min(CHUNK, 2 * N_EDGES - base);
  for (int i = tid; i < NBUK; i += 256) hist[i] = 0;
  __syncthreads();
  for (int i = tid; i < n; i += 256) {
    const int e = base + i;
    const int dst = (e < N_EDGES) ? ei[N_EDGES + e] : ei[e - N_EDGES];
    atomicAdd(&hist[dst >> 8], 1);
  }
  __syncthreads();
  for (int i = tid; i < NBUK; i += 256)
    if (hist[i]) atomicAdd(&bukcnt[i], hist[i]);
}

// Scan 391 bucket totals -> exclusive bbase[0..NBUK].
__global__ __launch_bounds__(512) void k_scan2(const int* __restrict__ bsum,
                                               int* __restrict__ bbase) {
  const int tid = threadIdx.x;
  const int v = (tid < NBUK) ? bsum[tid] : 0;
  int incl = v;
#pragma unroll
  for (int off = 1; off < 64; off <<= 1) {
    const int u = __shfl_up(incl, off);
    if ((tid & 63) >= off) incl += u;
  }
  __shared__ int wsum[8];
  if ((tid & 63) == 63) wsum[tid >> 6] = incl;
  __syncthreads();
  const int wid = tid >> 6;
  int add = 0;
#pragma unroll
  for (int k = 0; k < 7; ++k)
    if (k < wid) add += wsum[k];
  incl += add;
  if (tid < NBUK) bbase[tid] = incl - v;
  if (tid == NBUK - 1) bbase[NBUK] = incl;  // = 2*N_EDGES
}

__global__ __launch_bounds__(256) void k_binit(const int* __restrict__ bbase,
                                               int* __restrict__ bcursor,
                                               int* __restrict__ rowptr) {
  int b = blockIdx.x * 256 + threadIdx.x;
  if (b < NBUK) bcursor[b] = bbase[b];
  if (b == 0) rowptr[N_NODES] = 2 * N_EDGES;
}

// Pass 1: multisplit edges into 391 coarse dst-buckets with coalesced writes.
// payload pack = (dst&255)<<17 | src   (src < 2^17). Bucket id cached in u16 LDS
// (removes the 9-step binary search per edge on writeback).
__global__ __launch_bounds__(256) void k_bin(const int* __restrict__ ei,
                                             int* __restrict__ bcursor,
                                             uint32_t* __restrict__ ebuf) {
  __shared__ int hist[NBUK];
  __shared__ int excl[NBUK + 1];
  __shared__ int gbase[NBUK];
  __shared__ uint32_t stage[CHUNK];
  __shared__ unsigned short sbuk[CHUNK];
  const int tid = threadIdx.x;
  const int base = blockIdx.x * CHUNK;
  const int n = min(CHUNK, 2 * N_EDGES - base);
  for (int i = tid; i < NBUK; i += 256) hist[i] = 0;
  __syncthreads();
  uint32_t pk[16]; int bk[16]; int rk[16];
#pragma unroll
  for (int i = 0; i < 16; ++i) {
    const int li = i * 256 + tid;
    bk[i] = -1;
    if (li < n) {
      const int e = base + li;
      const int src = ei[e];
      const int dst = (e < N_EDGES) ? ei[N_EDGES + e] : ei[e - N_EDGES];
      bk[i] = dst >> 8;
      pk[i] = ((uint32_t)(dst & 255) << 17) | (uint32_t)src;
      rk[i] = atomicAdd(&hist[bk[i]], 1);
    }
  }
  __syncthreads();
  if (tid < 64) {
    int c[7]; int s = 0;
#pragma unroll
    for (int j = 0; j < 7; ++j) {
      const int b = tid * 7 + j;
      c[j] = (b < NBUK) ? hist[b] : 0;
      s += c[j];
    }
    int incl = s;
#pragma unroll
    for (int off = 1; off < 64; off <<= 1) {
      const int v = __shfl_up(incl, off);
      if (tid >= off) incl += v;
    }
    int run = incl - s;
#pragma unroll
    for (int j = 0; j < 7; ++j) {
      const int b = tid * 7 + j;
      if (b < NBUK) {
        excl[b] = run;
        gbase[b] = atomicAdd(&bcursor[b], c[j]);
        run += c[j];
      }
    }
    if (tid == 63) excl[NBUK] = incl;
  }
  __syncthreads();
#pragma unroll
  for (int i = 0; i < 16; ++i)
    if (bk[i] >= 0) {
      const int pos = excl[bk[i]] + rk[i];
      stage[pos] = pk[i];
      sbuk[pos] = (unsigned short)bk[i];
    }
  __syncthreads();
  for (int i = tid; i < n; i += 256) {
    const int b = sbuk[i];
    ebuf[gbase[b] + (i - excl[b])] = stage[i];
  }
}

// Pass 2: one workgroup per bucket. Derives per-node degree from its own histogram
// (writes rowptr + dinv), counting sort by (dst_local, src>>13), coalesced writeback.
__global__ __launch_bounds__(256) void k_csr(const uint32_t* __restrict__ ebuf,
                                             const int* __restrict__ bbase,
                                             int* __restrict__ col,
                                             int* __restrict__ rowptr,
                                             float* __restrict__ dinv) {
  __shared__ int cnt[256 * NSB];   // 16 KB
  __shared__ int lstage[MAXB];     // 40 KB
  __shared__ int wsum[4];
  const int b = blockIdx.x;
  const int node0 = b << 8;
  const int gstart = bbase[b];
  const int total = bbase[b + 1] - gstart;
  const int tid = threadIdx.x;
  for (int i = tid; i < 256 * NSB; i += 256) cnt[i] = 0;
  __syncthreads();
  for (int i = tid; i < total; i += 256) {
    const uint32_t pk = ebuf[gstart + i];
    atomicAdd(&cnt[(pk >> 17) * NSB + ((pk & 0x1FFFF) >> 13)], 1);
  }
  __syncthreads();
  int nodetotal = 0;
#pragma unroll
  for (int s = 0; s < NSB; ++s) nodetotal += cnt[tid * NSB + s];
  int incl = nodetotal;
#pragma unroll
  for (int off = 1; off < 64; off <<= 1) {
    const int u = __shfl_up(incl, off);
    if ((tid & 63) >= off) incl += u;
  }
  if ((tid & 63) == 63) wsum[tid >> 6] = incl;
  __syncthreads();
  const int wid = tid >> 6;
  int add = 0;
#pragma unroll
  for (int k = 0; k < 3; ++k)
    if (k < wid) add += wsum[k];
  incl += add;
  const int prefix = incl - nodetotal;
  const int node = node0 + tid;
  if (node < N_NODES) {
    rowptr[node] = gstart + prefix;
    dinv[node] = rsqrtf((float)(nodetotal + 1));  // +1 self loop
  }
  {
    int run = prefix;
#pragma unroll
    for (int s = 0; s < NSB; ++s) {
      const int c = cnt[tid * NSB + s];
      cnt[tid * NSB + s] = run;
      run += c;
    }
  }
  __syncthreads();
  for (int i = tid; i < total; i += 256) {
    const uint32_t pk = ebuf[gstart + i];
    const int src = pk & 0x1FFFF;
    const int p = atomicAdd(&cnt[(pk >> 17) * NSB + (src >> 13)], 1);
    if (p < MAXB) lstage[p] = src;
    else col[gstart + p] = src;  // overflow fallback (statistically never)
  }
  __syncthreads();
  const int m = min(total, MAXB);
  for (int i = tid; i < m; i += 256) col[gstart + i] = lstage[i];
}

// ---------------- MFMA GEMM: hs = dinv[row] * (x @ W.T), bf16x2 output ----------------
// 256 thr = 4 waves; block covers 64 rows; wave w: rows row0+16w..+15, all OUT cols.
// A: x rows (fp32 converted, or packed bf16); B: W[n][k] staged bf16 in LDS (k-major).
// mfma_f32_16x16x32_bf16; C/D: col=lane&15, row=(lane>>4)*4+reg (m89-verified layout).
template<int OUT, bool FP32IN>
__global__ __launch_bounds__(256) void k_gemm(const void* __restrict__ xin,
                                              const float* __restrict__ W,
                                              const float* __restrict__ dinv,
                                              uint32_t* __restrict__ hout) {
  constexpr int NT = OUT / 16;
  __shared__ uint32_t wlds[OUT * 68];     // W bf16x2, row n stride 68 u32 (pad)
  __shared__ float clds[4][16][36];       // per-wave C staging (2 n-tiles)
  const int tid = threadIdx.x;
  const int lane = tid & 63;
  const int wv = tid >> 6;
  // stage W -> bf16 LDS [n][k]
  for (int idx = tid; idx < OUT * 32; idx += 256) {
    const int n = idx >> 5;
    const int kq = idx & 31;              // 4 k per step
    const float4 w4 = *(const float4*)(W + (size_t)n * 128 + kq * 4);
    wlds[n * 68 + kq * 2 + 0] = pack_bf16x2(w4.x, w4.y);
    wlds[n * 68 + kq * 2 + 1] = pack_bf16x2(w4.z, w4.w);
  }
  __syncthreads();
  const int row0 = blockIdx.x * 64 + wv * 16;
  const int r = min(row0 + (lane & 15), N_NODES - 1);
  const int kh = lane >> 4;               // k-octet selector 0..3
  // A fragments: k = kb*32 + kh*8 .. +7
  U4 a[4];
  if (FP32IN) {
    const float* xp = (const float*)xin + (size_t)r * 128 + kh * 8;
#pragma unroll
    for (int kb = 0; kb < 4; ++kb) {
      const float4 lo = *(const float4*)(xp + kb * 32);
      const float4 hi = *(const float4*)(xp + kb * 32 + 4);
      a[kb].u = make_uint4(pack_bf16x2(lo.x, lo.y), pack_bf16x2(lo.z, lo.w),
                           pack_bf16x2(hi.x, hi.y), pack_bf16x2(hi.z, hi.w));
    }
  } else {
    const uint4* xp = (const uint4*)xin + (size_t)r * 16 + kh;
#pragma unroll
    for (int kb = 0; kb < 4; ++kb) a[kb].u = xp[kb * 4];
  }
#pragma unroll
  for (int np = 0; np < NT; np += 2) {
#pragma unroll
    for (int t = 0; t < 2; ++t) {
      f32x4 acc = {0.f, 0.f, 0.f, 0.f};
      const int n = (np + t) * 16 + (lane & 15);
#pragma unroll
      for (int kb = 0; kb < 4; ++kb) {
        U4 bf;
        bf.u = *(const uint4*)(wlds + n * 68 + kb * 16 + kh * 4);
        acc = __builtin_amdgcn_mfma_f32_16x16x32_bf16(a[kb].v, bf.v, acc, 0, 0, 0);
      }
#pragma unroll
      for (int rr = 0; rr < 4; ++rr)
        clds[wv][kh * 4 + rr][t * 16 + (lane & 15)] = acc[rr];
    }
    __syncthreads();
    // repack: lane -> row orow, 8 cols at colg; dinv scale; bf16x2; 16B store
    const int orow = lane & 15;
    const int colg = (lane >> 4) * 8;     // 0,8,16,24
    const int grow = row0 + orow;
    const float di = dinv[grow < N_NODES ? grow : 0];
    const float4 c0 = *(const float4*)&clds[wv][orow][colg];
    const float4 c1 = *(const float4*)&clds[wv][orow][colg + 4];
    if (grow < N_NODES) {
      const uint4 pkv = make_uint4(pack_bf16x2(di * c0.x, di * c0.y),
                                   pack_bf16x2(di * c0.z, di * c0.w),
                                   pack_bf16x2(di * c1.x, di * c1.y),
                                   pack_bf16x2(di * c1.z, di * c1.w));
      *(uint4*)(hout + (size_t)grow * (OUT / 2) + np * 8 + colg / 2) = pkv;
    }
    __syncthreads();
  }
}

// ---------------- aggregation: out[i] = di*(sum_c hs[c] + hs[i]) + b ----------------
// Paired-edge layout; bf16x2 output. Chunked XCD swizzle.
template<bool RELU>
__global__ __launch_bounds__(256) void k_agg128(const uint32_t* __restrict__ hs,
                                                const float* __restrict__ dinv,
                                                const int* __restrict__ rowptr,
                                                const int* __restrict__ col,
                                                const float* __restrict__ bias,
                                                uint32_t* __restrict__ out) {
  const int lane = threadIdx.x & 63;
  const int half = lane >> 5;   // 0 = even edges, 1 = odd edges
  const int w = lane & 31;      // uint2 index: cols {4w..4w+3}
  const int bswz = (blockIdx.x & 7) * (gridDim.x >> 3) + (blockIdx.x >> 3);
  const int node = bswz * 4 + (threadIdx.x >> 6);
  if (node >= N_NODES) return;
  const int e0 = rowptr[node], e1 = rowptr[node + 1];
  const uint2* hp = (const uint2*)hs;   // row = 32 uint2
  float a0 = 0.f, a1 = 0.f, a2 = 0.f, a3 = 0.f;
  if (half == 0) {  // self-loop counted once
    const uint2 us = hp[(size_t)node * 32 + w];
    a0 = bf16lo(us.x); a1 = bf16hi(us.x); a2 = bf16lo(us.y); a3 = bf16hi(us.y);
  }
  for (int eb = e0; eb < e1; eb += 64) {
    const int n = min(64, e1 - eb);
    const int ce = col[min(eb + lane, e1 - 1)];
    const int hn = (n + 1) >> 1;
#pragma unroll 4
    for (int j = 0; j < hn; ++j) {
      const int idx = 2 * j + half;
      const int c = __shfl(ce, idx);
      if (idx < n) {
        const uint2 u = hp[(size_t)c * 32 + w];
        a0 += bf16lo(u.x); a1 += bf16hi(u.x);
        a2 += bf16lo(u.y); a3 += bf16hi(u.y);
      }
    }
  }
  a0 += __shfl_xor(a0, 32); a1 += __shfl_xor(a1, 32);
  a2 += __shfl_xor(a2, 32); a3 += __shfl_xor(a3, 32);
  if (half == 0) {
    const float di = dinv[node];
    const float4 bv = ((const float4*)bias)[w];
    float o0 = di * a0 + bv.x, o1 = di * a1 + bv.y;
    float o2 = di * a2 + bv.z, o3 = di * a3 + bv.w;
    if (RELU) {
      o0 = fmaxf(o0, 0.f); o1 = fmaxf(o1, 0.f);
      o2 = fmaxf(o2, 0.f); o3 = fmaxf(o3, 0.f);
    }
    ((uint2*)out)[(size_t)node * 32 + w] = make_uint2(pack_bf16x2(o0, o1), pack_bf16x2(o2, o3));
  }
}

// Final layer: quad-edge layout; fused bias + log_softmax; fp32 output.
__global__ __launch_bounds__(256) void k_agg64_lsm(const uint32_t* __restrict__ hs,
                                                   const float* __restrict__ dinv,
                                                   const int* __restrict__ rowptr,
                                                   const int* __restrict__ col,
                                                   const float* __restrict__ bias,
                                                   float* __restrict__ out) {
  const int lane = threadIdx.x & 63;
  const int q = lane >> 4;      // edge sub-slot 0..3
  const int t = lane & 15;      // uint2 index: cols {4t..4t+3}
  const int bswz = (blockIdx.x & 7) * (gridDim.x >> 3) + (blockIdx.x >> 3);
  const int node = bswz * 4 + (threadIdx.x >> 6);
  if (node >= N_NODES) return;
  const int e0 = rowptr[node], e1 = rowptr[node + 1];
  const uint2* hp = (const uint2*)hs;   // row = 16 uint2
  float a0 = 0.f, a1 = 0.f, a2 = 0.f, a3 = 0.f;
  if (q == 0) {  // self-loop counted once
    const uint2 us = hp[(size_t)node * 16 + t];
    a0 = bf16lo(us.x); a1 = bf16hi(us.x); a2 = bf16lo(us.y); a3 = bf16hi(us.y);
  }
  for (int eb = e0; eb < e1; eb += 64) {
    const int n = min(64, e1 - eb);
    const int ce = col[min(eb + lane, e1 - 1)];
    const int qn = (n + 3) >> 2;
#pragma unroll 4
    for (int j = 0; j < qn; ++j) {
      const int idx = 4 * j + q;
      const int c = __shfl(ce, idx);
      if (idx < n) {
        const uint2 u = hp[(size_t)c * 16 + t];
        a0 += bf16lo(u.x); a1 += bf16hi(u.x);
        a2 += bf16lo(u.y); a3 += bf16hi(u.y);
      }
    }
  }
  a0 += __shfl_xor(a0, 32); a1 += __shfl_xor(a1, 32);
  a2 += __shfl_xor(a2, 32); a3 += __shfl_xor(a3, 32);
  a0 += __shfl_xor(a0, 16); a1 += __shfl_xor(a1, 16);
  a2 += __shfl_xor(a2, 16); a3 += __shfl_xor(a3, 16);
  const float di = dinv[node];
  const float4 bv = ((const float4*)bias)[t];
  const float v0 = di * a0 + bv.x;
  const float v1 = di * a1 + bv.y;
  const float v2 = di * a2 + bv.z;
  const float v3 = di * a3 + bv.w;
  float m = fmaxf(fmaxf(v0, v1), fmaxf(v2, v3));
#pragma unroll
  for (int off = 8; off > 0; off >>= 1) m = fmaxf(m, __shfl_xor(m, off));
  float s = __expf(v0 - m) + __expf(v1 - m) + __expf(v2 - m) + __expf(v3 - m);
#pragma unroll
  for (int off = 8; off > 0; off >>= 1) s += __shfl_xor(s, off);
  const float ls = m + __logf(s);
  if (q == 0)
    ((float4*)out)[(size_t)node * 16 + t] = make_float4(v0 - ls, v1 - ls, v2 - ls, v3 - ls);
}

// ---------------- launch ----------------

extern "C" void kernel_launch(void* const* d_in, const int* in_sizes, int n_in,
                              void* d_out, int out_size, void* d_ws, size_t ws_size,
                              hipStream_t stream) {
  const float* x  = (const float*)d_in[0];
  const int*   ei = (const int*)d_in[1];
  const float* W0 = (const float*)d_in[2];
  const float* b0 = (const float*)d_in[3];
  const float* W1 = (const float*)d_in[4];
  const float* b1 = (const float*)d_in[5];
  const float* W2 = (const float*)d_in[6];
  const float* b2 = (const float*)d_in[7];
  float* outp = (float*)d_out;

  char* p = (char*)d_ws;
  float* dinv    = (float*)p; p += alup((size_t)N_NODES * 4);
  int*   rowptr  = (int*)p;   p += alup((size_t)(N_NODES + 1) * 4);
  int*   bcursor = (int*)p;   p += alup((size_t)NBUK * 4);
  int*   bukcnt  = (int*)p;   p += alup((size_t)NBUK * 4);
  int*   bbase   = (int*)p;   p += alup((size_t)(NBUK + 1) * 4);
  int*   col     = (int*)p;   p += alup((size_t)2 * N_EDGES * 4);
  float* bufA    = (float*)p; p += alup((size_t)N_NODES * 128 * 4);
  float* bufB    = (float*)p;
  uint32_t* ebuf = (uint32_t*)bufA;       // pass-1 staging aliases bufA
  uint32_t* h16  = (uint32_t*)bufA;       // bf16x2 gemm output (all layers)
  uint32_t* a16  = (uint32_t*)bufB;       // bf16x2 agg output (layers 0/1)

  hipMemsetAsync(bukcnt, 0, (size_t)NBUK * 4, stream);
  k_hist<<<(2 * N_EDGES + CHUNK - 1) / CHUNK, 256, 0, stream>>>(ei, bukcnt);
  k_scan2<<<1, 512, 0, stream>>>(bukcnt, bbase);
  k_binit<<<(NBUK + 255) / 256, 256, 0, stream>>>(bbase, bcursor, rowptr);
  k_bin<<<(2 * N_EDGES + CHUNK - 1) / CHUNK, 256, 0, stream>>>(ei, bcursor, ebuf);
  k_csr<<<NBUK, 256, 0, stream>>>(ebuf, bbase, col, rowptr, dinv);

  const int gblk = (N_NODES + 63) / 64;   // 1563
  k_gemm<128, true><<<gblk, 256, 0, stream>>>(x, W0, dinv, h16);
  k_agg128<true><<<N_NODES / 4, 256, 0, stream>>>(h16, dinv, rowptr, col, b0, a16);
  k_gemm<128, false><<<gblk, 256, 0, stream>>>(a16, W1, dinv, h16);
  k_agg128<true><<<N_NODES / 4, 256, 0, stream>>>(h16, dinv, rowptr, col, b1, a16);
  k_gemm<64, false><<<gblk, 256, 0, stream>>>(a16, W2, dinv, h16);
  k_agg64_lsm<<<N_NODES / 4, 256, 0, stream>>>(h16, dinv, rowptr, col, b2, outp);
}

// Round 12
// 458.257 us; speedup vs baseline: 2.8195x; 1.2071x over previous
//
#include <hip/hip_runtime.h>
#include <hip/hip_bf16.h>
#include <cstdint>

#define N_NODES 100000
#define N_EDGES 1600000
#define NBUK 391   // ceil(N_NODES / 256) buckets of 256 dst nodes
#define CHUNK 4096
#define MAXB 10240 // LDS staging capacity per bucket (mean 8192, +22σ)
#define NSB 16     // src super-buckets: src>>13 in [0,13)

static inline size_t alup(size_t x) { return (x + 255) & ~(size_t)255; }

typedef __attribute__((ext_vector_type(8))) short bf16x8;
typedef __attribute__((ext_vector_type(4))) float f32x4;
typedef __attribute__((ext_vector_type(2))) float f32x2;
union U4 { uint4 u; bf16x8 v; };

static __device__ __forceinline__ uint32_t pack_bf16x2(float a, float b) {
  uint32_t ua = __float_as_uint(a); ua += 0x7FFF + ((ua >> 16) & 1);
  uint32_t ub = __float_as_uint(b); ub += 0x7FFF + ((ub >> 16) & 1);
  return (ua >> 16) | (ub & 0xFFFF0000u);
}
static __device__ __forceinline__ float bf16lo(uint32_t u) { return __uint_as_float(u << 16); }
static __device__ __forceinline__ float bf16hi(uint32_t u) { return __uint_as_float(u & 0xFFFF0000u); }

// fp8 e4m3 decode-accumulate: 8 fp8 in a uint2 -> a0..a7 (HW v_cvt_pk_f32_fp8)
#define ACC8(u)                                                              \
  {                                                                          \
    f32x2 p;                                                                 \
    p = __builtin_amdgcn_cvt_pk_f32_fp8((u).x, false); a0 += p.x; a1 += p.y; \
    p = __builtin_amdgcn_cvt_pk_f32_fp8((u).x, true);  a2 += p.x; a3 += p.y; \
    p = __builtin_amdgcn_cvt_pk_f32_fp8((u).y, false); a4 += p.x; a5 += p.y; \
    p = __builtin_amdgcn_cvt_pk_f32_fp8((u).y, true);  a6 += p.x; a7 += p.y; \
  }

// ---------------- prep kernels ----------------

__global__ __launch_bounds__(256) void k_hist(const int* __restrict__ ei,
                                              int* __restrict__ bukcnt) {
  __shared__ int hist[NBUK];
  const int tid = threadIdx.x;
  const int base = blockIdx.x * CHUNK;
  const int n = min(CHUNK, 2 * N_EDGES - base);
  for (int i = tid; i < NBUK; i += 256) hist[i] = 0;
  __syncthreads();
  for (int i = tid; i < n; i += 256) {
    const int e = base + i;
    const int dst = (e < N_EDGES) ? ei[N_EDGES + e] : ei[e - N_EDGES];
    atomicAdd(&hist[dst >> 8], 1);
  }
  __syncthreads();
  for (int i = tid; i < NBUK; i += 256)
    if (hist[i]) atomicAdd(&bukcnt[i], hist[i]);
}

__global__ __launch_bounds__(512) void k_scan2(const int* __restrict__ bsum,
                                               int* __restrict__ bbase) {
  const int tid = threadIdx.x;
  const int v = (tid < NBUK) ? bsum[tid] : 0;
  int incl = v;
#pragma unroll
  for (int off = 1; off < 64; off <<= 1) {
    const int u = __shfl_up(incl, off);
    if ((tid & 63) >= off) incl += u;
  }
  __shared__ int wsum[8];
  if ((tid & 63) == 63) wsum[tid >> 6] = incl;
  __syncthreads();
  const int wid = tid >> 6;
  int add = 0;
#pragma unroll
  for (int k = 0; k < 7; ++k)
    if (k < wid) add += wsum[k];
  incl += add;
  if (tid < NBUK) bbase[tid] = incl - v;
  if (tid == NBUK - 1) bbase[NBUK] = incl;  // = 2*N_EDGES
}

__global__ __launch_bounds__(256) void k_binit(const int* __restrict__ bbase,
                                               int* __restrict__ bcursor,
                                               int* __restrict__ rowptr) {
  int b = blockIdx.x * 256 + threadIdx.x;
  if (b < NBUK) bcursor[b] = bbase[b];
  if (b == 0) rowptr[N_NODES] = 2 * N_EDGES;
}

// Pass 1: multisplit into 391 dst-buckets, coalesced writes; bucket id cached in LDS.
__global__ __launch_bounds__(256) void k_bin(const int* __restrict__ ei,
                                             int* __restrict__ bcursor,
                                             uint32_t* __restrict__ ebuf) {
  __shared__ int hist[NBUK];
  __shared__ int excl[NBUK + 1];
  __shared__ int gbase[NBUK];
  __shared__ uint32_t stage[CHUNK];
  __shared__ unsigned short sbuk[CHUNK];
  const int tid = threadIdx.x;
  const int base = blockIdx.x * CHUNK;
  const int n = min(CHUNK, 2 * N_EDGES - base);
  for (int i = tid; i < NBUK; i += 256) hist[i] = 0;
  __syncthreads();
  uint32_t pk[16]; int bk[16]; int rk[16];
#pragma unroll
  for (int i = 0; i < 16; ++i) {
    const int li = i * 256 + tid;
    bk[i] = -1;
    if (li < n) {
      const int e = base + li;
      const int src = ei[e];
      const int dst = (e < N_EDGES) ? ei[N_EDGES + e] : ei[e - N_EDGES];
      bk[i] = dst >> 8;
      pk[i] = ((uint32_t)(dst & 255) << 17) | (uint32_t)src;
      rk[i] = atomicAdd(&hist[bk[i]], 1);
    }
  }
  __syncthreads();
  if (tid < 64) {
    int c[7]; int s = 0;
#pragma unroll
    for (int j = 0; j < 7; ++j) {
      const int b = tid * 7 + j;
      c[j] = (b < NBUK) ? hist[b] : 0;
      s += c[j];
    }
    int incl = s;
#pragma unroll
    for (int off = 1; off < 64; off <<= 1) {
      const int v = __shfl_up(incl, off);
      if (tid >= off) incl += v;
    }
    int run = incl - s;
#pragma unroll
    for (int j = 0; j < 7; ++j) {
      const int b = tid * 7 + j;
      if (b < NBUK) {
        excl[b] = run;
        gbase[b] = atomicAdd(&bcursor[b], c[j]);
        run += c[j];
      }
    }
    if (tid == 63) excl[NBUK] = incl;
  }
  __syncthreads();
#pragma unroll
  for (int i = 0; i < 16; ++i)
    if (bk[i] >= 0) {
      const int pos = excl[bk[i]] + rk[i];
      stage[pos] = pk[i];
      sbuk[pos] = (unsigned short)bk[i];
    }
  __syncthreads();
  for (int i = tid; i < n; i += 256) {
    const int b = sbuk[i];
    ebuf[gbase[b] + (i - excl[b])] = stage[i];
  }
}

// Pass 2: per-bucket counting sort by (dst_local, src>>13); emits rowptr + dinv.
__global__ __launch_bounds__(256) void k_csr(const uint32_t* __restrict__ ebuf,
                                             const int* __restrict__ bbase,
                                             int* __restrict__ col,
                                             int* __restrict__ rowptr,
                                             float* __restrict__ dinv) {
  __shared__ int cnt[256 * NSB];   // 16 KB
  __shared__ int lstage[MAXB];     // 40 KB
  __shared__ int wsum[4];
  const int b = blockIdx.x;
  const int node0 = b << 8;
  const int gstart = bbase[b];
  const int total = bbase[b + 1] - gstart;
  const int tid = threadIdx.x;
  for (int i = tid; i < 256 * NSB; i += 256) cnt[i] = 0;
  __syncthreads();
  for (int i = tid; i < total; i += 256) {
    const uint32_t pk = ebuf[gstart + i];
    atomicAdd(&cnt[(pk >> 17) * NSB + ((pk & 0x1FFFF) >> 13)], 1);
  }
  __syncthreads();
  int nodetotal = 0;
#pragma unroll
  for (int s = 0; s < NSB; ++s) nodetotal += cnt[tid * NSB + s];
  int incl = nodetotal;
#pragma unroll
  for (int off = 1; off < 64; off <<= 1) {
    const int u = __shfl_up(incl, off);
    if ((tid & 63) >= off) incl += u;
  }
  if ((tid & 63) == 63) wsum[tid >> 6] = incl;
  __syncthreads();
  const int wid = tid >> 6;
  int add = 0;
#pragma unroll
  for (int k = 0; k < 3; ++k)
    if (k < wid) add += wsum[k];
  incl += add;
  const int prefix = incl - nodetotal;
  const int node = node0 + tid;
  if (node < N_NODES) {
    rowptr[node] = gstart + prefix;
    dinv[node] = rsqrtf((float)(nodetotal + 1));  // +1 self loop
  }
  {
    int run = prefix;
#pragma unroll
    for (int s = 0; s < NSB; ++s) {
      const int c = cnt[tid * NSB + s];
      cnt[tid * NSB + s] = run;
      run += c;
    }
  }
  __syncthreads();
  for (int i = tid; i < total; i += 256) {
    const uint32_t pk = ebuf[gstart + i];
    const int src = pk & 0x1FFFF;
    const int p = atomicAdd(&cnt[(pk >> 17) * NSB + (src >> 13)], 1);
    if (p < MAXB) lstage[p] = src;
    else col[gstart + p] = src;  // overflow fallback (statistically never)
  }
  __syncthreads();
  const int m = min(total, MAXB);
  for (int i = tid; i < m; i += 256) col[gstart + i] = lstage[i];
}

// ---------------- MFMA GEMM: hs = dinv[row] * (x @ W.T) ----------------
// FP8OUT: pack to fp8 e4m3 (row = 32 u32 = 128 B); else bf16x2 (row = OUT/2 u32).
template<int OUT, bool FP32IN, bool FP8OUT>
__global__ __launch_bounds__(256) void k_gemm(const void* __restrict__ xin,
                                              const float* __restrict__ W,
                                              const float* __restrict__ dinv,
                                              uint32_t* __restrict__ hout) {
  constexpr int NT = OUT / 16;
  __shared__ uint32_t wlds[OUT * 68];     // W bf16x2, row n stride 68 u32 (pad)
  __shared__ float clds[4][16][36];       // per-wave C staging (2 n-tiles)
  const int tid = threadIdx.x;
  const int lane = tid & 63;
  const int wv = tid >> 6;
  for (int idx = tid; idx < OUT * 32; idx += 256) {
    const int n = idx >> 5;
    const int kq = idx & 31;              // 4 k per step
    const float4 w4 = *(const float4*)(W + (size_t)n * 128 + kq * 4);
    wlds[n * 68 + kq * 2 + 0] = pack_bf16x2(w4.x, w4.y);
    wlds[n * 68 + kq * 2 + 1] = pack_bf16x2(w4.z, w4.w);
  }
  __syncthreads();
  const int row0 = blockIdx.x * 64 + wv * 16;
  const int r = min(row0 + (lane & 15), N_NODES - 1);
  const int kh = lane >> 4;               // k-octet selector 0..3
  U4 a[4];
  if (FP32IN) {
    const float* xp = (const float*)xin + (size_t)r * 128 + kh * 8;
#pragma unroll
    for (int kb = 0; kb < 4; ++kb) {
      const float4 lo = *(const float4*)(xp + kb * 32);
      const float4 hi = *(const float4*)(xp + kb * 32 + 4);
      a[kb].u = make_uint4(pack_bf16x2(lo.x, lo.y), pack_bf16x2(lo.z, lo.w),
                           pack_bf16x2(hi.x, hi.y), pack_bf16x2(hi.z, hi.w));
    }
  } else {
    const uint4* xp = (const uint4*)xin + (size_t)r * 16 + kh;
#pragma unroll
    for (int kb = 0; kb < 4; ++kb) a[kb].u = xp[kb * 4];
  }
#pragma unroll
  for (int np = 0; np < NT; np += 2) {
#pragma unroll
    for (int t = 0; t < 2; ++t) {
      f32x4 acc = {0.f, 0.f, 0.f, 0.f};
      const int n = (np + t) * 16 + (lane & 15);
#pragma unroll
      for (int kb = 0; kb < 4; ++kb) {
        U4 bf;
        bf.u = *(const uint4*)(wlds + n * 68 + kb * 16 + kh * 4);
        acc = __builtin_amdgcn_mfma_f32_16x16x32_bf16(a[kb].v, bf.v, acc, 0, 0, 0);
      }
#pragma unroll
      for (int rr = 0; rr < 4; ++rr)
        clds[wv][kh * 4 + rr][t * 16 + (lane & 15)] = acc[rr];
    }
    __syncthreads();
    const int orow = lane & 15;
    const int colg = (lane >> 4) * 8;     // 0,8,16,24
    const int grow = row0 + orow;
    const float di = dinv[grow < N_NODES ? grow : 0];
    const float4 c0 = *(const float4*)&clds[wv][orow][colg];
    const float4 c1 = *(const float4*)&clds[wv][orow][colg + 4];
    if (grow < N_NODES) {
      if (FP8OUT) {
        uint32_t u0 = __builtin_amdgcn_cvt_pk_fp8_f32(di * c0.x, di * c0.y, 0, false);
        u0 = __builtin_amdgcn_cvt_pk_fp8_f32(di * c0.z, di * c0.w, u0, true);
        uint32_t u1 = __builtin_amdgcn_cvt_pk_fp8_f32(di * c1.x, di * c1.y, 0, false);
        u1 = __builtin_amdgcn_cvt_pk_fp8_f32(di * c1.z, di * c1.w, u1, true);
        *(uint2*)(hout + (size_t)grow * 32 + np * 4 + colg / 4) = make_uint2(u0, u1);
      } else {
        const uint4 pkv = make_uint4(pack_bf16x2(di * c0.x, di * c0.y),
                                     pack_bf16x2(di * c0.z, di * c0.w),
                                     pack_bf16x2(di * c1.x, di * c1.y),
                                     pack_bf16x2(di * c1.z, di * c1.w));
        *(uint4*)(hout + (size_t)grow * (OUT / 2) + np * 8 + colg / 2) = pkv;
      }
    }
    __syncthreads();
  }
}

// ---------------- aggregation (fp8 gather): out[i] = di*(sum_c hs[c] + hs[i]) + b ----------------
// Quad-edge layout: lane quarter q handles edges 4j+q; 16 lanes x uint2 = full 128B row;
// 8 cols/lane fp32 acc; quarters combined via shfl_xor(32),(16); bf16x2 output.
template<bool RELU>
__global__ __launch_bounds__(256) void k_agg128(const uint2* __restrict__ h8,
                                                const float* __restrict__ dinv,
                                                const int* __restrict__ rowptr,
                                                const int* __restrict__ col,
                                                const float* __restrict__ bias,
                                                uint32_t* __restrict__ out) {
  const int lane = threadIdx.x & 63;
  const int q = lane >> 4;      // edge sub-slot 0..3
  const int t = lane & 15;      // uint2 index: cols {8t..8t+7}
  const int bswz = (blockIdx.x & 7) * (gridDim.x >> 3) + (blockIdx.x >> 3);
  const int node = bswz * 4 + (threadIdx.x >> 6);
  if (node >= N_NODES) return;
  const int e0 = rowptr[node], e1 = rowptr[node + 1];
  float a0 = 0.f, a1 = 0.f, a2 = 0.f, a3 = 0.f, a4 = 0.f, a5 = 0.f, a6 = 0.f, a7 = 0.f;
  if (q == 0) {  // self-loop counted once
    const uint2 us = h8[(size_t)node * 16 + t];
    ACC8(us);
  }
  for (int eb = e0; eb < e1; eb += 64) {
    const int n = min(64, e1 - eb);
    const int ce = col[min(eb + lane, e1 - 1)];
    const int qn = (n + 3) >> 2;
#pragma unroll 4
    for (int j = 0; j < qn; ++j) {
      const int idx = 4 * j + q;
      const int c = __shfl(ce, idx);
      if (idx < n) {
        const uint2 u = h8[(size_t)c * 16 + t];
        ACC8(u);
      }
    }
  }
  a0 += __shfl_xor(a0, 32); a1 += __shfl_xor(a1, 32);
  a2 += __shfl_xor(a2, 32); a3 += __shfl_xor(a3, 32);
  a4 += __shfl_xor(a4, 32); a5 += __shfl_xor(a5, 32);
  a6 += __shfl_xor(a6, 32); a7 += __shfl_xor(a7, 32);
  a0 += __shfl_xor(a0, 16); a1 += __shfl_xor(a1, 16);
  a2 += __shfl_xor(a2, 16); a3 += __shfl_xor(a3, 16);
  a4 += __shfl_xor(a4, 16); a5 += __shfl_xor(a5, 16);
  a6 += __shfl_xor(a6, 16); a7 += __shfl_xor(a7, 16);
  if (q == 0) {
    const float di = dinv[node];
    const float4 b0 = ((const float4*)bias)[t * 2];
    const float4 b1 = ((const float4*)bias)[t * 2 + 1];
    float o0 = di * a0 + b0.x, o1 = di * a1 + b0.y;
    float o2 = di * a2 + b0.z, o3 = di * a3 + b0.w;
    float o4 = di * a4 + b1.x, o5 = di * a5 + b1.y;
    float o6 = di * a6 + b1.z, o7 = di * a7 + b1.w;
    if (RELU) {
      o0 = fmaxf(o0, 0.f); o1 = fmaxf(o1, 0.f); o2 = fmaxf(o2, 0.f); o3 = fmaxf(o3, 0.f);
      o4 = fmaxf(o4, 0.f); o5 = fmaxf(o5, 0.f); o6 = fmaxf(o6, 0.f); o7 = fmaxf(o7, 0.f);
    }
    ((uint4*)out)[(size_t)node * 16 + t] =
        make_uint4(pack_bf16x2(o0, o1), pack_bf16x2(o2, o3),
                   pack_bf16x2(o4, o5), pack_bf16x2(o6, o7));
  }
}

// Final layer: bf16 gather (accuracy), quad-edge; fused bias + log_softmax; fp32 out.
__global__ __launch_bounds__(256) void k_agg64_lsm(const uint32_t* __restrict__ hs,
                                                   const float* __restrict__ dinv,
                                                   const int* __restrict__ rowptr,
                                                   const int* __restrict__ col,
                                                   const float* __restrict__ bias,
                                                   float* __restrict__ out) {
  const int lane = threadIdx.x & 63;
  const int q = lane >> 4;      // edge sub-slot 0..3
  const int t = lane & 15;      // uint2 index: cols {4t..4t+3}
  const int bswz = (blockIdx.x & 7) * (gridDim.x >> 3) + (blockIdx.x >> 3);
  const int node = bswz * 4 + (threadIdx.x >> 6);
  if (node >= N_NODES) return;
  const int e0 = rowptr[node], e1 = rowptr[node + 1];
  const uint2* hp = (const uint2*)hs;   // row = 16 uint2
  float a0 = 0.f, a1 = 0.f, a2 = 0.f, a3 = 0.f;
  if (q == 0) {  // self-loop counted once
    const uint2 us = hp[(size_t)node * 16 + t];
    a0 = bf16lo(us.x); a1 = bf16hi(us.x); a2 = bf16lo(us.y); a3 = bf16hi(us.y);
  }
  for (int eb = e0; eb < e1; eb += 64) {
    const int n = min(64, e1 - eb);
    const int ce = col[min(eb + lane, e1 - 1)];
    const int qn = (n + 3) >> 2;
#pragma unroll 4
    for (int j = 0; j < qn; ++j) {
      const int idx = 4 * j + q;
      const int c = __shfl(ce, idx);
      if (idx < n) {
        const uint2 u = hp[(size_t)c * 16 + t];
        a0 += bf16lo(u.x); a1 += bf16hi(u.x);
        a2 += bf16lo(u.y); a3 += bf16hi(u.y);
      }
    }
  }
  a0 += __shfl_xor(a0, 32); a1 += __shfl_xor(a1, 32);
  a2 += __shfl_xor(a2, 32); a3 += __shfl_xor(a3, 32);
  a0 += __shfl_xor(a0, 16); a1 += __shfl_xor(a1, 16);
  a2 += __shfl_xor(a2, 16); a3 += __shfl_xor(a3, 16);
  const float di = dinv[node];
  const float4 bv = ((const float4*)bias)[t];
  const float v0 = di * a0 + bv.x;
  const float v1 = di * a1 + bv.y;
  const float v2 = di * a2 + bv.z;
  const float v3 = di * a3 + bv.w;
  float m = fmaxf(fmaxf(v0, v1), fmaxf(v2, v3));
#pragma unroll
  for (int off = 8; off > 0; off >>= 1) m = fmaxf(m, __shfl_xor(m, off));
  float s = __expf(v0 - m) + __expf(v1 - m) + __expf(v2 - m) + __expf(v3 - m);
#pragma unroll
  for (int off = 8; off > 0; off >>= 1) s += __shfl_xor(s, off);
  const float ls = m + __logf(s);
  if (q == 0)
    ((float4*)out)[(size_t)node * 16 + t] = make_float4(v0 - ls, v1 - ls, v2 - ls, v3 - ls);
}

// ---------------- launch ----------------

extern "C" void kernel_launch(void* const* d_in, const int* in_sizes, int n_in,
                              void* d_out, int out_size, void* d_ws, size_t ws_size,
                              hipStream_t stream) {
  const float* x  = (const float*)d_in[0];
  const int*   ei = (const int*)d_in[1];
  const float* W0 = (const float*)d_in[2];
  const float* b0 = (const float*)d_in[3];
  const float* W1 = (const float*)d_in[4];
  const float* b1 = (const float*)d_in[5];
  const float* W2 = (const float*)d_in[6];
  const float* b2 = (const float*)d_in[7];
  float* outp = (float*)d_out;

  char* p = (char*)d_ws;
  float* dinv    = (float*)p; p += alup((size_t)N_NODES * 4);
  int*   rowptr  = (int*)p;   p += alup((size_t)(N_NODES + 1) * 4);
  int*   bcursor = (int*)p;   p += alup((size_t)NBUK * 4);
  int*   bukcnt  = (int*)p;   p += alup((size_t)NBUK * 4);
  int*   bbase   = (int*)p;   p += alup((size_t)(NBUK + 1) * 4);
  int*   col     = (int*)p;   p += alup((size_t)2 * N_EDGES * 4);
  float* bufA    = (float*)p; p += alup((size_t)N_NODES * 128 * 4);
  float* bufB    = (float*)p;
  uint32_t* ebuf = (uint32_t*)bufA;       // pass-1 staging aliases bufA
  uint32_t* h16  = (uint32_t*)bufA;       // gemm output buffer (fp8 or bf16)
  uint32_t* a16  = (uint32_t*)bufB;       // bf16x2 agg output (layers 0/1)

  hipMemsetAsync(bukcnt, 0, (size_t)NBUK * 4, stream);
  k_hist<<<(2 * N_EDGES + CHUNK - 1) / CHUNK, 256, 0, stream>>>(ei, bukcnt);
  k_scan2<<<1, 512, 0, stream>>>(bukcnt, bbase);
  k_binit<<<(NBUK + 255) / 256, 256, 0, stream>>>(bbase, bcursor, rowptr);
  k_bin<<<(2 * N_EDGES + CHUNK - 1) / CHUNK, 256, 0, stream>>>(ei, bcursor, ebuf);
  k_csr<<<NBUK, 256, 0, stream>>>(ebuf, bbase, col, rowptr, dinv);

  const int gblk = (N_NODES + 63) / 64;   // 1563
  k_gemm<128, true, true><<<gblk, 256, 0, stream>>>(x, W0, dinv, h16);
  k_agg128<true><<<N_NODES / 4, 256, 0, stream>>>((const uint2*)h16, dinv, rowptr, col, b0, a16);
  k_gemm<128, false, true><<<gblk, 256, 0, stream>>>(a16, W1, dinv, h16);
  k_agg128<true><<<N_NODES / 4, 256, 0, stream>>>((const uint2*)h16, dinv, rowptr, col, b1, a16);
  k_gemm<64, false, false><<<gblk, 256, 0, stream>>>(a16, W2, dinv, h16);
  k_agg64_lsm<<<N_NODES / 4, 256, 0, stream>>>(h16, dinv, rowptr, col, b2, outp);
}

// Round 13
// 446.322 us; speedup vs baseline: 2.8949x; 1.0267x over previous
//
#include <hip/hip_runtime.h>
#include <hip/hip_bf16.h>
#include <cstdint>

#define N_NODES 100000
#define N_EDGES 1600000
#define NBUK 391   // ceil(N_NODES / 256) buckets of 256 dst nodes
#define CHUNK 4096
#define MAXB 10240 // LDS staging capacity per bucket (mean 8192, +22σ)
#define NSB 16     // src super-buckets: src>>13 in [0,13)

static inline size_t alup(size_t x) { return (x + 255) & ~(size_t)255; }

typedef __attribute__((ext_vector_type(8))) short bf16x8;
typedef __attribute__((ext_vector_type(4))) float f32x4;
typedef __attribute__((ext_vector_type(2))) float f32x2;
union U4 { uint4 u; bf16x8 v; };

static __device__ __forceinline__ uint32_t pack_bf16x2(float a, float b) {
  uint32_t ua = __float_as_uint(a); ua += 0x7FFF + ((ua >> 16) & 1);
  uint32_t ub = __float_as_uint(b); ub += 0x7FFF + ((ub >> 16) & 1);
  return (ua >> 16) | (ub & 0xFFFF0000u);
}
static __device__ __forceinline__ float bf16lo(uint32_t u) { return __uint_as_float(u << 16); }
static __device__ __forceinline__ float bf16hi(uint32_t u) { return __uint_as_float(u & 0xFFFF0000u); }

// fp8 e4m3 decode-accumulate: 8 fp8 in a uint2 -> a0..a7 (HW v_cvt_pk_f32_fp8)
#define ACC8(u)                                                              \
  {                                                                          \
    f32x2 p;                                                                 \
    p = __builtin_amdgcn_cvt_pk_f32_fp8((u).x, false); a0 += p.x; a1 += p.y; \
    p = __builtin_amdgcn_cvt_pk_f32_fp8((u).x, true);  a2 += p.x; a3 += p.y; \
    p = __builtin_amdgcn_cvt_pk_f32_fp8((u).y, false); a4 += p.x; a5 += p.y; \
    p = __builtin_amdgcn_cvt_pk_f32_fp8((u).y, true);  a6 += p.x; a7 += p.y; \
  }

// ---------------- prep kernels ----------------

// Coarse histogram: 512 threads (latency hiding), LDS per-block, one global atomic
// per (block,bucket).
__global__ __launch_bounds__(512) void k_hist(const int* __restrict__ ei,
                                              int* __restrict__ bukcnt) {
  __shared__ int hist[NBUK];
  const int tid = threadIdx.x;
  const int base = blockIdx.x * CHUNK;
  const int n = min(CHUNK, 2 * N_EDGES - base);
  for (int i = tid; i < NBUK; i += 512) hist[i] = 0;
  __syncthreads();
  for (int i = tid; i < n; i += 512) {
    const int e = base + i;
    const int dst = (e < N_EDGES) ? ei[N_EDGES + e] : ei[e - N_EDGES];
    atomicAdd(&hist[dst >> 8], 1);
  }
  __syncthreads();
  for (int i = tid; i < NBUK; i += 512)
    if (hist[i]) atomicAdd(&bukcnt[i], hist[i]);
}

__global__ __launch_bounds__(512) void k_scan2(const int* __restrict__ bsum,
                                               int* __restrict__ bbase) {
  const int tid = threadIdx.x;
  const int v = (tid < NBUK) ? bsum[tid] : 0;
  int incl = v;
#pragma unroll
  for (int off = 1; off < 64; off <<= 1) {
    const int u = __shfl_up(incl, off);
    if ((tid & 63) >= off) incl += u;
  }
  __shared__ int wsum[8];
  if ((tid & 63) == 63) wsum[tid >> 6] = incl;
  __syncthreads();
  const int wid = tid >> 6;
  int add = 0;
#pragma unroll
  for (int k = 0; k < 7; ++k)
    if (k < wid) add += wsum[k];
  incl += add;
  if (tid < NBUK) bbase[tid] = incl - v;
  if (tid == NBUK - 1) bbase[NBUK] = incl;  // = 2*N_EDGES
}

__global__ __launch_bounds__(256) void k_binit(const int* __restrict__ bbase,
                                               int* __restrict__ bcursor,
                                               int* __restrict__ rowptr) {
  int b = blockIdx.x * 256 + threadIdx.x;
  if (b < NBUK) bcursor[b] = bbase[b];
  if (b == 0) rowptr[N_NODES] = 2 * N_EDGES;
}

// Pass 1: multisplit into 391 dst-buckets, coalesced writes; bucket id cached in LDS.
// 512 threads, 8 edges/thread: doubles resident waves/CU (grid is CU-count-limited).
__global__ __launch_bounds__(512) void k_bin(const int* __restrict__ ei,
                                             int* __restrict__ bcursor,
                                             uint32_t* __restrict__ ebuf) {
  __shared__ int hist[NBUK];
  __shared__ int excl[NBUK + 1];
  __shared__ int gbase[NBUK];
  __shared__ uint32_t stage[CHUNK];
  __shared__ unsigned short sbuk[CHUNK];
  const int tid = threadIdx.x;
  const int base = blockIdx.x * CHUNK;
  const int n = min(CHUNK, 2 * N_EDGES - base);
  for (int i = tid; i < NBUK; i += 512) hist[i] = 0;
  __syncthreads();
  uint32_t pk[8]; int bk[8]; int rk[8];
#pragma unroll
  for (int i = 0; i < 8; ++i) {
    const int li = i * 512 + tid;
    bk[i] = -1;
    if (li < n) {
      const int e = base + li;
      const int src = ei[e];
      const int dst = (e < N_EDGES) ? ei[N_EDGES + e] : ei[e - N_EDGES];
      bk[i] = dst >> 8;
      pk[i] = ((uint32_t)(dst & 255) << 17) | (uint32_t)src;
      rk[i] = atomicAdd(&hist[bk[i]], 1);
    }
  }
  __syncthreads();
  if (tid < 64) {
    int c[7]; int s = 0;
#pragma unroll
    for (int j = 0; j < 7; ++j) {
      const int b = tid * 7 + j;
      c[j] = (b < NBUK) ? hist[b] : 0;
      s += c[j];
    }
    int incl = s;
#pragma unroll
    for (int off = 1; off < 64; off <<= 1) {
      const int v = __shfl_up(incl, off);
      if (tid >= off) incl += v;
    }
    int run = incl - s;
#pragma unroll
    for (int j = 0; j < 7; ++j) {
      const int b = tid * 7 + j;
      if (b < NBUK) {
        excl[b] = run;
        gbase[b] = atomicAdd(&bcursor[b], c[j]);
        run += c[j];
      }
    }
    if (tid == 63) excl[NBUK] = incl;
  }
  __syncthreads();
#pragma unroll
  for (int i = 0; i < 8; ++i)
    if (bk[i] >= 0) {
      const int pos = excl[bk[i]] + rk[i];
      stage[pos] = pk[i];
      sbuk[pos] = (unsigned short)bk[i];
    }
  __syncthreads();
  for (int i = tid; i < n; i += 512) {
    const int b = sbuk[i];
    ebuf[gbase[b] + (i - excl[b])] = stage[i];
  }
}

// Pass 2: per-bucket counting sort by (dst_local, src>>13); emits rowptr + dinv.
// 512 threads (391-block grid is CU-limited; double waves for latency hiding).
__global__ __launch_bounds__(512) void k_csr(const uint32_t* __restrict__ ebuf,
                                             const int* __restrict__ bbase,
                                             int* __restrict__ col,
                                             int* __restrict__ rowptr,
                                             float* __restrict__ dinv) {
  __shared__ int cnt[256 * NSB];   // 16 KB
  __shared__ int lstage[MAXB];     // 40 KB
  __shared__ int wsum[4];
  const int b = blockIdx.x;
  const int node0 = b << 8;
  const int gstart = bbase[b];
  const int total = bbase[b + 1] - gstart;
  const int tid = threadIdx.x;
  for (int i = tid; i < 256 * NSB; i += 512) cnt[i] = 0;
  __syncthreads();
  for (int i = tid; i < total; i += 512) {
    const uint32_t pk = ebuf[gstart + i];
    atomicAdd(&cnt[(pk >> 17) * NSB + ((pk & 0x1FFFF) >> 13)], 1);
  }
  __syncthreads();
  int nodetotal = 0;
  if (tid < 256) {
#pragma unroll
    for (int s = 0; s < NSB; ++s) nodetotal += cnt[tid * NSB + s];
    int incl = nodetotal;
#pragma unroll
    for (int off = 1; off < 64; off <<= 1) {
      const int u = __shfl_up(incl, off);
      if ((tid & 63) >= off) incl += u;
    }
    if ((tid & 63) == 63) wsum[tid >> 6] = incl;
    nodetotal = incl;   // stash inclusive value
  }
  __syncthreads();
  if (tid < 256) {
    int deg = 0;
#pragma unroll
    for (int s = 0; s < NSB; ++s) deg += cnt[tid * NSB + s];
    const int wid = tid >> 6;
    int add = 0;
#pragma unroll
    for (int k = 0; k < 3; ++k)
      if (k < wid) add += wsum[k];
    const int prefix = nodetotal + add - deg;
    const int node = node0 + tid;
    if (node < N_NODES) {
      rowptr[node] = gstart + prefix;
      dinv[node] = rsqrtf((float)(deg + 1));  // +1 self loop
    }
    int run = prefix;
#pragma unroll
    for (int s = 0; s < NSB; ++s) {
      const int c = cnt[tid * NSB + s];
      cnt[tid * NSB + s] = run;
      run += c;
    }
  }
  __syncthreads();
  for (int i = tid; i < total; i += 512) {
    const uint32_t pk = ebuf[gstart + i];
    const int src = pk & 0x1FFFF;
    const int p = atomicAdd(&cnt[(pk >> 17) * NSB + (src >> 13)], 1);
    if (p < MAXB) lstage[p] = src;
    else col[gstart + p] = src;  // overflow fallback (statistically never)
  }
  __syncthreads();
  const int m = min(total, MAXB);
  for (int i = tid; i < m; i += 512) col[gstart + i] = lstage[i];
}

// ---------------- MFMA GEMM: hs = dinv[row] * (x @ W.T) ----------------
// FP8OUT: pack to fp8 e4m3 (row = 32 u32 = 128 B); else bf16x2 (row = OUT/2 u32).
template<int OUT, bool FP32IN, bool FP8OUT>
__global__ __launch_bounds__(256) void k_gemm(const void* __restrict__ xin,
                                              const float* __restrict__ W,
                                              const float* __restrict__ dinv,
                                              uint32_t* __restrict__ hout) {
  constexpr int NT = OUT / 16;
  __shared__ uint32_t wlds[OUT * 68];     // W bf16x2, row n stride 68 u32 (pad)
  __shared__ float clds[4][16][36];       // per-wave C staging (2 n-tiles)
  const int tid = threadIdx.x;
  const int lane = tid & 63;
  const int wv = tid >> 6;
  for (int idx = tid; idx < OUT * 32; idx += 256) {
    const int n = idx >> 5;
    const int kq = idx & 31;              // 4 k per step
    const float4 w4 = *(const float4*)(W + (size_t)n * 128 + kq * 4);
    wlds[n * 68 + kq * 2 + 0] = pack_bf16x2(w4.x, w4.y);
    wlds[n * 68 + kq * 2 + 1] = pack_bf16x2(w4.z, w4.w);
  }
  __syncthreads();
  const int row0 = blockIdx.x * 64 + wv * 16;
  const int r = min(row0 + (lane & 15), N_NODES - 1);
  const int kh = lane >> 4;               // k-octet selector 0..3
  U4 a[4];
  if (FP32IN) {
    const float* xp = (const float*)xin + (size_t)r * 128 + kh * 8;
#pragma unroll
    for (int kb = 0; kb < 4; ++kb) {
      const float4 lo = *(const float4*)(xp + kb * 32);
      const float4 hi = *(const float4*)(xp + kb * 32 + 4);
      a[kb].u = make_uint4(pack_bf16x2(lo.x, lo.y), pack_bf16x2(lo.z, lo.w),
                           pack_bf16x2(hi.x, hi.y), pack_bf16x2(hi.z, hi.w));
    }
  } else {
    const uint4* xp = (const uint4*)xin + (size_t)r * 16 + kh;
#pragma unroll
    for (int kb = 0; kb < 4; ++kb) a[kb].u = xp[kb * 4];
  }
#pragma unroll
  for (int np = 0; np < NT; np += 2) {
#pragma unroll
    for (int t = 0; t < 2; ++t) {
      f32x4 acc = {0.f, 0.f, 0.f, 0.f};
      const int n = (np + t) * 16 + (lane & 15);
#pragma unroll
      for (int kb = 0; kb < 4; ++kb) {
        U4 bf;
        bf.u = *(const uint4*)(wlds + n * 68 + kb * 16 + kh * 4);
        acc = __builtin_amdgcn_mfma_f32_16x16x32_bf16(a[kb].v, bf.v, acc, 0, 0, 0);
      }
#pragma unroll
      for (int rr = 0; rr < 4; ++rr)
        clds[wv][kh * 4 + rr][t * 16 + (lane & 15)] = acc[rr];
    }
    __syncthreads();
    const int orow = lane & 15;
    const int colg = (lane >> 4) * 8;     // 0,8,16,24
    const int grow = row0 + orow;
    const float di = dinv[grow < N_NODES ? grow : 0];
    const float4 c0 = *(const float4*)&clds[wv][orow][colg];
    const float4 c1 = *(const float4*)&clds[wv][orow][colg + 4];
    if (grow < N_NODES) {
      if (FP8OUT) {
        uint32_t u0 = __builtin_amdgcn_cvt_pk_fp8_f32(di * c0.x, di * c0.y, 0, false);
        u0 = __builtin_amdgcn_cvt_pk_fp8_f32(di * c0.z, di * c0.w, u0, true);
        uint32_t u1 = __builtin_amdgcn_cvt_pk_fp8_f32(di * c1.x, di * c1.y, 0, false);
        u1 = __builtin_amdgcn_cvt_pk_fp8_f32(di * c1.z, di * c1.w, u1, true);
        *(uint2*)(hout + (size_t)grow * 32 + np * 4 + colg / 4) = make_uint2(u0, u1);
      } else {
        const uint4 pkv = make_uint4(pack_bf16x2(di * c0.x, di * c0.y),
                                     pack_bf16x2(di * c0.z, di * c0.w),
                                     pack_bf16x2(di * c1.x, di * c1.y),
                                     pack_bf16x2(di * c1.z, di * c1.w));
        *(uint4*)(hout + (size_t)grow * (OUT / 2) + np * 8 + colg / 2) = pkv;
      }
    }
    __syncthreads();
  }
}

// ---------------- aggregation (fp8 gather): out[i] = di*(sum_c hs[c] + hs[i]) + b ----------------
// Quad-edge layout: lane quarter q handles edges 4j+q; 16 lanes x uint2 = full 128B row;
// 8 cols/lane fp32 acc; quarters combined via shfl_xor(32),(16); bf16x2 output.
template<bool RELU>
__global__ __launch_bounds__(256) void k_agg128(const uint2* __restrict__ h8,
                                                const float* __restrict__ dinv,
                                                const int* __restrict__ rowptr,
                                                const int* __restrict__ col,
                                                const float* __restrict__ bias,
                                                uint32_t* __restrict__ out) {
  const int lane = threadIdx.x & 63;
  const int q = lane >> 4;      // edge sub-slot 0..3
  const int t = lane & 15;      // uint2 index: cols {8t..8t+7}
  const int bswz = (blockIdx.x & 7) * (gridDim.x >> 3) + (blockIdx.x >> 3);
  const int node = bswz * 4 + (threadIdx.x >> 6);
  if (node >= N_NODES) return;
  const int e0 = rowptr[node], e1 = rowptr[node + 1];
  float a0 = 0.f, a1 = 0.f, a2 = 0.f, a3 = 0.f, a4 = 0.f, a5 = 0.f, a6 = 0.f, a7 = 0.f;
  if (q == 0) {  // self-loop counted once
    const uint2 us = h8[(size_t)node * 16 + t];
    ACC8(us);
  }
  for (int eb = e0; eb < e1; eb += 64) {
    const int n = min(64, e1 - eb);
    const int ce = col[min(eb + lane, e1 - 1)];
    const int qn = (n + 3) >> 2;
#pragma unroll 4
    for (int j = 0; j < qn; ++j) {
      const int idx = 4 * j + q;
      const int c = __shfl(ce, idx);
      if (idx < n) {
        const uint2 u = h8[(size_t)c * 16 + t];
        ACC8(u);
      }
    }
  }
  a0 += __shfl_xor(a0, 32); a1 += __shfl_xor(a1, 32);
  a2 += __shfl_xor(a2, 32); a3 += __shfl_xor(a3, 32);
  a4 += __shfl_xor(a4, 32); a5 += __shfl_xor(a5, 32);
  a6 += __shfl_xor(a6, 32); a7 += __shfl_xor(a7, 32);
  a0 += __shfl_xor(a0, 16); a1 += __shfl_xor(a1, 16);
  a2 += __shfl_xor(a2, 16); a3 += __shfl_xor(a3, 16);
  a4 += __shfl_xor(a4, 16); a5 += __shfl_xor(a5, 16);
  a6 += __shfl_xor(a6, 16); a7 += __shfl_xor(a7, 16);
  if (q == 0) {
    const float di = dinv[node];
    const float4 b0 = ((const float4*)bias)[t * 2];
    const float4 b1 = ((const float4*)bias)[t * 2 + 1];
    float o0 = di * a0 + b0.x, o1 = di * a1 + b0.y;
    float o2 = di * a2 + b0.z, o3 = di * a3 + b0.w;
    float o4 = di * a4 + b1.x, o5 = di * a5 + b1.y;
    float o6 = di * a6 + b1.z, o7 = di * a7 + b1.w;
    if (RELU) {
      o0 = fmaxf(o0, 0.f); o1 = fmaxf(o1, 0.f); o2 = fmaxf(o2, 0.f); o3 = fmaxf(o3, 0.f);
      o4 = fmaxf(o4, 0.f); o5 = fmaxf(o5, 0.f); o6 = fmaxf(o6, 0.f); o7 = fmaxf(o7, 0.f);
    }
    ((uint4*)out)[(size_t)node * 16 + t] =
        make_uint4(pack_bf16x2(o0, o1), pack_bf16x2(o2, o3),
                   pack_bf16x2(o4, o5), pack_bf16x2(o6, o7));
  }
}

// Final layer: bf16 gather (accuracy), quad-edge; fused bias + log_softmax; fp32 out.
__global__ __launch_bounds__(256) void k_agg64_lsm(const uint32_t* __restrict__ hs,
                                                   const float* __restrict__ dinv,
                                                   const int* __restrict__ rowptr,
                                                   const int* __restrict__ col,
                                                   const float* __restrict__ bias,
                                                   float* __restrict__ out) {
  const int lane = threadIdx.x & 63;
  const int q = lane >> 4;      // edge sub-slot 0..3
  const int t = lane & 15;      // uint2 index: cols {4t..4t+3}
  const int bswz = (blockIdx.x & 7) * (gridDim.x >> 3) + (blockIdx.x >> 3);
  const int node = bswz * 4 + (threadIdx.x >> 6);
  if (node >= N_NODES) return;
  const int e0 = rowptr[node], e1 = rowptr[node + 1];
  const uint2* hp = (const uint2*)hs;   // row = 16 uint2
  float a0 = 0.f, a1 = 0.f, a2 = 0.f, a3 = 0.f;
  if (q == 0) {  // self-loop counted once
    const uint2 us = hp[(size_t)node * 16 + t];
    a0 = bf16lo(us.x); a1 = bf16hi(us.x); a2 = bf16lo(us.y); a3 = bf16hi(us.y);
  }
  for (int eb = e0; eb < e1; eb += 64) {
    const int n = min(64, e1 - eb);
    const int ce = col[min(eb + lane, e1 - 1)];
    const int qn = (n + 3) >> 2;
#pragma unroll 4
    for (int j = 0; j < qn; ++j) {
      const int idx = 4 * j + q;
      const int c = __shfl(ce, idx);
      if (idx < n) {
        const uint2 u = hp[(size_t)c * 16 + t];
        a0 += bf16lo(u.x); a1 += bf16hi(u.x);
        a2 += bf16lo(u.y); a3 += bf16hi(u.y);
      }
    }
  }
  a0 += __shfl_xor(a0, 32); a1 += __shfl_xor(a1, 32);
  a2 += __shfl_xor(a2, 32); a3 += __shfl_xor(a3, 32);
  a0 += __shfl_xor(a0, 16); a1 += __shfl_xor(a1, 16);
  a2 += __shfl_xor(a2, 16); a3 += __shfl_xor(a3, 16);
  const float di = dinv[node];
  const float4 bv = ((const float4*)bias)[t];
  const float v0 = di * a0 + bv.x;
  const float v1 = di * a1 + bv.y;
  const float v2 = di * a2 + bv.z;
  const float v3 = di * a3 + bv.w;
  float m = fmaxf(fmaxf(v0, v1), fmaxf(v2, v3));
#pragma unroll
  for (int off = 8; off > 0; off >>= 1) m = fmaxf(m, __shfl_xor(m, off));
  float s = __expf(v0 - m) + __expf(v1 - m) + __expf(v2 - m) + __expf(v3 - m);
#pragma unroll
  for (int off = 8; off > 0; off >>= 1) s += __shfl_xor(s, off);
  const float ls = m + __logf(s);
  if (q == 0)
    ((float4*)out)[(size_t)node * 16 + t] = make_float4(v0 - ls, v1 - ls, v2 - ls, v3 - ls);
}

// ---------------- launch ----------------

extern "C" void kernel_launch(void* const* d_in, const int* in_sizes, int n_in,
                              void* d_out, int out_size, void* d_ws, size_t ws_size,
                              hipStream_t stream) {
  const float* x  = (const float*)d_in[0];
  const int*   ei = (const int*)d_in[1];
  const float* W0 = (const float*)d_in[2];
  const float* b0 = (const float*)d_in[3];
  const float* W1 = (const float*)d_in[4];
  const float* b1 = (const float*)d_in[5];
  const float* W2 = (const float*)d_in[6];
  const float* b2 = (const float*)d_in[7];
  float* outp = (float*)d_out;

  char* p = (char*)d_ws;
  float* dinv    = (float*)p; p += alup((size_t)N_NODES * 4);
  int*   rowptr  = (int*)p;   p += alup((size_t)(N_NODES + 1) * 4);
  int*   bcursor = (int*)p;   p += alup((size_t)NBUK * 4);
  int*   bukcnt  = (int*)p;   p += alup((size_t)NBUK * 4);
  int*   bbase   = (int*)p;   p += alup((size_t)(NBUK + 1) * 4);
  int*   col     = (int*)p;   p += alup((size_t)2 * N_EDGES * 4);
  float* bufA    = (float*)p; p += alup((size_t)N_NODES * 128 * 4);
  float* bufB    = (float*)p;
  uint32_t* ebuf = (uint32_t*)bufA;       // pass-1 staging aliases bufA
  uint32_t* h16  = (uint32_t*)bufA;       // gemm output buffer (fp8 or bf16)
  uint32_t* a16  = (uint32_t*)bufB;       // bf16x2 agg output (layers 0/1)

  hipMemsetAsync(bukcnt, 0, (size_t)NBUK * 4, stream);
  k_hist<<<(2 * N_EDGES + CHUNK - 1) / CHUNK, 512, 0, stream>>>(ei, bukcnt);
  k_scan2<<<1, 512, 0, stream>>>(bukcnt, bbase);
  k_binit<<<(NBUK + 255) / 256, 256, 0, stream>>>(bbase, bcursor, rowptr);
  k_bin<<<(2 * N_EDGES + CHUNK - 1) / CHUNK, 512, 0, stream>>>(ei, bcursor, ebuf);
  k_csr<<<NBUK, 512, 0, stream>>>(ebuf, bbase, col, rowptr, dinv);

  const int gblk = (N_NODES + 63) / 64;   // 1563
  k_gemm<128, true, true><<<gblk, 256, 0, stream>>>(x, W0, dinv, h16);
  k_agg128<true><<<N_NODES / 4, 256, 0, stream>>>((const uint2*)h16, dinv, rowptr, col, b0, a16);
  k_gemm<128, false, true><<<gblk, 256, 0, stream>>>(a16, W1, dinv, h16);
  k_agg128<true><<<N_NODES / 4, 256, 0, stream>>>((const uint2*)h16, dinv, rowptr, col, b1, a16);
  k_gemm<64, false, false><<<gblk, 256, 0, stream>>>(a16, W2, dinv, h16);
  k_agg64_lsm<<<N_NODES / 4, 256, 0, stream>>>(h16, dinv, rowptr, col, b2, outp);
}

// Round 14
// 330.546 us; speedup vs baseline: 3.9089x; 1.3503x over previous
//
#include <hip/hip_runtime.h>
#include <hip/hip_bf16.h>
#include <cstdint>

#define N_NODES 100000
#define N_EDGES 1600000
#define NBUK 391   // ceil(N_NODES / 256) buckets of 256 dst nodes
#define CHUNK 4096
#define NBLK 782   // ceil(2*N_EDGES / CHUNK)
#define MAXB 10240 // LDS staging capacity per bucket (mean 8192, +22σ)
#define NSB 16     // src super-buckets: src>>13 in [0,13)

static inline size_t alup(size_t x) { return (x + 255) & ~(size_t)255; }

typedef __attribute__((ext_vector_type(8))) short bf16x8;
typedef __attribute__((ext_vector_type(4))) float f32x4;
typedef __attribute__((ext_vector_type(2))) float f32x2;
union U4 { uint4 u; bf16x8 v; };

static __device__ __forceinline__ uint32_t pack_bf16x2(float a, float b) {
  uint32_t ua = __float_as_uint(a); ua += 0x7FFF + ((ua >> 16) & 1);
  uint32_t ub = __float_as_uint(b); ub += 0x7FFF + ((ub >> 16) & 1);
  return (ua >> 16) | (ub & 0xFFFF0000u);
}
static __device__ __forceinline__ float bf16lo(uint32_t u) { return __uint_as_float(u << 16); }
static __device__ __forceinline__ float bf16hi(uint32_t u) { return __uint_as_float(u & 0xFFFF0000u); }

// fp8 e4m3 decode-accumulate: 8 fp8 in a uint2 -> a0..a7 (HW v_cvt_pk_f32_fp8)
#define ACC8(u)                                                              \
  {                                                                          \
    f32x2 p;                                                                 \
    p = __builtin_amdgcn_cvt_pk_f32_fp8((u).x, false); a0 += p.x; a1 += p.y; \
    p = __builtin_amdgcn_cvt_pk_f32_fp8((u).x, true);  a2 += p.x; a3 += p.y; \
    p = __builtin_amdgcn_cvt_pk_f32_fp8((u).y, false); a4 += p.x; a5 += p.y; \
    p = __builtin_amdgcn_cvt_pk_f32_fp8((u).y, true);  a6 += p.x; a7 += p.y; \
  }

// ---------------- prep kernels (atomic-free CSR build) ----------------

// Per-block histogram -> row of cntmat (coalesced stores, NO global atomics).
__global__ __launch_bounds__(512) void k_hist(const int* __restrict__ ei,
                                              int* __restrict__ cntmat) {
  __shared__ int hist[NBUK];
  const int tid = threadIdx.x;
  const int base = blockIdx.x * CHUNK;
  const int n = min(CHUNK, 2 * N_EDGES - base);
  for (int i = tid; i < NBUK; i += 512) hist[i] = 0;
  __syncthreads();
  for (int i = tid; i < n; i += 512) {
    const int e = base + i;
    const int dst = (e < N_EDGES) ? ei[N_EDGES + e] : ei[e - N_EDGES];
    atomicAdd(&hist[dst >> 8], 1);
  }
  __syncthreads();
  for (int i = tid; i < NBUK; i += 512)
    cntmat[(size_t)blockIdx.x * NBUK + i] = hist[i];
}

// Column scan: one wave per bucket; cntmat[blk][b] -> exclusive prefix over blk
// (in place); bucket total -> bukcnt[b].
__global__ __launch_bounds__(64) void k_scanB(int* __restrict__ cntmat,
                                              int* __restrict__ bukcnt) {
  const int b = blockIdx.x;
  const int lane = threadIdx.x;
  const int PER = (NBLK + 63) / 64;  // 13
  int v[PER]; int s = 0;
#pragma unroll
  for (int j = 0; j < PER; ++j) {
    const int blk = lane * PER + j;
    v[j] = (blk < NBLK) ? cntmat[(size_t)blk * NBUK + b] : 0;
    s += v[j];
  }
  int incl = s;
#pragma unroll
  for (int off = 1; off < 64; off <<= 1) {
    const int u = __shfl_up(incl, off);
    if (lane >= off) incl += u;
  }
  int run = incl - s;
#pragma unroll
  for (int j = 0; j < PER; ++j) {
    const int blk = lane * PER + j;
    if (blk < NBLK) cntmat[(size_t)blk * NBUK + b] = run;
    run += v[j];
  }
  if (lane == 63) bukcnt[b] = incl;
}

// Scan 391 bucket totals -> exclusive bbase[0..NBUK]; also seeds rowptr[N_NODES].
__global__ __launch_bounds__(512) void k_scan2(const int* __restrict__ bsum,
                                               int* __restrict__ bbase,
                                               int* __restrict__ rowptr) {
  const int tid = threadIdx.x;
  const int v = (tid < NBUK) ? bsum[tid] : 0;
  int incl = v;
#pragma unroll
  for (int off = 1; off < 64; off <<= 1) {
    const int u = __shfl_up(incl, off);
    if ((tid & 63) >= off) incl += u;
  }
  __shared__ int wsum[8];
  if ((tid & 63) == 63) wsum[tid >> 6] = incl;
  __syncthreads();
  const int wid = tid >> 6;
  int add = 0;
#pragma unroll
  for (int k = 0; k < 7; ++k)
    if (k < wid) add += wsum[k];
  incl += add;
  if (tid < NBUK) bbase[tid] = incl - v;
  if (tid == NBUK - 1) bbase[NBUK] = incl;  // = 2*N_EDGES
  if (tid == 0) rowptr[N_NODES] = 2 * N_EDGES;
}

// Pass 1: multisplit into 391 dst-buckets, coalesced writes; bucket id cached in LDS.
// Global write bases are precomputed (bbase + per-block prefix) -> NO global atomics.
__global__ __launch_bounds__(512) void k_bin(const int* __restrict__ ei,
                                             const int* __restrict__ bbase,
                                             const int* __restrict__ cntpre,
                                             uint32_t* __restrict__ ebuf) {
  __shared__ int hist[NBUK];
  __shared__ int excl[NBUK + 1];
  __shared__ int gbase[NBUK];
  __shared__ uint32_t stage[CHUNK];
  __shared__ unsigned short sbuk[CHUNK];
  const int tid = threadIdx.x;
  const int base = blockIdx.x * CHUNK;
  const int n = min(CHUNK, 2 * N_EDGES - base);
  for (int i = tid; i < NBUK; i += 512) {
    hist[i] = 0;
    gbase[i] = bbase[i] + cntpre[(size_t)blockIdx.x * NBUK + i];
  }
  __syncthreads();
  uint32_t pk[8]; int bk[8]; int rk[8];
#pragma unroll
  for (int i = 0; i < 8; ++i) {
    const int li = i * 512 + tid;
    bk[i] = -1;
    if (li < n) {
      const int e = base + li;
      const int src = ei[e];
      const int dst = (e < N_EDGES) ? ei[N_EDGES + e] : ei[e - N_EDGES];
      bk[i] = dst >> 8;
      pk[i] = ((uint32_t)(dst & 255) << 17) | (uint32_t)src;
      rk[i] = atomicAdd(&hist[bk[i]], 1);
    }
  }
  __syncthreads();
  if (tid < 64) {  // block-local exclusive prefix of hist (LDS only)
    int c[7]; int s = 0;
#pragma unroll
    for (int j = 0; j < 7; ++j) {
      const int b = tid * 7 + j;
      c[j] = (b < NBUK) ? hist[b] : 0;
      s += c[j];
    }
    int incl = s;
#pragma unroll
    for (int off = 1; off < 64; off <<= 1) {
      const int v = __shfl_up(incl, off);
      if (tid >= off) incl += v;
    }
    int run = incl - s;
#pragma unroll
    for (int j = 0; j < 7; ++j) {
      const int b = tid * 7 + j;
      if (b < NBUK) {
        excl[b] = run;
        run += c[j];
      }
    }
    if (tid == 63) excl[NBUK] = incl;
  }
  __syncthreads();
#pragma unroll
  for (int i = 0; i < 8; ++i)
    if (bk[i] >= 0) {
      const int pos = excl[bk[i]] + rk[i];
      stage[pos] = pk[i];
      sbuk[pos] = (unsigned short)bk[i];
    }
  __syncthreads();
  for (int i = tid; i < n; i += 512) {
    const int b = sbuk[i];
    ebuf[gbase[b] + (i - excl[b])] = stage[i];
  }
}

// Pass 2: per-bucket counting sort by (dst_local, src>>13); emits rowptr + dinv.
__global__ __launch_bounds__(512) void k_csr(const uint32_t* __restrict__ ebuf,
                                             const int* __restrict__ bbase,
                                             int* __restrict__ col,
                                             int* __restrict__ rowptr,
                                             float* __restrict__ dinv) {
  __shared__ int cnt[256 * NSB];   // 16 KB
  __shared__ int lstage[MAXB];     // 40 KB
  __shared__ int wsum[4];
  const int b = blockIdx.x;
  const int node0 = b << 8;
  const int gstart = bbase[b];
  const int total = bbase[b + 1] - gstart;
  const int tid = threadIdx.x;
  for (int i = tid; i < 256 * NSB; i += 512) cnt[i] = 0;
  __syncthreads();
  for (int i = tid; i < total; i += 512) {
    const uint32_t pk = ebuf[gstart + i];
    atomicAdd(&cnt[(pk >> 17) * NSB + ((pk & 0x1FFFF) >> 13)], 1);
  }
  __syncthreads();
  int nodetotal = 0;
  if (tid < 256) {
#pragma unroll
    for (int s = 0; s < NSB; ++s) nodetotal += cnt[tid * NSB + s];
    int incl = nodetotal;
#pragma unroll
    for (int off = 1; off < 64; off <<= 1) {
      const int u = __shfl_up(incl, off);
      if ((tid & 63) >= off) incl += u;
    }
    if ((tid & 63) == 63) wsum[tid >> 6] = incl;
    nodetotal = incl;   // stash inclusive value
  }
  __syncthreads();
  if (tid < 256) {
    int deg = 0;
#pragma unroll
    for (int s = 0; s < NSB; ++s) deg += cnt[tid * NSB + s];
    const int wid = tid >> 6;
    int add = 0;
#pragma unroll
    for (int k = 0; k < 3; ++k)
      if (k < wid) add += wsum[k];
    const int prefix = nodetotal + add - deg;
    const int node = node0 + tid;
    if (node < N_NODES) {
      rowptr[node] = gstart + prefix;
      dinv[node] = rsqrtf((float)(deg + 1));  // +1 self loop
    }
    int run = prefix;
#pragma unroll
    for (int s = 0; s < NSB; ++s) {
      const int c = cnt[tid * NSB + s];
      cnt[tid * NSB + s] = run;
      run += c;
    }
  }
  __syncthreads();
  for (int i = tid; i < total; i += 512) {
    const uint32_t pk = ebuf[gstart + i];
    const int src = pk & 0x1FFFF;
    const int p = atomicAdd(&cnt[(pk >> 17) * NSB + (src >> 13)], 1);
    if (p < MAXB) lstage[p] = src;
    else col[gstart + p] = src;  // overflow fallback (statistically never)
  }
  __syncthreads();
  const int m = min(total, MAXB);
  for (int i = tid; i < m; i += 512) col[gstart + i] = lstage[i];
}

// ---------------- MFMA GEMM: hs = dinv[row] * (x @ W.T) ----------------
// FP8OUT: pack to fp8 e4m3 (row = 32 u32 = 128 B); else bf16x2 (row = OUT/2 u32).
template<int OUT, bool FP32IN, bool FP8OUT>
__global__ __launch_bounds__(256) void k_gemm(const void* __restrict__ xin,
                                              const float* __restrict__ W,
                                              const float* __restrict__ dinv,
                                              uint32_t* __restrict__ hout) {
  constexpr int NT = OUT / 16;
  __shared__ uint32_t wlds[OUT * 68];     // W bf16x2, row n stride 68 u32 (pad)
  __shared__ float clds[4][16][36];       // per-wave C staging (2 n-tiles)
  const int tid = threadIdx.x;
  const int lane = tid & 63;
  const int wv = tid >> 6;
  for (int idx = tid; idx < OUT * 32; idx += 256) {
    const int n = idx >> 5;
    const int kq = idx & 31;              // 4 k per step
    const float4 w4 = *(const float4*)(W + (size_t)n * 128 + kq * 4);
    wlds[n * 68 + kq * 2 + 0] = pack_bf16x2(w4.x, w4.y);
    wlds[n * 68 + kq * 2 + 1] = pack_bf16x2(w4.z, w4.w);
  }
  __syncthreads();
  const int row0 = blockIdx.x * 64 + wv * 16;
  const int r = min(row0 + (lane & 15), N_NODES - 1);
  const int kh = lane >> 4;               // k-octet selector 0..3
  U4 a[4];
  if (FP32IN) {
    const float* xp = (const float*)xin + (size_t)r * 128 + kh * 8;
#pragma unroll
    for (int kb = 0; kb < 4; ++kb) {
      const float4 lo = *(const float4*)(xp + kb * 32);
      const float4 hi = *(const float4*)(xp + kb * 32 + 4);
      a[kb].u = make_uint4(pack_bf16x2(lo.x, lo.y), pack_bf16x2(lo.z, lo.w),
                           pack_bf16x2(hi.x, hi.y), pack_bf16x2(hi.z, hi.w));
    }
  } else {
    const uint4* xp = (const uint4*)xin + (size_t)r * 16 + kh;
#pragma unroll
    for (int kb = 0; kb < 4; ++kb) a[kb].u = xp[kb * 4];
  }
#pragma unroll
  for (int np = 0; np < NT; np += 2) {
#pragma unroll
    for (int t = 0; t < 2; ++t) {
      f32x4 acc = {0.f, 0.f, 0.f, 0.f};
      const int n = (np + t) * 16 + (lane & 15);
#pragma unroll
      for (int kb = 0; kb < 4; ++kb) {
        U4 bf;
        bf.u = *(const uint4*)(wlds + n * 68 + kb * 16 + kh * 4);
        acc = __builtin_amdgcn_mfma_f32_16x16x32_bf16(a[kb].v, bf.v, acc, 0, 0, 0);
      }
#pragma unroll
      for (int rr = 0; rr < 4; ++rr)
        clds[wv][kh * 4 + rr][t * 16 + (lane & 15)] = acc[rr];
    }
    __syncthreads();
    const int orow = lane & 15;
    const int colg = (lane >> 4) * 8;     // 0,8,16,24
    const int grow = row0 + orow;
    const float di = dinv[grow < N_NODES ? grow : 0];
    const float4 c0 = *(const float4*)&clds[wv][orow][colg];
    const float4 c1 = *(const float4*)&clds[wv][orow][colg + 4];
    if (grow < N_NODES) {
      if (FP8OUT) {
        uint32_t u0 = __builtin_amdgcn_cvt_pk_fp8_f32(di * c0.x, di * c0.y, 0, false);
        u0 = __builtin_amdgcn_cvt_pk_fp8_f32(di * c0.z, di * c0.w, u0, true);
        uint32_t u1 = __builtin_amdgcn_cvt_pk_fp8_f32(di * c1.x, di * c1.y, 0, false);
        u1 = __builtin_amdgcn_cvt_pk_fp8_f32(di * c1.z, di * c1.w, u1, true);
        *(uint2*)(hout + (size_t)grow * 32 + np * 4 + colg / 4) = make_uint2(u0, u1);
      } else {
        const uint4 pkv = make_uint4(pack_bf16x2(di * c0.x, di * c0.y),
                                     pack_bf16x2(di * c0.z, di * c0.w),
                                     pack_bf16x2(di * c1.x, di * c1.y),
                                     pack_bf16x2(di * c1.z, di * c1.w));
        *(uint4*)(hout + (size_t)grow * (OUT / 2) + np * 8 + colg / 2) = pkv;
      }
    }
    __syncthreads();
  }
}

// ---------------- aggregation (fp8 gather): out[i] = di*(sum_c hs[c] + hs[i]) + b ----------------
// Quad-edge layout: lane quarter q handles edges 4j+q; 16 lanes x uint2 = full 128B row;
// 8 cols/lane fp32 acc; quarters combined via shfl_xor(32),(16); bf16x2 output.
template<bool RELU>
__global__ __launch_bounds__(256) void k_agg128(const uint2* __restrict__ h8,
                                                const float* __restrict__ dinv,
                                                const int* __restrict__ rowptr,
                                                const int* __restrict__ col,
                                                const float* __restrict__ bias,
                                                uint32_t* __restrict__ out) {
  const int lane = threadIdx.x & 63;
  const int q = lane >> 4;      // edge sub-slot 0..3
  const int t = lane & 15;      // uint2 index: cols {8t..8t+7}
  const int bswz = (blockIdx.x & 7) * (gridDim.x >> 3) + (blockIdx.x >> 3);
  const int node = bswz * 4 + (threadIdx.x >> 6);
  if (node >= N_NODES) return;
  const int e0 = rowptr[node], e1 = rowptr[node + 1];
  float a0 = 0.f, a1 = 0.f, a2 = 0.f, a3 = 0.f, a4 = 0.f, a5 = 0.f, a6 = 0.f, a7 = 0.f;
  if (q == 0) {  // self-loop counted once
    const uint2 us = h8[(size_t)node * 16 + t];
    ACC8(us);
  }
  for (int eb = e0; eb < e1; eb += 64) {
    const int n = min(64, e1 - eb);
    const int ce = col[min(eb + lane, e1 - 1)];
    const int qn = (n + 3) >> 2;
#pragma unroll 4
    for (int j = 0; j < qn; ++j) {
      const int idx = 4 * j + q;
      const int c = __shfl(ce, idx);
      if (idx < n) {
        const uint2 u = h8[(size_t)c * 16 + t];
        ACC8(u);
      }
    }
  }
  a0 += __shfl_xor(a0, 32); a1 += __shfl_xor(a1, 32);
  a2 += __shfl_xor(a2, 32); a3 += __shfl_xor(a3, 32);
  a4 += __shfl_xor(a4, 32); a5 += __shfl_xor(a5, 32);
  a6 += __shfl_xor(a6, 32); a7 += __shfl_xor(a7, 32);
  a0 += __shfl_xor(a0, 16); a1 += __shfl_xor(a1, 16);
  a2 += __shfl_xor(a2, 16); a3 += __shfl_xor(a3, 16);
  a4 += __shfl_xor(a4, 16); a5 += __shfl_xor(a5, 16);
  a6 += __shfl_xor(a6, 16); a7 += __shfl_xor(a7, 16);
  if (q == 0) {
    const float di = dinv[node];
    const float4 b0 = ((const float4*)bias)[t * 2];
    const float4 b1 = ((const float4*)bias)[t * 2 + 1];
    float o0 = di * a0 + b0.x, o1 = di * a1 + b0.y;
    float o2 = di * a2 + b0.z, o3 = di * a3 + b0.w;
    float o4 = di * a4 + b1.x, o5 = di * a5 + b1.y;
    float o6 = di * a6 + b1.z, o7 = di * a7 + b1.w;
    if (RELU) {
      o0 = fmaxf(o0, 0.f); o1 = fmaxf(o1, 0.f); o2 = fmaxf(o2, 0.f); o3 = fmaxf(o3, 0.f);
      o4 = fmaxf(o4, 0.f); o5 = fmaxf(o5, 0.f); o6 = fmaxf(o6, 0.f); o7 = fmaxf(o7, 0.f);
    }
    ((uint4*)out)[(size_t)node * 16 + t] =
        make_uint4(pack_bf16x2(o0, o1), pack_bf16x2(o2, o3),
                   pack_bf16x2(o4, o5), pack_bf16x2(o6, o7));
  }
}

// Final layer: bf16 gather (accuracy), quad-edge; fused bias + log_softmax; fp32 out.
__global__ __launch_bounds__(256) void k_agg64_lsm(const uint32_t* __restrict__ hs,
                                                   const float* __restrict__ dinv,
                                                   const int* __restrict__ rowptr,
                                                   const int* __restrict__ col,
                                                   const float* __restrict__ bias,
                                                   float* __restrict__ out) {
  const int lane = threadIdx.x & 63;
  const int q = lane >> 4;      // edge sub-slot 0..3
  const int t = lane & 15;      // uint2 index: cols {4t..4t+3}
  const int bswz = (blockIdx.x & 7) * (gridDim.x >> 3) + (blockIdx.x >> 3);
  const int node = bswz * 4 + (threadIdx.x >> 6);
  if (node >= N_NODES) return;
  const int e0 = rowptr[node], e1 = rowptr[node + 1];
  const uint2* hp = (const uint2*)hs;   // row = 16 uint2
  float a0 = 0.f, a1 = 0.f, a2 = 0.f, a3 = 0.f;
  if (q == 0) {  // self-loop counted once
    const uint2 us = hp[(size_t)node * 16 + t];
    a0 = bf16lo(us.x); a1 = bf16hi(us.x); a2 = bf16lo(us.y); a3 = bf16hi(us.y);
  }
  for (int eb = e0; eb < e1; eb += 64) {
    const int n = min(64, e1 - eb);
    const int ce = col[min(eb + lane, e1 - 1)];
    const int qn = (n + 3) >> 2;
#pragma unroll 4
    for (int j = 0; j < qn; ++j) {
      const int idx = 4 * j + q;
      const int c = __shfl(ce, idx);
      if (idx < n) {
        const uint2 u = hp[(size_t)c * 16 + t];
        a0 += bf16lo(u.x); a1 += bf16hi(u.x);
        a2 += bf16lo(u.y); a3 += bf16hi(u.y);
      }
    }
  }
  a0 += __shfl_xor(a0, 32); a1 += __shfl_xor(a1, 32);
  a2 += __shfl_xor(a2, 32); a3 += __shfl_xor(a3, 32);
  a0 += __shfl_xor(a0, 16); a1 += __shfl_xor(a1, 16);
  a2 += __shfl_xor(a2, 16); a3 += __shfl_xor(a3, 16);
  const float di = dinv[node];
  const float4 bv = ((const float4*)bias)[t];
  const float v0 = di * a0 + bv.x;
  const float v1 = di * a1 + bv.y;
  const float v2 = di * a2 + bv.z;
  const float v3 = di * a3 + bv.w;
  float m = fmaxf(fmaxf(v0, v1), fmaxf(v2, v3));
#pragma unroll
  for (int off = 8; off > 0; off >>= 1) m = fmaxf(m, __shfl_xor(m, off));
  float s = __expf(v0 - m) + __expf(v1 - m) + __expf(v2 - m) + __expf(v3 - m);
#pragma unroll
  for (int off = 8; off > 0; off >>= 1) s += __shfl_xor(s, off);
  const float ls = m + __logf(s);
  if (q == 0)
    ((float4*)out)[(size_t)node * 16 + t] = make_float4(v0 - ls, v1 - ls, v2 - ls, v3 - ls);
}

// ---------------- launch ----------------

extern "C" void kernel_launch(void* const* d_in, const int* in_sizes, int n_in,
                              void* d_out, int out_size, void* d_ws, size_t ws_size,
                              hipStream_t stream) {
  const float* x  = (const float*)d_in[0];
  const int*   ei = (const int*)d_in[1];
  const float* W0 = (const float*)d_in[2];
  const float* b0 = (const float*)d_in[3];
  const float* W1 = (const float*)d_in[4];
  const float* b1 = (const float*)d_in[5];
  const float* W2 = (const float*)d_in[6];
  const float* b2 = (const float*)d_in[7];
  float* outp = (float*)d_out;

  char* p = (char*)d_ws;
  float* dinv    = (float*)p; p += alup((size_t)N_NODES * 4);
  int*   rowptr  = (int*)p;   p += alup((size_t)(N_NODES + 1) * 4);
  int*   bukcnt  = (int*)p;   p += alup((size_t)NBUK * 4);
  int*   bbase   = (int*)p;   p += alup((size_t)(NBUK + 1) * 4);
  int*   cntmat  = (int*)p;   p += alup((size_t)NBLK * NBUK * 4);
  int*   col     = (int*)p;   p += alup((size_t)2 * N_EDGES * 4);
  float* bufA    = (float*)p; p += alup((size_t)N_NODES * 128 * 4);
  float* bufB    = (float*)p;
  uint32_t* ebuf = (uint32_t*)bufA;       // pass-1 staging aliases bufA
  uint32_t* h16  = (uint32_t*)bufA;       // gemm output buffer (fp8 or bf16)
  uint32_t* a16  = (uint32_t*)bufB;       // bf16x2 agg output (layers 0/1)

  k_hist<<<NBLK, 512, 0, stream>>>(ei, cntmat);
  k_scanB<<<NBUK, 64, 0, stream>>>(cntmat, bukcnt);
  k_scan2<<<1, 512, 0, stream>>>(bukcnt, bbase, rowptr);
  k_bin<<<NBLK, 512, 0, stream>>>(ei, bbase, cntmat, ebuf);
  k_csr<<<NBUK, 512, 0, stream>>>(ebuf, bbase, col, rowptr, dinv);

  const int gblk = (N_NODES + 63) / 64;   // 1563
  k_gemm<128, true, true><<<gblk, 256, 0, stream>>>(x, W0, dinv, h16);
  k_agg128<true><<<N_NODES / 4, 256, 0, stream>>>((const uint2*)h16, dinv, rowptr, col, b0, a16);
  k_gemm<128, false, true><<<gblk, 256, 0, stream>>>(a16, W1, dinv, h16);
  k_agg128<true><<<N_NODES / 4, 256, 0, stream>>>((const uint2*)h16, dinv, rowptr, col, b1, a16);
  k_gemm<64, false, false><<<gblk, 256, 0, stream>>>(a16, W2, dinv, h16);
  k_agg64_lsm<<<N_NODES / 4, 256, 0, stream>>>(h16, dinv, rowptr, col, b2, outp);
}

// Round 15
// 309.300 us; speedup vs baseline: 4.1774x; 1.0687x over previous
//
#include <hip/hip_runtime.h>
#include <hip/hip_bf16.h>
#include <cstdint>

#define N_NODES 100000
#define N_EDGES 1600000
#define NBUK 391   // ceil(N_NODES / 256) buckets of 256 dst nodes
#define CHUNK 4096
#define NBLK 782   // ceil(2*N_EDGES / CHUNK)
#define MAXB 10240 // LDS staging capacity per bucket (mean 8192, +22σ)
#define NSB 16     // src super-buckets: src>>13 in [0,13)

static inline size_t alup(size_t x) { return (x + 255) & ~(size_t)255; }

typedef __attribute__((ext_vector_type(8))) short bf16x8;
typedef __attribute__((ext_vector_type(4))) float f32x4;
typedef __attribute__((ext_vector_type(2))) float f32x2;
union U4 { uint4 u; bf16x8 v; };

static __device__ __forceinline__ uint32_t pack_bf16x2(float a, float b) {
  uint32_t ua = __float_as_uint(a); ua += 0x7FFF + ((ua >> 16) & 1);
  uint32_t ub = __float_as_uint(b); ub += 0x7FFF + ((ub >> 16) & 1);
  return (ua >> 16) | (ub & 0xFFFF0000u);
}
static __device__ __forceinline__ float bf16lo(uint32_t u) { return __uint_as_float(u << 16); }
static __device__ __forceinline__ float bf16hi(uint32_t u) { return __uint_as_float(u & 0xFFFF0000u); }

// fp8 e4m3 decode-accumulate: 8 fp8 in a uint2 -> a0..a7 (HW v_cvt_pk_f32_fp8)
#define ACC8(u)                                                              \
  {                                                                          \
    f32x2 p;                                                                 \
    p = __builtin_amdgcn_cvt_pk_f32_fp8((u).x, false); a0 += p.x; a1 += p.y; \
    p = __builtin_amdgcn_cvt_pk_f32_fp8((u).x, true);  a2 += p.x; a3 += p.y; \
    p = __builtin_amdgcn_cvt_pk_f32_fp8((u).y, false); a4 += p.x; a5 += p.y; \
    p = __builtin_amdgcn_cvt_pk_f32_fp8((u).y, true);  a6 += p.x; a7 += p.y; \
  }

// ---------------- prep kernels (atomic-free CSR build) ----------------

// Per-block histogram -> row of cntmat (coalesced stores, NO global atomics).
__global__ __launch_bounds__(512) void k_hist(const int* __restrict__ ei,
                                              int* __restrict__ cntmat) {
  __shared__ int hist[NBUK];
  const int tid = threadIdx.x;
  const int base = blockIdx.x * CHUNK;
  const int n = min(CHUNK, 2 * N_EDGES - base);
  for (int i = tid; i < NBUK; i += 512) hist[i] = 0;
  __syncthreads();
  for (int i = tid; i < n; i += 512) {
    const int e = base + i;
    const int dst = (e < N_EDGES) ? ei[N_EDGES + e] : ei[e - N_EDGES];
    atomicAdd(&hist[dst >> 8], 1);
  }
  __syncthreads();
  for (int i = tid; i < NBUK; i += 512)
    cntmat[(size_t)blockIdx.x * NBUK + i] = hist[i];
}

// Column scan: one wave per bucket; cntmat[blk][b] -> exclusive prefix over blk
// (in place); bucket total -> bukcnt[b].
__global__ __launch_bounds__(64) void k_scanB(int* __restrict__ cntmat,
                                              int* __restrict__ bukcnt) {
  const int b = blockIdx.x;
  const int lane = threadIdx.x;
  const int PER = (NBLK + 63) / 64;  // 13
  int v[PER]; int s = 0;
#pragma unroll
  for (int j = 0; j < PER; ++j) {
    const int blk = lane * PER + j;
    v[j] = (blk < NBLK) ? cntmat[(size_t)blk * NBUK + b] : 0;
    s += v[j];
  }
  int incl = s;
#pragma unroll
  for (int off = 1; off < 64; off <<= 1) {
    const int u = __shfl_up(incl, off);
    if (lane >= off) incl += u;
  }
  int run = incl - s;
#pragma unroll
  for (int j = 0; j < PER; ++j) {
    const int blk = lane * PER + j;
    if (blk < NBLK) cntmat[(size_t)blk * NBUK + b] = run;
    run += v[j];
  }
  if (lane == 63) bukcnt[b] = incl;
}

// Scan 391 bucket totals -> exclusive bbase[0..NBUK]; also seeds rowptr[N_NODES].
__global__ __launch_bounds__(512) void k_scan2(const int* __restrict__ bsum,
                                               int* __restrict__ bbase,
                                               int* __restrict__ rowptr) {
  const int tid = threadIdx.x;
  const int v = (tid < NBUK) ? bsum[tid] : 0;
  int incl = v;
#pragma unroll
  for (int off = 1; off < 64; off <<= 1) {
    const int u = __shfl_up(incl, off);
    if ((tid & 63) >= off) incl += u;
  }
  __shared__ int wsum[8];
  if ((tid & 63) == 63) wsum[tid >> 6] = incl;
  __syncthreads();
  const int wid = tid >> 6;
  int add = 0;
#pragma unroll
  for (int k = 0; k < 7; ++k)
    if (k < wid) add += wsum[k];
  incl += add;
  if (tid < NBUK) bbase[tid] = incl - v;
  if (tid == NBUK - 1) bbase[NBUK] = incl;  // = 2*N_EDGES
  if (tid == 0) rowptr[N_NODES] = 2 * N_EDGES;
}

// Pass 1: multisplit into 391 dst-buckets, coalesced writes; bucket id cached in LDS.
// Global write bases are precomputed (bbase + per-block prefix) -> NO global atomics.
__global__ __launch_bounds__(512) void k_bin(const int* __restrict__ ei,
                                             const int* __restrict__ bbase,
                                             const int* __restrict__ cntpre,
                                             uint32_t* __restrict__ ebuf) {
  __shared__ int hist[NBUK];
  __shared__ int excl[NBUK + 1];
  __shared__ int gbase[NBUK];
  __shared__ uint32_t stage[CHUNK];
  __shared__ unsigned short sbuk[CHUNK];
  const int tid = threadIdx.x;
  const int base = blockIdx.x * CHUNK;
  const int n = min(CHUNK, 2 * N_EDGES - base);
  for (int i = tid; i < NBUK; i += 512) {
    hist[i] = 0;
    gbase[i] = bbase[i] + cntpre[(size_t)blockIdx.x * NBUK + i];
  }
  __syncthreads();
  uint32_t pk[8]; int bk[8]; int rk[8];
#pragma unroll
  for (int i = 0; i < 8; ++i) {
    const int li = i * 512 + tid;
    bk[i] = -1;
    if (li < n) {
      const int e = base + li;
      const int src = ei[e];
      const int dst = (e < N_EDGES) ? ei[N_EDGES + e] : ei[e - N_EDGES];
      bk[i] = dst >> 8;
      pk[i] = ((uint32_t)(dst & 255) << 17) | (uint32_t)src;
      rk[i] = atomicAdd(&hist[bk[i]], 1);
    }
  }
  __syncthreads();
  if (tid < 64) {  // block-local exclusive prefix of hist (LDS only)
    int c[7]; int s = 0;
#pragma unroll
    for (int j = 0; j < 7; ++j) {
      const int b = tid * 7 + j;
      c[j] = (b < NBUK) ? hist[b] : 0;
      s += c[j];
    }
    int incl = s;
#pragma unroll
    for (int off = 1; off < 64; off <<= 1) {
      const int v = __shfl_up(incl, off);
      if (tid >= off) incl += v;
    }
    int run = incl - s;
#pragma unroll
    for (int j = 0; j < 7; ++j) {
      const int b = tid * 7 + j;
      if (b < NBUK) {
        excl[b] = run;
        run += c[j];
      }
    }
    if (tid == 63) excl[NBUK] = incl;
  }
  __syncthreads();
#pragma unroll
  for (int i = 0; i < 8; ++i)
    if (bk[i] >= 0) {
      const int pos = excl[bk[i]] + rk[i];
      stage[pos] = pk[i];
      sbuk[pos] = (unsigned short)bk[i];
    }
  __syncthreads();
  for (int i = tid; i < n; i += 512) {
    const int b = sbuk[i];
    ebuf[gbase[b] + (i - excl[b])] = stage[i];
  }
}

// Pass 2: per-bucket counting sort by (dst_local, src>>13); emits rowptr + dinv.
__global__ __launch_bounds__(512) void k_csr(const uint32_t* __restrict__ ebuf,
                                             const int* __restrict__ bbase,
                                             int* __restrict__ col,
                                             int* __restrict__ rowptr,
                                             float* __restrict__ dinv) {
  __shared__ int cnt[256 * NSB];   // 16 KB
  __shared__ int lstage[MAXB];     // 40 KB
  __shared__ int wsum[4];
  const int b = blockIdx.x;
  const int node0 = b << 8;
  const int gstart = bbase[b];
  const int total = bbase[b + 1] - gstart;
  const int tid = threadIdx.x;
  for (int i = tid; i < 256 * NSB; i += 512) cnt[i] = 0;
  __syncthreads();
  for (int i = tid; i < total; i += 512) {
    const uint32_t pk = ebuf[gstart + i];
    atomicAdd(&cnt[(pk >> 17) * NSB + ((pk & 0x1FFFF) >> 13)], 1);
  }
  __syncthreads();
  int nodetotal = 0;
  if (tid < 256) {
#pragma unroll
    for (int s = 0; s < NSB; ++s) nodetotal += cnt[tid * NSB + s];
    int incl = nodetotal;
#pragma unroll
    for (int off = 1; off < 64; off <<= 1) {
      const int u = __shfl_up(incl, off);
      if ((tid & 63) >= off) incl += u;
    }
    if ((tid & 63) == 63) wsum[tid >> 6] = incl;
    nodetotal = incl;   // stash inclusive value
  }
  __syncthreads();
  if (tid < 256) {
    int deg = 0;
#pragma unroll
    for (int s = 0; s < NSB; ++s) deg += cnt[tid * NSB + s];
    const int wid = tid >> 6;
    int add = 0;
#pragma unroll
    for (int k = 0; k < 3; ++k)
      if (k < wid) add += wsum[k];
    const int prefix = nodetotal + add - deg;
    const int node = node0 + tid;
    if (node < N_NODES) {
      rowptr[node] = gstart + prefix;
      dinv[node] = rsqrtf((float)(deg + 1));  // +1 self loop
    }
    int run = prefix;
#pragma unroll
    for (int s = 0; s < NSB; ++s) {
      const int c = cnt[tid * NSB + s];
      cnt[tid * NSB + s] = run;
      run += c;
    }
  }
  __syncthreads();
  for (int i = tid; i < total; i += 512) {
    const uint32_t pk = ebuf[gstart + i];
    const int src = pk & 0x1FFFF;
    const int p = atomicAdd(&cnt[(pk >> 17) * NSB + (src >> 13)], 1);
    if (p < MAXB) lstage[p] = src;
    else col[gstart + p] = src;  // overflow fallback (statistically never)
  }
  __syncthreads();
  const int m = min(total, MAXB);
  for (int i = tid; i < m; i += 512) col[gstart + i] = lstage[i];
}

// ---------------- MFMA GEMM: hs = dinv[row] * (x @ W.T) ----------------
// FP8OUT: pack to fp8 e4m3 (row = OUT/4 u32); else bf16x2 (row = OUT/2 u32).
template<int OUT, bool FP32IN, bool FP8OUT>
__global__ __launch_bounds__(256) void k_gemm(const void* __restrict__ xin,
                                              const float* __restrict__ W,
                                              const float* __restrict__ dinv,
                                              uint32_t* __restrict__ hout) {
  constexpr int NT = OUT / 16;
  __shared__ uint32_t wlds[OUT * 68];     // W bf16x2, row n stride 68 u32 (pad)
  __shared__ float clds[4][16][36];       // per-wave C staging (2 n-tiles)
  const int tid = threadIdx.x;
  const int lane = tid & 63;
  const int wv = tid >> 6;
  for (int idx = tid; idx < OUT * 32; idx += 256) {
    const int n = idx >> 5;
    const int kq = idx & 31;              // 4 k per step
    const float4 w4 = *(const float4*)(W + (size_t)n * 128 + kq * 4);
    wlds[n * 68 + kq * 2 + 0] = pack_bf16x2(w4.x, w4.y);
    wlds[n * 68 + kq * 2 + 1] = pack_bf16x2(w4.z, w4.w);
  }
  __syncthreads();
  const int row0 = blockIdx.x * 64 + wv * 16;
  const int r = min(row0 + (lane & 15), N_NODES - 1);
  const int kh = lane >> 4;               // k-octet selector 0..3
  U4 a[4];
  if (FP32IN) {
    const float* xp = (const float*)xin + (size_t)r * 128 + kh * 8;
#pragma unroll
    for (int kb = 0; kb < 4; ++kb) {
      const float4 lo = *(const float4*)(xp + kb * 32);
      const float4 hi = *(const float4*)(xp + kb * 32 + 4);
      a[kb].u = make_uint4(pack_bf16x2(lo.x, lo.y), pack_bf16x2(lo.z, lo.w),
                           pack_bf16x2(hi.x, hi.y), pack_bf16x2(hi.z, hi.w));
    }
  } else {
    const uint4* xp = (const uint4*)xin + (size_t)r * 16 + kh;
#pragma unroll
    for (int kb = 0; kb < 4; ++kb) a[kb].u = xp[kb * 4];
  }
#pragma unroll
  for (int np = 0; np < NT; np += 2) {
#pragma unroll
    for (int t = 0; t < 2; ++t) {
      f32x4 acc = {0.f, 0.f, 0.f, 0.f};
      const int n = (np + t) * 16 + (lane & 15);
#pragma unroll
      for (int kb = 0; kb < 4; ++kb) {
        U4 bf;
        bf.u = *(const uint4*)(wlds + n * 68 + kb * 16 + kh * 4);
        acc = __builtin_amdgcn_mfma_f32_16x16x32_bf16(a[kb].v, bf.v, acc, 0, 0, 0);
      }
#pragma unroll
      for (int rr = 0; rr < 4; ++rr)
        clds[wv][kh * 4 + rr][t * 16 + (lane & 15)] = acc[rr];
    }
    __syncthreads();
    const int orow = lane & 15;
    const int colg = (lane >> 4) * 8;     // 0,8,16,24
    const int grow = row0 + orow;
    const float di = dinv[grow < N_NODES ? grow : 0];
    const float4 c0 = *(const float4*)&clds[wv][orow][colg];
    const float4 c1 = *(const float4*)&clds[wv][orow][colg + 4];
    if (grow < N_NODES) {
      if (FP8OUT) {
        uint32_t u0 = __builtin_amdgcn_cvt_pk_fp8_f32(di * c0.x, di * c0.y, 0, false);
        u0 = __builtin_amdgcn_cvt_pk_fp8_f32(di * c0.z, di * c0.w, u0, true);
        uint32_t u1 = __builtin_amdgcn_cvt_pk_fp8_f32(di * c1.x, di * c1.y, 0, false);
        u1 = __builtin_amdgcn_cvt_pk_fp8_f32(di * c1.z, di * c1.w, u1, true);
        *(uint2*)(hout + (size_t)grow * (OUT / 4) + np * 4 + colg / 4) = make_uint2(u0, u1);
      } else {
        const uint4 pkv = make_uint4(pack_bf16x2(di * c0.x, di * c0.y),
                                     pack_bf16x2(di * c0.z, di * c0.w),
                                     pack_bf16x2(di * c1.x, di * c1.y),
                                     pack_bf16x2(di * c1.z, di * c1.w));
        *(uint4*)(hout + (size_t)grow * (OUT / 2) + np * 8 + colg / 2) = pkv;
      }
    }
    __syncthreads();
  }
}

// ---------------- aggregation (fp8 gather): out[i] = di*(sum_c hs[c] + hs[i]) + b ----------------
// Quad-edge layout: lane quarter q handles edges 4j+q; 16 lanes x uint2 = full 128B row;
// 8 cols/lane fp32 acc; quarters combined via shfl_xor(32),(16); bf16x2 output.
template<bool RELU>
__global__ __launch_bounds__(256) void k_agg128(const uint2* __restrict__ h8,
                                                const float* __restrict__ dinv,
                                                const int* __restrict__ rowptr,
                                                const int* __restrict__ col,
                                                const float* __restrict__ bias,
                                                uint32_t* __restrict__ out) {
  const int lane = threadIdx.x & 63;
  const int q = lane >> 4;      // edge sub-slot 0..3
  const int t = lane & 15;      // uint2 index: cols {8t..8t+7}
  const int bswz = (blockIdx.x & 7) * (gridDim.x >> 3) + (blockIdx.x >> 3);
  const int node = bswz * 4 + (threadIdx.x >> 6);
  if (node >= N_NODES) return;
  const int e0 = rowptr[node], e1 = rowptr[node + 1];
  float a0 = 0.f, a1 = 0.f, a2 = 0.f, a3 = 0.f, a4 = 0.f, a5 = 0.f, a6 = 0.f, a7 = 0.f;
  if (q == 0) {  // self-loop counted once
    const uint2 us = h8[(size_t)node * 16 + t];
    ACC8(us);
  }
  for (int eb = e0; eb < e1; eb += 64) {
    const int n = min(64, e1 - eb);
    const int ce = col[min(eb + lane, e1 - 1)];
    const int qn = (n + 3) >> 2;
#pragma unroll 4
    for (int j = 0; j < qn; ++j) {
      const int idx = 4 * j + q;
      const int c = __shfl(ce, idx);
      if (idx < n) {
        const uint2 u = h8[(size_t)c * 16 + t];
        ACC8(u);
      }
    }
  }
  a0 += __shfl_xor(a0, 32); a1 += __shfl_xor(a1, 32);
  a2 += __shfl_xor(a2, 32); a3 += __shfl_xor(a3, 32);
  a4 += __shfl_xor(a4, 32); a5 += __shfl_xor(a5, 32);
  a6 += __shfl_xor(a6, 32); a7 += __shfl_xor(a7, 32);
  a0 += __shfl_xor(a0, 16); a1 += __shfl_xor(a1, 16);
  a2 += __shfl_xor(a2, 16); a3 += __shfl_xor(a3, 16);
  a4 += __shfl_xor(a4, 16); a5 += __shfl_xor(a5, 16);
  a6 += __shfl_xor(a6, 16); a7 += __shfl_xor(a7, 16);
  if (q == 0) {
    const float di = dinv[node];
    const float4 b0 = ((const float4*)bias)[t * 2];
    const float4 b1 = ((const float4*)bias)[t * 2 + 1];
    float o0 = di * a0 + b0.x, o1 = di * a1 + b0.y;
    float o2 = di * a2 + b0.z, o3 = di * a3 + b0.w;
    float o4 = di * a4 + b1.x, o5 = di * a5 + b1.y;
    float o6 = di * a6 + b1.z, o7 = di * a7 + b1.w;
    if (RELU) {
      o0 = fmaxf(o0, 0.f); o1 = fmaxf(o1, 0.f); o2 = fmaxf(o2, 0.f); o3 = fmaxf(o3, 0.f);
      o4 = fmaxf(o4, 0.f); o5 = fmaxf(o5, 0.f); o6 = fmaxf(o6, 0.f); o7 = fmaxf(o7, 0.f);
    }
    ((uint4*)out)[(size_t)node * 16 + t] =
        make_uint4(pack_bf16x2(o0, o1), pack_bf16x2(o2, o3),
                   pack_bf16x2(o4, o5), pack_bf16x2(o6, o7));
  }
}

// Final layer, fp8 gather (row = 8 uint2 = 64 B): octet-edge layout — lane octet q
// handles edges 8j+q; 8 lanes x uint2 cover a row; combine via shfl_xor(32,16,8);
// fused bias + log_softmax over 8 lanes x 8 cols (shfl_xor 4,2,1); fp32 out.
__global__ __launch_bounds__(256) void k_agg64_lsm(const uint2* __restrict__ h8,
                                                   const float* __restrict__ dinv,
                                                   const int* __restrict__ rowptr,
                                                   const int* __restrict__ col,
                                                   const float* __restrict__ bias,
                                                   float* __restrict__ out) {
  const int lane = threadIdx.x & 63;
  const int q = lane >> 3;      // edge sub-slot 0..7
  const int t = lane & 7;       // uint2 index: cols {8t..8t+7}
  const int bswz = (blockIdx.x & 7) * (gridDim.x >> 3) + (blockIdx.x >> 3);
  const int node = bswz * 4 + (threadIdx.x >> 6);
  if (node >= N_NODES) return;
  const int e0 = rowptr[node], e1 = rowptr[node + 1];
  float a0 = 0.f, a1 = 0.f, a2 = 0.f, a3 = 0.f, a4 = 0.f, a5 = 0.f, a6 = 0.f, a7 = 0.f;
  if (q == 0) {  // self-loop counted once
    const uint2 us = h8[(size_t)node * 8 + t];
    ACC8(us);
  }
  for (int eb = e0; eb < e1; eb += 64) {
    const int n = min(64, e1 - eb);
    const int ce = col[min(eb + lane, e1 - 1)];
    const int qn = (n + 7) >> 3;
#pragma unroll 4
    for (int j = 0; j < qn; ++j) {
      const int idx = 8 * j + q;
      const int c = __shfl(ce, idx);
      if (idx < n) {
        const uint2 u = h8[(size_t)c * 8 + t];
        ACC8(u);
      }
    }
  }
  // reduce over edge octets (bits 3..5 of lane)
  a0 += __shfl_xor(a0, 32); a1 += __shfl_xor(a1, 32);
  a2 += __shfl_xor(a2, 32); a3 += __shfl_xor(a3, 32);
  a4 += __shfl_xor(a4, 32); a5 += __shfl_xor(a5, 32);
  a6 += __shfl_xor(a6, 32); a7 += __shfl_xor(a7, 32);
  a0 += __shfl_xor(a0, 16); a1 += __shfl_xor(a1, 16);
  a2 += __shfl_xor(a2, 16); a3 += __shfl_xor(a3, 16);
  a4 += __shfl_xor(a4, 16); a5 += __shfl_xor(a5, 16);
  a6 += __shfl_xor(a6, 16); a7 += __shfl_xor(a7, 16);
  a0 += __shfl_xor(a0, 8);  a1 += __shfl_xor(a1, 8);
  a2 += __shfl_xor(a2, 8);  a3 += __shfl_xor(a3, 8);
  a4 += __shfl_xor(a4, 8);  a5 += __shfl_xor(a5, 8);
  a6 += __shfl_xor(a6, 8);  a7 += __shfl_xor(a7, 8);
  const float di = dinv[node];
  const float4 b0 = ((const float4*)bias)[t * 2];
  const float4 b1 = ((const float4*)bias)[t * 2 + 1];
  const float v0 = di * a0 + b0.x, v1 = di * a1 + b0.y;
  const float v2 = di * a2 + b0.z, v3 = di * a3 + b0.w;
  const float v4 = di * a4 + b1.x, v5 = di * a5 + b1.y;
  const float v6 = di * a6 + b1.z, v7 = di * a7 + b1.w;
  float m = fmaxf(fmaxf(fmaxf(v0, v1), fmaxf(v2, v3)),
                  fmaxf(fmaxf(v4, v5), fmaxf(v6, v7)));
#pragma unroll
  for (int off = 4; off > 0; off >>= 1) m = fmaxf(m, __shfl_xor(m, off));
  float s = __expf(v0 - m) + __expf(v1 - m) + __expf(v2 - m) + __expf(v3 - m) +
            __expf(v4 - m) + __expf(v5 - m) + __expf(v6 - m) + __expf(v7 - m);
#pragma unroll
  for (int off = 4; off > 0; off >>= 1) s += __shfl_xor(s, off);
  const float ls = m + __logf(s);
  if (q == 0) {
    float* op = out + (size_t)node * 64 + t * 8;
    *(float4*)op = make_float4(v0 - ls, v1 - ls, v2 - ls, v3 - ls);
    *(float4*)(op + 4) = make_float4(v4 - ls, v5 - ls, v6 - ls, v7 - ls);
  }
}

// ---------------- launch ----------------

extern "C" void kernel_launch(void* const* d_in, const int* in_sizes, int n_in,
                              void* d_out, int out_size, void* d_ws, size_t ws_size,
                              hipStream_t stream) {
  const float* x  = (const float*)d_in[0];
  const int*   ei = (const int*)d_in[1];
  const float* W0 = (const float*)d_in[2];
  const float* b0 = (const float*)d_in[3];
  const float* W1 = (const float*)d_in[4];
  const float* b1 = (const float*)d_in[5];
  const float* W2 = (const float*)d_in[6];
  const float* b2 = (const float*)d_in[7];
  float* outp = (float*)d_out;

  char* p = (char*)d_ws;
  float* dinv    = (float*)p; p += alup((size_t)N_NODES * 4);
  int*   rowptr  = (int*)p;   p += alup((size_t)(N_NODES + 1) * 4);
  int*   bukcnt  = (int*)p;   p += alup((size_t)NBUK * 4);
  int*   bbase   = (int*)p;   p += alup((size_t)(NBUK + 1) * 4);
  int*   cntmat  = (int*)p;   p += alup((size_t)NBLK * NBUK * 4);
  int*   col     = (int*)p;   p += alup((size_t)2 * N_EDGES * 4);
  float* bufA    = (float*)p; p += alup((size_t)N_NODES * 128 * 4);
  float* bufB    = (float*)p;
  uint32_t* ebuf = (uint32_t*)bufA;       // pass-1 staging aliases bufA
  uint32_t* h16  = (uint32_t*)bufA;       // gemm output buffer (fp8)
  uint32_t* a16  = (uint32_t*)bufB;       // bf16x2 agg output (layers 0/1)

  k_hist<<<NBLK, 512, 0, stream>>>(ei, cntmat);
  k_scanB<<<NBUK, 64, 0, stream>>>(cntmat, bukcnt);
  k_scan2<<<1, 512, 0, stream>>>(bukcnt, bbase, rowptr);
  k_bin<<<NBLK, 512, 0, stream>>>(ei, bbase, cntmat, ebuf);
  k_csr<<<NBUK, 512, 0, stream>>>(ebuf, bbase, col, rowptr, dinv);

  const int gblk = (N_NODES + 63) / 64;   // 1563
  k_gemm<128, true, true><<<gblk, 256, 0, stream>>>(x, W0, dinv, h16);
  k_agg128<true><<<N_NODES / 4, 256, 0, stream>>>((const uint2*)h16, dinv, rowptr, col, b0, a16);
  k_gemm<128, false, true><<<gblk, 256, 0, stream>>>(a16, W1, dinv, h16);
  k_agg128<true><<<N_NODES / 4, 256, 0, stream>>>((const uint2*)h16, dinv, rowptr, col, b1, a16);
  k_gemm<64, false, true><<<gblk, 256, 0, stream>>>(a16, W2, dinv, h16);
  k_agg64_lsm<<<N_NODES / 4, 256, 0, stream>>>((const uint2*)h16, dinv, rowptr, col, b2, outp);
}